// Round 6
// baseline (5114.633 us; speedup 1.0000x reference)
//
#include <hip/hip_runtime.h>
#include <hip/hip_bf16.h>

using bf16 = __hip_bfloat16;

#define D_DIM 512
#define C_DIM 2048
#define U_DIM 4
#define DK 64
#define TQF 32   // query tokens per flash block
#define TC 64    // contexts per tile

// Flag-selected load: f=1 -> fp32 data, f=0 -> bf16 data.
__device__ __forceinline__ float dload(const void* p, size_t i, int f) {
    return f ? ((const float*)p)[i] : __bfloat162float(((const bf16*)p)[i]);
}

// ---------------------------------------------------------------------------
// Input dtype detection (robustness; expected flag=1 -> fp32).
// ---------------------------------------------------------------------------
__global__ void detect_kernel(const void* __restrict__ x, int* __restrict__ flag) {
    const bf16* xb = (const bf16*)x;
    int tid = threadIdx.x;
    int cnt = 0;
    for (int i = tid; i < 8192; i += 256) {
        float a = fabsf(__bfloat162float(xb[i]));
        if (!(a <= 100.0f)) cnt++;
    }
    #pragma unroll
    for (int o = 32; o > 0; o >>= 1) cnt += __shfl_down(cnt, o);
    __shared__ int sred[4];
    if ((tid & 63) == 0) sred[tid >> 6] = cnt;
    __syncthreads();
    if (tid == 0) {
        int c = sred[0] + sred[1] + sred[2] + sred[3];
        *flag = (c > 400) ? 1 : 0;
    }
}

// ---------------------------------------------------------------------------
// Per-row mean / rstd for LayerNorm fusion. One block (256 thr) per row, D=512.
// ---------------------------------------------------------------------------
__global__ void row_stats_kernel(const void* __restrict__ x, int x_raw,
                                 float* __restrict__ stats, const int* __restrict__ flagp) {
    int f = x_raw ? *flagp : 1;
    int row = blockIdx.x;
    int tid = threadIdx.x;
    size_t base = (size_t)row * D_DIM;
    float v0 = dload(x, base + tid, f);
    float v1 = dload(x, base + tid + 256, f);
    float s  = v0 + v1;
    float ss = v0 * v0 + v1 * v1;
    #pragma unroll
    for (int o = 32; o > 0; o >>= 1) {
        s  += __shfl_down(s, o);
        ss += __shfl_down(ss, o);
    }
    __shared__ float sred[8];
    int wv = tid >> 6, ln = tid & 63;
    if (ln == 0) { sred[wv] = s; sred[wv + 4] = ss; }
    __syncthreads();
    if (tid == 0) {
        float S  = sred[0] + sred[1] + sred[2] + sred[3];
        float SS = sred[4] + sred[5] + sred[6] + sred[7];
        float mu  = S * (1.0f / D_DIM);
        float var = SS * (1.0f / D_DIM) - mu * mu;
        stats[row * 2]     = mu;
        stats[row * 2 + 1] = rsqrtf(var + 1e-5f);
    }
}

// ---------------------------------------------------------------------------
// Y[N x 512] = (LN? LN(X) : X) @ W + bias.  64x64 tile, 256 thr, 4x4/thread.
// ---------------------------------------------------------------------------
template <bool LN>
__global__ void gemm_ln_kernel(const void* __restrict__ X, int x_raw,
                               const float* __restrict__ stats,
                               const void* __restrict__ lnw, const void* __restrict__ lnb,
                               const void* __restrict__ W, const void* __restrict__ bias,
                               float* __restrict__ Y, const int* __restrict__ flagp) {
    __shared__ float As[16][68];
    __shared__ float Bs[16][68];
    int f = *flagp;
    int xf = x_raw ? f : 1;
    int tid = threadIdx.x;
    int tx = tid & 15, ty = tid >> 4;
    int row0 = blockIdx.y * 64, col0 = blockIdx.x * 64;
    float acc[4][4] = {};
    for (int kt = 0; kt < D_DIM; kt += 16) {
        #pragma unroll
        for (int i = 0; i < 4; ++i) {
            int e = tid + i * 256;
            int r = e >> 4, kk = e & 15;
            float xv = dload(X, (size_t)(row0 + r) * D_DIM + kt + kk, xf);
            if constexpr (LN) {
                float mu = stats[(row0 + r) * 2];
                float rs = stats[(row0 + r) * 2 + 1];
                xv = (xv - mu) * rs * dload(lnw, kt + kk, f) + dload(lnb, kt + kk, f);
            }
            As[kk][r] = xv;
            int kk2 = e >> 6, c2 = e & 63;
            Bs[kk2][c2] = dload(W, (size_t)(kt + kk2) * D_DIM + col0 + c2, f);
        }
        __syncthreads();
        #pragma unroll
        for (int kk = 0; kk < 16; ++kk) {
            float4 a = *(const float4*)&As[kk][ty * 4];
            float4 b = *(const float4*)&Bs[kk][tx * 4];
            acc[0][0] += a.x * b.x; acc[0][1] += a.x * b.y; acc[0][2] += a.x * b.z; acc[0][3] += a.x * b.w;
            acc[1][0] += a.y * b.x; acc[1][1] += a.y * b.y; acc[1][2] += a.y * b.z; acc[1][3] += a.y * b.w;
            acc[2][0] += a.z * b.x; acc[2][1] += a.z * b.y; acc[2][2] += a.z * b.z; acc[2][3] += a.z * b.w;
            acc[3][0] += a.w * b.x; acc[3][1] += a.w * b.y; acc[3][2] += a.w * b.z; acc[3][3] += a.w * b.w;
        }
        __syncthreads();
    }
    #pragma unroll
    for (int i = 0; i < 4; ++i) {
        int r = row0 + ty * 4 + i;
        #pragma unroll
        for (int j = 0; j < 4; ++j) {
            int c = col0 + tx * 4 + j;
            Y[(size_t)r * D_DIM + c] = acc[i][j] + dload(bias, c, f);
        }
    }
}

// ---------------------------------------------------------------------------
// Flash-style fused ColBERT attention. 256 blocks = 32 q-tiles x 8 heads.
// Block: 256 thr, TQF=32 query tokens, one head. Online softmax over C in
// TC=64-context tiles. Wave w owns output rows 8w..8w+7; lane = output dim.
// Traffic per block: K-slice 2MB + V-slice 0.5MB -> 256 x 2.5MB = 640 MB
// total (8x less than TQ=4).  LDS ~33.5 KB.
// ---------------------------------------------------------------------------
__global__ void attn_flash_kernel(const float* __restrict__ qp, const float* __restrict__ kp,
                                  const float* __restrict__ vp, float* __restrict__ att) {
    __shared__ float sq[TQF][DK];        // 8 KB   query tile
    __shared__ float sp[TQF][TC + 4];    // 8.5 KB score/prob tile (row stride 68: b128-aligned, 2-way banks = free)
    __shared__ float sv[TC][DK];         // 16 KB  V tile
    __shared__ float sm[TQF], sl[TQF];   // running max / sum

    int tid = threadIdx.x;
    int h = blockIdx.x & 7;
    int bt0 = (blockIdx.x >> 3) * TQF;
    int w = tid >> 6, lane = tid & 63;

    #pragma unroll
    for (int i = 0; i < 2; ++i) {                 // 512 float4 of Q
        int e4 = i * 256 + tid;
        int tq = e4 >> 4, dq = (e4 & 15) * 4;
        *(float4*)&sq[tq][dq] = *(const float4*)&qp[(size_t)(bt0 + tq) * D_DIM + h * DK + dq];
    }
    if (tid < TQF) { sm[tid] = -1e30f; sl[tid] = 0.0f; }
    __syncthreads();

    float acc[8] = {};
    int u = tid & 3, csub = tid >> 2;

    for (int tile = 0; tile < C_DIM / TC; ++tile) {
        int c0 = tile * TC;

        // K fragment for this thread's (context, u) into registers
        const float* kvp = kp + ((size_t)(c0 + csub) * U_DIM + u) * D_DIM + h * DK;
        float4 kr[16];
        #pragma unroll
        for (int dd = 0; dd < 16; ++dd) kr[dd] = ((const float4*)kvp)[dd];

        // V tile -> LDS (independent of score compute; overlaps K latency)
        #pragma unroll
        for (int i = 0; i < 4; ++i) {
            int e4 = i * 256 + tid;               // 1024 float4
            int c = e4 >> 4, dq = (e4 & 15) * 4;
            *(float4*)&sv[c][dq] = *(const float4*)&vp[(size_t)(c0 + c) * D_DIM + h * DK + dq];
        }

        // scores: MaxSim over u via quad shuffles
        #pragma unroll 4
        for (int tq = 0; tq < TQF; ++tq) {
            float s = 0.0f;
            #pragma unroll
            for (int dd = 0; dd < 16; ++dd) {
                float4 qv = *(const float4*)&sq[tq][dd * 4];
                s += qv.x * kr[dd].x + qv.y * kr[dd].y + qv.z * kr[dd].z + qv.w * kr[dd].w;
            }
            s = fmaxf(s, __shfl_xor(s, 1));
            s = fmaxf(s, __shfl_xor(s, 2));
            if (u == 0) sp[tq][csub] = s * 0.125f;   // 1/sqrt(dk)
        }
        __syncthreads();

        // online-softmax update + PV for this wave's 8 rows
        #pragma unroll
        for (int j = 0; j < 8; ++j) {
            int tq = w * 8 + j;
            float sval = sp[tq][lane];               // lane <-> context in tile
            float tmax = sval;
            #pragma unroll
            for (int o = 1; o < 64; o <<= 1) tmax = fmaxf(tmax, __shfl_xor(tmax, o));
            float mold = sm[tq];
            float mnew = fmaxf(mold, tmax);
            float alpha = __expf(mold - mnew);       // 0 on first tile (mold=-1e30)
            float p = __expf(sval - mnew);
            float rsum = p;
            #pragma unroll
            for (int o = 1; o < 64; o <<= 1) rsum += __shfl_xor(rsum, o);
            if (lane == 0) { sm[tq] = mnew; sl[tq] = sl[tq] * alpha + rsum; }
            sp[tq][lane] = p;                        // same-wave LDS round-trip
            acc[j] *= alpha;
            #pragma unroll
            for (int c4 = 0; c4 < TC / 4; ++c4) {
                float4 pv = *(const float4*)&sp[tq][c4 * 4];
                acc[j] += pv.x * sv[c4 * 4 + 0][lane];
                acc[j] += pv.y * sv[c4 * 4 + 1][lane];
                acc[j] += pv.z * sv[c4 * 4 + 2][lane];
                acc[j] += pv.w * sv[c4 * 4 + 3][lane];
            }
        }
        __syncthreads();
    }

    #pragma unroll
    for (int j = 0; j < 8; ++j) {
        int tq = w * 8 + j;
        att[(size_t)(bt0 + tq) * D_DIM + h * DK + lane] = acc[j] / sl[tq];
    }
}

extern "C" void kernel_launch(void* const* d_in, const int* in_sizes, int n_in,
                              void* d_out, int out_size, void* d_ws, size_t ws_size,
                              hipStream_t stream) {
    const void* model_embed = d_in[0];
    const void* ctx_key     = d_in[1];
    const void* ctx_val     = d_in[2];
    const void* ln1w = d_in[3];  const void* ln1b = d_in[4];
    const void* ln2w = d_in[5];  const void* ln2b = d_in[6];
    const void* ln3w = d_in[7];  const void* ln3b = d_in[8];
    const void* ln4w = d_in[9];  const void* ln4b = d_in[10];
    const void* wq = d_in[11];   const void* bq = d_in[12];
    const void* wk = d_in[13];   const void* bk = d_in[14];
    const void* wv = d_in[15];   const void* bv = d_in[16];
    const void* wo = d_in[17];   const void* bo = d_in[18];
    const void* wp = d_in[19];   const void* bp = d_in[20];

    int*   flagp  = (int*)d_ws;
    float* ws     = (float*)d_ws + 16;
    float* qp     = ws;                    // 1024*512
    float* kp     = qp + 1024 * 512;       // 8192*512
    float* vp     = kp + 8192 * 512;       // 2048*512
    float* att    = vp + 2048 * 512;       // 1024*512
    float* o1     = att + 1024 * 512;      // 1024*512
    float* statsQ = o1 + 1024 * 512;       // 2048
    float* statsK = statsQ + 2048;         // 16384
    float* statsV = statsK + 16384;        // 4096
    float* statsO = statsV + 4096;         // 2048

    detect_kernel<<<1, 256, 0, stream>>>(model_embed, flagp);

    row_stats_kernel<<<1024, 256, 0, stream>>>(model_embed, 1, statsQ, flagp);
    row_stats_kernel<<<8192, 256, 0, stream>>>(ctx_key, 1, statsK, flagp);
    row_stats_kernel<<<2048, 256, 0, stream>>>(ctx_val, 1, statsV, flagp);

    gemm_ln_kernel<true><<<dim3(8, 16), 256, 0, stream>>>(model_embed, 1, statsQ, ln1w, ln1b, wq, bq, qp, flagp);
    gemm_ln_kernel<true><<<dim3(8, 128), 256, 0, stream>>>(ctx_key, 1, statsK, ln2w, ln2b, wk, bk, kp, flagp);
    gemm_ln_kernel<true><<<dim3(8, 32), 256, 0, stream>>>(ctx_val, 1, statsV, ln3w, ln3b, wv, bv, vp, flagp);

    attn_flash_kernel<<<256, 256, 0, stream>>>(qp, kp, vp, att);

    gemm_ln_kernel<false><<<dim3(8, 16), 256, 0, stream>>>(att, 0, nullptr, nullptr, nullptr, wo, bo, o1, flagp);
    row_stats_kernel<<<1024, 256, 0, stream>>>(o1, 0, statsO, flagp);
    gemm_ln_kernel<true><<<dim3(8, 16), 256, 0, stream>>>(o1, 0, statsO, ln4w, ln4b, wp, bp, (float*)d_out, flagp);
}

// Round 7
// 2922.048 us; speedup vs baseline: 1.7504x; 1.7504x over previous
//
#include <hip/hip_runtime.h>
#include <hip/hip_bf16.h>

using bf16 = __hip_bfloat16;

#define D_DIM 512
#define C_DIM 2048
#define U_DIM 4
#define DK 64
#define TQF 32   // query tokens per flash block
#define TC 64    // contexts per tile

// Flag-selected load: f=1 -> fp32 data, f=0 -> bf16 data.
__device__ __forceinline__ float dload(const void* p, size_t i, int f) {
    return f ? ((const float*)p)[i] : __bfloat162float(((const bf16*)p)[i]);
}

// ---------------------------------------------------------------------------
// Input dtype detection (robustness; expected flag=1 -> fp32).
// ---------------------------------------------------------------------------
__global__ void detect_kernel(const void* __restrict__ x, int* __restrict__ flag) {
    const bf16* xb = (const bf16*)x;
    int tid = threadIdx.x;
    int cnt = 0;
    for (int i = tid; i < 8192; i += 256) {
        float a = fabsf(__bfloat162float(xb[i]));
        if (!(a <= 100.0f)) cnt++;
    }
    #pragma unroll
    for (int o = 32; o > 0; o >>= 1) cnt += __shfl_down(cnt, o);
    __shared__ int sred[4];
    if ((tid & 63) == 0) sred[tid >> 6] = cnt;
    __syncthreads();
    if (tid == 0) {
        int c = sred[0] + sred[1] + sred[2] + sred[3];
        *flag = (c > 400) ? 1 : 0;
    }
}

// ---------------------------------------------------------------------------
// Per-row mean / rstd for LayerNorm fusion. One block (256 thr) per row, D=512.
// ---------------------------------------------------------------------------
__global__ void row_stats_kernel(const void* __restrict__ x, int x_raw,
                                 float* __restrict__ stats, const int* __restrict__ flagp) {
    int f = x_raw ? *flagp : 1;
    int row = blockIdx.x;
    int tid = threadIdx.x;
    size_t base = (size_t)row * D_DIM;
    float v0 = dload(x, base + tid, f);
    float v1 = dload(x, base + tid + 256, f);
    float s  = v0 + v1;
    float ss = v0 * v0 + v1 * v1;
    #pragma unroll
    for (int o = 32; o > 0; o >>= 1) {
        s  += __shfl_down(s, o);
        ss += __shfl_down(ss, o);
    }
    __shared__ float sred[8];
    int wv = tid >> 6, ln = tid & 63;
    if (ln == 0) { sred[wv] = s; sred[wv + 4] = ss; }
    __syncthreads();
    if (tid == 0) {
        float S  = sred[0] + sred[1] + sred[2] + sred[3];
        float SS = sred[4] + sred[5] + sred[6] + sred[7];
        float mu  = S * (1.0f / D_DIM);
        float var = SS * (1.0f / D_DIM) - mu * mu;
        stats[row * 2]     = mu;
        stats[row * 2 + 1] = rsqrtf(var + 1e-5f);
    }
}

// ---------------------------------------------------------------------------
// Y[N x 512] = (LN? LN(X) : X) @ W + bias.  64x64 tile, 256 thr, 4x4/thread.
// ---------------------------------------------------------------------------
template <bool LN>
__global__ void gemm_ln_kernel(const void* __restrict__ X, int x_raw,
                               const float* __restrict__ stats,
                               const void* __restrict__ lnw, const void* __restrict__ lnb,
                               const void* __restrict__ W, const void* __restrict__ bias,
                               float* __restrict__ Y, const int* __restrict__ flagp) {
    __shared__ float As[16][68];
    __shared__ float Bs[16][68];
    int f = *flagp;
    int xf = x_raw ? f : 1;
    int tid = threadIdx.x;
    int tx = tid & 15, ty = tid >> 4;
    int row0 = blockIdx.y * 64, col0 = blockIdx.x * 64;
    float acc[4][4] = {};
    for (int kt = 0; kt < D_DIM; kt += 16) {
        #pragma unroll
        for (int i = 0; i < 4; ++i) {
            int e = tid + i * 256;
            int r = e >> 4, kk = e & 15;
            float xv = dload(X, (size_t)(row0 + r) * D_DIM + kt + kk, xf);
            if constexpr (LN) {
                float mu = stats[(row0 + r) * 2];
                float rs = stats[(row0 + r) * 2 + 1];
                xv = (xv - mu) * rs * dload(lnw, kt + kk, f) + dload(lnb, kt + kk, f);
            }
            As[kk][r] = xv;
            int kk2 = e >> 6, c2 = e & 63;
            Bs[kk2][c2] = dload(W, (size_t)(kt + kk2) * D_DIM + col0 + c2, f);
        }
        __syncthreads();
        #pragma unroll
        for (int kk = 0; kk < 16; ++kk) {
            float4 a = *(const float4*)&As[kk][ty * 4];
            float4 b = *(const float4*)&Bs[kk][tx * 4];
            acc[0][0] += a.x * b.x; acc[0][1] += a.x * b.y; acc[0][2] += a.x * b.z; acc[0][3] += a.x * b.w;
            acc[1][0] += a.y * b.x; acc[1][1] += a.y * b.y; acc[1][2] += a.y * b.z; acc[1][3] += a.y * b.w;
            acc[2][0] += a.z * b.x; acc[2][1] += a.z * b.y; acc[2][2] += a.z * b.z; acc[2][3] += a.z * b.w;
            acc[3][0] += a.w * b.x; acc[3][1] += a.w * b.y; acc[3][2] += a.w * b.z; acc[3][3] += a.w * b.w;
        }
        __syncthreads();
    }
    #pragma unroll
    for (int i = 0; i < 4; ++i) {
        int r = row0 + ty * 4 + i;
        #pragma unroll
        for (int j = 0; j < 4; ++j) {
            int c = col0 + tx * 4 + j;
            Y[(size_t)r * D_DIM + c] = acc[i][j] + dload(bias, c, f);
        }
    }
}

// ---------------------------------------------------------------------------
// Flash-style fused ColBERT attention, context-split.
// Grid = 32 q-tiles x 8 heads x nsplit. Each block scans C/nsplit contexts
// with online softmax; writes unnormalized partial (acc, m, l) unless
// nsplit==1 (then final). __launch_bounds__(256,1): kr[16] float4 stays in
// registers (round-6 postmortem: default 64-VGPR cap spilled -> 6.6 GB
// scratch writes).
// ---------------------------------------------------------------------------
__global__ __launch_bounds__(256, 1)
void attn_flash_part(const float* __restrict__ qp, const float* __restrict__ kp,
                     const float* __restrict__ vp,
                     float* __restrict__ pacc, float* __restrict__ pm,
                     float* __restrict__ pl, int nsplit, float* __restrict__ att) {
    __shared__ float sq[TQF][DK];        // 8 KB
    __shared__ float sp[TQF][TC + 4];    // 8.5 KB
    __shared__ float sv[TC][DK];         // 16 KB
    __shared__ float sm[TQF], sl[TQF];

    int tid = threadIdx.x;
    int b = blockIdx.x;
    int s = b & (nsplit - 1);
    int h = (b / nsplit) & 7;
    int qt = b / (nsplit * 8);
    int bt0 = qt * TQF;
    int w = tid >> 6, lane = tid & 63;

    #pragma unroll
    for (int i = 0; i < 2; ++i) {
        int e4 = i * 256 + tid;
        int tq = e4 >> 4, dq = (e4 & 15) * 4;
        *(float4*)&sq[tq][dq] = *(const float4*)&qp[(size_t)(bt0 + tq) * D_DIM + h * DK + dq];
    }
    if (tid < TQF) { sm[tid] = -1e30f; sl[tid] = 0.0f; }
    __syncthreads();

    float acc[8] = {};
    int u = tid & 3, csub = tid >> 2;
    int cs = C_DIM / nsplit;            // contexts per split
    int ntile = cs / TC;

    for (int tile = 0; tile < ntile; ++tile) {
        int c0 = s * cs + tile * TC;

        const float* kvp = kp + ((size_t)(c0 + csub) * U_DIM + u) * D_DIM + h * DK;
        float4 kr[16];
        #pragma unroll
        for (int dd = 0; dd < 16; ++dd) kr[dd] = ((const float4*)kvp)[dd];

        #pragma unroll
        for (int i = 0; i < 4; ++i) {
            int e4 = i * 256 + tid;
            int c = e4 >> 4, dq = (e4 & 15) * 4;
            *(float4*)&sv[c][dq] = *(const float4*)&vp[(size_t)(c0 + c) * D_DIM + h * DK + dq];
        }

        #pragma unroll 4
        for (int tq = 0; tq < TQF; ++tq) {
            float sc = 0.0f;
            #pragma unroll
            for (int dd = 0; dd < 16; ++dd) {
                float4 qv = *(const float4*)&sq[tq][dd * 4];
                sc += qv.x * kr[dd].x + qv.y * kr[dd].y + qv.z * kr[dd].z + qv.w * kr[dd].w;
            }
            sc = fmaxf(sc, __shfl_xor(sc, 1));
            sc = fmaxf(sc, __shfl_xor(sc, 2));
            if (u == 0) sp[tq][csub] = sc * 0.125f;   // 1/sqrt(dk)
        }
        __syncthreads();

        #pragma unroll
        for (int j = 0; j < 8; ++j) {
            int tq = w * 8 + j;
            float sval = sp[tq][lane];
            float tmax = sval;
            #pragma unroll
            for (int o = 1; o < 64; o <<= 1) tmax = fmaxf(tmax, __shfl_xor(tmax, o));
            float mold = sm[tq];
            float mnew = fmaxf(mold, tmax);
            float alpha = __expf(mold - mnew);
            float p = __expf(sval - mnew);
            float rsum = p;
            #pragma unroll
            for (int o = 1; o < 64; o <<= 1) rsum += __shfl_xor(rsum, o);
            if (lane == 0) { sm[tq] = mnew; sl[tq] = sl[tq] * alpha + rsum; }
            sp[tq][lane] = p;
            acc[j] *= alpha;
            #pragma unroll
            for (int c4 = 0; c4 < TC / 4; ++c4) {
                float4 pv = *(const float4*)&sp[tq][c4 * 4];
                acc[j] += pv.x * sv[c4 * 4 + 0][lane];
                acc[j] += pv.y * sv[c4 * 4 + 1][lane];
                acc[j] += pv.z * sv[c4 * 4 + 2][lane];
                acc[j] += pv.w * sv[c4 * 4 + 3][lane];
            }
        }
        __syncthreads();
    }

    if (nsplit == 1) {
        #pragma unroll
        for (int j = 0; j < 8; ++j) {
            int tq = w * 8 + j;
            att[(size_t)(bt0 + tq) * D_DIM + h * DK + lane] = acc[j] / sl[tq];
        }
    } else {
        int p = (qt * 8 + h) * nsplit + s;
        #pragma unroll
        for (int j = 0; j < 8; ++j) {
            int tq = w * 8 + j;
            pacc[((size_t)p * TQF + tq) * DK + lane] = acc[j];
            if (lane == 0) { pm[p * TQF + tq] = sm[tq]; pl[p * TQF + tq] = sl[tq]; }
        }
    }
}

// Merge nsplit partials per (q-tile, head). Grid 256, 256 thr.
__global__ void attn_merge_kernel(const float* __restrict__ pacc, const float* __restrict__ pm,
                                  const float* __restrict__ pl, int nsplit,
                                  float* __restrict__ att) {
    int b = blockIdx.x;             // = qt*8 + h
    int qt = b >> 3, h = b & 7;
    int tid = threadIdx.x;
    int w = tid >> 6, lane = tid & 63;
    int p0 = b * nsplit;
    #pragma unroll
    for (int j = 0; j < 8; ++j) {
        int tq = w * 8 + j;
        float M = -1e30f;
        for (int s = 0; s < nsplit; ++s) M = fmaxf(M, pm[(p0 + s) * TQF + tq]);
        float L = 0.0f, o = 0.0f;
        for (int s = 0; s < nsplit; ++s) {
            float e = __expf(pm[(p0 + s) * TQF + tq] - M);
            L += pl[(p0 + s) * TQF + tq] * e;
            o += pacc[((size_t)(p0 + s) * TQF + tq) * DK + lane] * e;
        }
        att[(size_t)(qt * TQF + tq) * D_DIM + h * DK + lane] = o / L;
    }
}

extern "C" void kernel_launch(void* const* d_in, const int* in_sizes, int n_in,
                              void* d_out, int out_size, void* d_ws, size_t ws_size,
                              hipStream_t stream) {
    const void* model_embed = d_in[0];
    const void* ctx_key     = d_in[1];
    const void* ctx_val     = d_in[2];
    const void* ln1w = d_in[3];  const void* ln1b = d_in[4];
    const void* ln2w = d_in[5];  const void* ln2b = d_in[6];
    const void* ln3w = d_in[7];  const void* ln3b = d_in[8];
    const void* ln4w = d_in[9];  const void* ln4b = d_in[10];
    const void* wq = d_in[11];   const void* bq = d_in[12];
    const void* wk = d_in[13];   const void* bk = d_in[14];
    const void* wv = d_in[15];   const void* bv = d_in[16];
    const void* wo = d_in[17];   const void* bo = d_in[18];
    const void* wp = d_in[19];   const void* bp = d_in[20];

    int*   flagp  = (int*)d_ws;
    float* ws     = (float*)d_ws + 16;
    float* qp     = ws;                    // 1024*512
    float* kp     = qp + 1024 * 512;       // 8192*512
    float* vp     = kp + 8192 * 512;       // 2048*512
    float* att    = vp + 2048 * 512;       // 1024*512
    float* o1     = att + 1024 * 512;      // 1024*512
    float* statsQ = o1 + 1024 * 512;       // 2048
    float* statsK = statsQ + 2048;         // 16384
    float* statsV = statsK + 16384;        // 4096
    float* statsO = statsV + 4096;         // 2048
    float* pacc   = statsO + 2048;         // 256*4*32*64 = 2097152
    float* pm     = pacc + 256 * 4 * 32 * 64;  // 32768
    float* pl     = pm + 32768;            // 32768

    // bytes needed through pl with 4-way split:
    size_t need4 = (size_t)((16 + 6815744 + 24576 + 2097152 + 65536)) * 4;
    int nsplit = (ws_size >= need4) ? 4 : 1;

    detect_kernel<<<1, 256, 0, stream>>>(model_embed, flagp);

    row_stats_kernel<<<1024, 256, 0, stream>>>(model_embed, 1, statsQ, flagp);
    row_stats_kernel<<<8192, 256, 0, stream>>>(ctx_key, 1, statsK, flagp);
    row_stats_kernel<<<2048, 256, 0, stream>>>(ctx_val, 1, statsV, flagp);

    gemm_ln_kernel<true><<<dim3(8, 16), 256, 0, stream>>>(model_embed, 1, statsQ, ln1w, ln1b, wq, bq, qp, flagp);
    gemm_ln_kernel<true><<<dim3(8, 128), 256, 0, stream>>>(ctx_key, 1, statsK, ln2w, ln2b, wk, bk, kp, flagp);
    gemm_ln_kernel<true><<<dim3(8, 32), 256, 0, stream>>>(ctx_val, 1, statsV, ln3w, ln3b, wv, bv, vp, flagp);

    attn_flash_part<<<256 * nsplit, 256, 0, stream>>>(qp, kp, vp, pacc, pm, pl, nsplit, att);
    if (nsplit > 1)
        attn_merge_kernel<<<256, 256, 0, stream>>>(pacc, pm, pl, nsplit, att);

    gemm_ln_kernel<false><<<dim3(8, 16), 256, 0, stream>>>(att, 0, nullptr, nullptr, nullptr, wo, bo, o1, flagp);
    row_stats_kernel<<<1024, 256, 0, stream>>>(o1, 0, statsO, flagp);
    gemm_ln_kernel<true><<<dim3(8, 16), 256, 0, stream>>>(o1, 0, statsO, ln4w, ln4b, wp, bp, (float*)d_out, flagp);
}

// Round 8
// 880.149 us; speedup vs baseline: 5.8111x; 3.3199x over previous
//
#include <hip/hip_runtime.h>
#include <hip/hip_bf16.h>

using bf16 = __hip_bfloat16;

#define D_DIM 512
#define C_DIM 2048
#define U_DIM 4
#define DK 64
#define TQF 32
#define TC 64

__device__ __forceinline__ float dload(const void* p, size_t i, int f) {
    return f ? ((const float*)p)[i] : __bfloat162float(((const bf16*)p)[i]);
}

// ---------------------------------------------------------------------------
__global__ void detect_kernel(const void* __restrict__ x, int* __restrict__ flag) {
    const bf16* xb = (const bf16*)x;
    int tid = threadIdx.x;
    int cnt = 0;
    for (int i = tid; i < 8192; i += 256) {
        float a = fabsf(__bfloat162float(xb[i]));
        if (!(a <= 100.0f)) cnt++;
    }
    #pragma unroll
    for (int o = 32; o > 0; o >>= 1) cnt += __shfl_down(cnt, o);
    __shared__ int sred[4];
    if ((tid & 63) == 0) sred[tid >> 6] = cnt;
    __syncthreads();
    if (tid == 0) {
        int c = sred[0] + sred[1] + sred[2] + sred[3];
        *flag = (c > 400) ? 1 : 0;
    }
}

// ---------------------------------------------------------------------------
__global__ void row_stats_kernel(const void* __restrict__ x, int x_raw,
                                 float* __restrict__ stats, const int* __restrict__ flagp) {
    int f = x_raw ? *flagp : 1;
    int row = blockIdx.x;
    int tid = threadIdx.x;
    size_t base = (size_t)row * D_DIM;
    float v0 = dload(x, base + tid, f);
    float v1 = dload(x, base + tid + 256, f);
    float s  = v0 + v1;
    float ss = v0 * v0 + v1 * v1;
    #pragma unroll
    for (int o = 32; o > 0; o >>= 1) {
        s  += __shfl_down(s, o);
        ss += __shfl_down(ss, o);
    }
    __shared__ float sred[8];
    int wv = tid >> 6, ln = tid & 63;
    if (ln == 0) { sred[wv] = s; sred[wv + 4] = ss; }
    __syncthreads();
    if (tid == 0) {
        float S  = sred[0] + sred[1] + sred[2] + sred[3];
        float SS = sred[4] + sred[5] + sred[6] + sred[7];
        float mu  = S * (1.0f / D_DIM);
        float var = SS * (1.0f / D_DIM) - mu * mu;
        stats[row * 2]     = mu;
        stats[row * 2 + 1] = rsqrtf(var + 1e-5f);
    }
}

// ---------------------------------------------------------------------------
template <bool LN>
__global__ void gemm_ln_kernel(const void* __restrict__ X, int x_raw,
                               const float* __restrict__ stats,
                               const void* __restrict__ lnw, const void* __restrict__ lnb,
                               const void* __restrict__ W, const void* __restrict__ bias,
                               float* __restrict__ Y, const int* __restrict__ flagp) {
    __shared__ float As[16][68];
    __shared__ float Bs[16][68];
    int f = *flagp;
    int xf = x_raw ? f : 1;
    int tid = threadIdx.x;
    int tx = tid & 15, ty = tid >> 4;
    int row0 = blockIdx.y * 64, col0 = blockIdx.x * 64;
    float acc[4][4] = {};
    for (int kt = 0; kt < D_DIM; kt += 16) {
        #pragma unroll
        for (int i = 0; i < 4; ++i) {
            int e = tid + i * 256;
            int r = e >> 4, kk = e & 15;
            float xv = dload(X, (size_t)(row0 + r) * D_DIM + kt + kk, xf);
            if constexpr (LN) {
                float mu = stats[(row0 + r) * 2];
                float rs = stats[(row0 + r) * 2 + 1];
                xv = (xv - mu) * rs * dload(lnw, kt + kk, f) + dload(lnb, kt + kk, f);
            }
            As[kk][r] = xv;
            int kk2 = e >> 6, c2 = e & 63;
            Bs[kk2][c2] = dload(W, (size_t)(kt + kk2) * D_DIM + col0 + c2, f);
        }
        __syncthreads();
        #pragma unroll
        for (int kk = 0; kk < 16; ++kk) {
            float4 a = *(const float4*)&As[kk][ty * 4];
            float4 b = *(const float4*)&Bs[kk][tx * 4];
            acc[0][0] += a.x * b.x; acc[0][1] += a.x * b.y; acc[0][2] += a.x * b.z; acc[0][3] += a.x * b.w;
            acc[1][0] += a.y * b.x; acc[1][1] += a.y * b.y; acc[1][2] += a.y * b.z; acc[1][3] += a.y * b.w;
            acc[2][0] += a.z * b.x; acc[2][1] += a.z * b.y; acc[2][2] += a.z * b.z; acc[2][3] += a.z * b.w;
            acc[3][0] += a.w * b.x; acc[3][1] += a.w * b.y; acc[3][2] += a.w * b.z; acc[3][3] += a.w * b.w;
        }
        __syncthreads();
    }
    #pragma unroll
    for (int i = 0; i < 4; ++i) {
        int r = row0 + ty * 4 + i;
        #pragma unroll
        for (int j = 0; j < 4; ++j) {
            int c = col0 + tx * 4 + j;
            Y[(size_t)r * D_DIM + c] = acc[i][j] + dload(bias, c, f);
        }
    }
}

// ---------------------------------------------------------------------------
// Transpose head-sliced [R][512] -> [8][64][R] (k-major operands for GEMMs).
// ---------------------------------------------------------------------------
__global__ void transpose_hd_kernel(const float* __restrict__ in, float* __restrict__ out, int R) {
    __shared__ float t[64][65];
    int h = blockIdx.y;
    int row0 = blockIdx.x * 64;
    int tid = threadIdx.x;
    #pragma unroll
    for (int i = 0; i < 4; ++i) {
        int e = i * 256 + tid;
        int r = e >> 4, c4 = (e & 15) * 4;
        float4 v = *(const float4*)&in[(size_t)(row0 + r) * D_DIM + h * 64 + c4];
        t[r][c4] = v.x; t[r][c4 + 1] = v.y; t[r][c4 + 2] = v.z; t[r][c4 + 3] = v.w;
    }
    __syncthreads();
    #pragma unroll
    for (int i = 0; i < 4; ++i) {
        int e = i * 256 + tid;
        int d = e >> 4, r4 = (e & 15) * 4;
        float4 v = { t[r4][d], t[r4 + 1][d], t[r4 + 2][d], t[r4 + 3][d] };
        *(float4*)&out[((size_t)h * 64 + d) * R + row0 + r4] = v;
    }
}

// ---------------------------------------------------------------------------
// Scores: per head GEMM M=1024 x N=8192 x K=64 from k-major qT/kT, epilogue
// fuses MaxSim over u (thread's 4 cols = one context) and 1/sqrt(dk).
// Sm[h][t][c], rows = h*1024+t.
// ---------------------------------------------------------------------------
__global__ void score_kernel(const float* __restrict__ qT, const float* __restrict__ kT,
                             float* __restrict__ Sm) {
    __shared__ float As[16][68];
    __shared__ float Bs[16][68];
    int h = blockIdx.z;
    int row0 = blockIdx.y * 64;   // tokens
    int col0 = blockIdx.x * 64;   // krows (c*4+u)
    int tid = threadIdx.x;
    int tx = tid & 15, ty = tid >> 4;
    const float* Ah = qT + (size_t)h * 64 * 1024;
    const float* Bh = kT + (size_t)h * 64 * 8192;
    float acc[4][4] = {};
    for (int kt = 0; kt < 64; kt += 16) {
        #pragma unroll
        for (int i = 0; i < 4; ++i) {
            int e = i * 256 + tid;
            int kk = e >> 6, rc = e & 63;
            As[kk][rc] = Ah[(size_t)(kt + kk) * 1024 + row0 + rc];
            Bs[kk][rc] = Bh[(size_t)(kt + kk) * 8192 + col0 + rc];
        }
        __syncthreads();
        #pragma unroll
        for (int kk = 0; kk < 16; ++kk) {
            float4 a = *(const float4*)&As[kk][ty * 4];
            float4 b = *(const float4*)&Bs[kk][tx * 4];
            acc[0][0] += a.x * b.x; acc[0][1] += a.x * b.y; acc[0][2] += a.x * b.z; acc[0][3] += a.x * b.w;
            acc[1][0] += a.y * b.x; acc[1][1] += a.y * b.y; acc[1][2] += a.y * b.z; acc[1][3] += a.y * b.w;
            acc[2][0] += a.z * b.x; acc[2][1] += a.z * b.y; acc[2][2] += a.z * b.z; acc[2][3] += a.z * b.w;
            acc[3][0] += a.w * b.x; acc[3][1] += a.w * b.y; acc[3][2] += a.w * b.z; acc[3][3] += a.w * b.w;
        }
        __syncthreads();
    }
    #pragma unroll
    for (int i = 0; i < 4; ++i) {
        float m = fmaxf(fmaxf(acc[i][0], acc[i][1]), fmaxf(acc[i][2], acc[i][3]));
        int t = row0 + ty * 4 + i;
        int c = (col0 >> 2) + tx;
        Sm[((size_t)h * 1024 + t) * C_DIM + c] = m * 0.125f;
    }
}

// ---------------------------------------------------------------------------
// Row softmax over 2048, in place. One block per (h,t) row.
// ---------------------------------------------------------------------------
__global__ void softmax_kernel(float* __restrict__ S) {
    size_t base = (size_t)blockIdx.x * C_DIM;
    int tid = threadIdx.x;
    int w = tid >> 6, lane = tid & 63;
    __shared__ float sred[8];
    float v[8];
    float m = -1e30f;
    #pragma unroll
    for (int i = 0; i < 8; ++i) { v[i] = S[base + i * 256 + tid]; m = fmaxf(m, v[i]); }
    #pragma unroll
    for (int o = 32; o > 0; o >>= 1) m = fmaxf(m, __shfl_xor(m, o));
    if (lane == 0) sred[w] = m;
    __syncthreads();
    m = fmaxf(fmaxf(sred[0], sred[1]), fmaxf(sred[2], sred[3]));
    float s = 0.0f;
    #pragma unroll
    for (int i = 0; i < 8; ++i) { v[i] = __expf(v[i] - m); s += v[i]; }
    #pragma unroll
    for (int o = 32; o > 0; o >>= 1) s += __shfl_xor(s, o);
    if (lane == 0) sred[4 + w] = s;
    __syncthreads();
    float inv = 1.0f / (sred[4] + sred[5] + sred[6] + sred[7]);
    #pragma unroll
    for (int i = 0; i < 8; ++i) S[base + i * 256 + tid] = v[i] * inv;
}

// ---------------------------------------------------------------------------
// PV: per head GEMM M=1024 x N=64 x K=2048: att[t][h*64+n] = P[h] @ V_h.
// ---------------------------------------------------------------------------
__global__ void pv_kernel(const float* __restrict__ P, const float* __restrict__ vp,
                          float* __restrict__ att) {
    __shared__ float As[16][68];
    __shared__ float Bs[16][68];
    int h = blockIdx.y;
    int row0 = blockIdx.x * 64;
    int tid = threadIdx.x;
    int tx = tid & 15, ty = tid >> 4;
    const float* Ph = P + (size_t)h * 1024 * C_DIM;
    float acc[4][4] = {};
    for (int kt = 0; kt < C_DIM; kt += 16) {
        #pragma unroll
        for (int i = 0; i < 4; ++i) {
            int e = i * 256 + tid;
            int r = e >> 4, kk = e & 15;
            As[kk][r] = Ph[(size_t)(row0 + r) * C_DIM + kt + kk];
            int kk2 = e >> 6, c2 = e & 63;
            Bs[kk2][c2] = vp[(size_t)(kt + kk2) * D_DIM + h * 64 + c2];
        }
        __syncthreads();
        #pragma unroll
        for (int kk = 0; kk < 16; ++kk) {
            float4 a = *(const float4*)&As[kk][ty * 4];
            float4 b = *(const float4*)&Bs[kk][tx * 4];
            acc[0][0] += a.x * b.x; acc[0][1] += a.x * b.y; acc[0][2] += a.x * b.z; acc[0][3] += a.x * b.w;
            acc[1][0] += a.y * b.x; acc[1][1] += a.y * b.y; acc[1][2] += a.y * b.z; acc[1][3] += a.y * b.w;
            acc[2][0] += a.z * b.x; acc[2][1] += a.z * b.y; acc[2][2] += a.z * b.z; acc[2][3] += a.z * b.w;
            acc[3][0] += a.w * b.x; acc[3][1] += a.w * b.y; acc[3][2] += a.w * b.z; acc[3][3] += a.w * b.w;
        }
        __syncthreads();
    }
    #pragma unroll
    for (int i = 0; i < 4; ++i)
        #pragma unroll
        for (int j = 0; j < 4; ++j)
            att[(size_t)(row0 + ty * 4 + i) * D_DIM + h * 64 + tx * 4 + j] = acc[i][j];
}

// ---------------------------------------------------------------------------
// Fallback flash attention (round 7) for small workspaces.
// ---------------------------------------------------------------------------
__global__ __launch_bounds__(256, 1)
void attn_flash_part(const float* __restrict__ qp, const float* __restrict__ kp,
                     const float* __restrict__ vp,
                     float* __restrict__ pacc, float* __restrict__ pm,
                     float* __restrict__ pl, int nsplit, float* __restrict__ att) {
    __shared__ float sq[TQF][DK];
    __shared__ float sp[TQF][TC + 4];
    __shared__ float sv[TC][DK];
    __shared__ float sm[TQF], sl[TQF];

    int tid = threadIdx.x;
    int b = blockIdx.x;
    int s = b & (nsplit - 1);
    int h = (b / nsplit) & 7;
    int qt = b / (nsplit * 8);
    int bt0 = qt * TQF;
    int w = tid >> 6, lane = tid & 63;

    #pragma unroll
    for (int i = 0; i < 2; ++i) {
        int e4 = i * 256 + tid;
        int tq = e4 >> 4, dq = (e4 & 15) * 4;
        *(float4*)&sq[tq][dq] = *(const float4*)&qp[(size_t)(bt0 + tq) * D_DIM + h * DK + dq];
    }
    if (tid < TQF) { sm[tid] = -1e30f; sl[tid] = 0.0f; }
    __syncthreads();

    float acc[8] = {};
    int u = tid & 3, csub = tid >> 2;
    int cs = C_DIM / nsplit;
    int ntile = cs / TC;

    for (int tile = 0; tile < ntile; ++tile) {
        int c0 = s * cs + tile * TC;
        const float* kvp = kp + ((size_t)(c0 + csub) * U_DIM + u) * D_DIM + h * DK;
        float4 kr[16];
        #pragma unroll
        for (int dd = 0; dd < 16; ++dd) kr[dd] = ((const float4*)kvp)[dd];
        #pragma unroll
        for (int i = 0; i < 4; ++i) {
            int e4 = i * 256 + tid;
            int c = e4 >> 4, dq = (e4 & 15) * 4;
            *(float4*)&sv[c][dq] = *(const float4*)&vp[(size_t)(c0 + c) * D_DIM + h * DK + dq];
        }
        #pragma unroll 4
        for (int tq = 0; tq < TQF; ++tq) {
            float sc = 0.0f;
            #pragma unroll
            for (int dd = 0; dd < 16; ++dd) {
                float4 qv = *(const float4*)&sq[tq][dd * 4];
                sc += qv.x * kr[dd].x + qv.y * kr[dd].y + qv.z * kr[dd].z + qv.w * kr[dd].w;
            }
            sc = fmaxf(sc, __shfl_xor(sc, 1));
            sc = fmaxf(sc, __shfl_xor(sc, 2));
            if (u == 0) sp[tq][csub] = sc * 0.125f;
        }
        __syncthreads();
        #pragma unroll
        for (int j = 0; j < 8; ++j) {
            int tq = w * 8 + j;
            float sval = sp[tq][lane];
            float tmax = sval;
            #pragma unroll
            for (int o = 1; o < 64; o <<= 1) tmax = fmaxf(tmax, __shfl_xor(tmax, o));
            float mold = sm[tq];
            float mnew = fmaxf(mold, tmax);
            float alpha = __expf(mold - mnew);
            float p = __expf(sval - mnew);
            float rsum = p;
            #pragma unroll
            for (int o = 1; o < 64; o <<= 1) rsum += __shfl_xor(rsum, o);
            if (lane == 0) { sm[tq] = mnew; sl[tq] = sl[tq] * alpha + rsum; }
            sp[tq][lane] = p;
            acc[j] *= alpha;
            #pragma unroll
            for (int c4 = 0; c4 < TC / 4; ++c4) {
                float4 pv = *(const float4*)&sp[tq][c4 * 4];
                acc[j] += pv.x * sv[c4 * 4 + 0][lane];
                acc[j] += pv.y * sv[c4 * 4 + 1][lane];
                acc[j] += pv.z * sv[c4 * 4 + 2][lane];
                acc[j] += pv.w * sv[c4 * 4 + 3][lane];
            }
        }
        __syncthreads();
    }

    if (nsplit == 1) {
        #pragma unroll
        for (int j = 0; j < 8; ++j) {
            int tq = w * 8 + j;
            att[(size_t)(bt0 + tq) * D_DIM + h * DK + lane] = acc[j] / sl[tq];
        }
    } else {
        int p = (qt * 8 + h) * nsplit + s;
        #pragma unroll
        for (int j = 0; j < 8; ++j) {
            int tq = w * 8 + j;
            pacc[((size_t)p * TQF + tq) * DK + lane] = acc[j];
            if (lane == 0) { pm[p * TQF + tq] = sm[tq]; pl[p * TQF + tq] = sl[tq]; }
        }
    }
}

__global__ void attn_merge_kernel(const float* __restrict__ pacc, const float* __restrict__ pm,
                                  const float* __restrict__ pl, int nsplit,
                                  float* __restrict__ att) {
    int b = blockIdx.x;
    int qt = b >> 3, h = b & 7;
    int tid = threadIdx.x;
    int w = tid >> 6, lane = tid & 63;
    int p0 = b * nsplit;
    #pragma unroll
    for (int j = 0; j < 8; ++j) {
        int tq = w * 8 + j;
        float M = -1e30f;
        for (int s = 0; s < nsplit; ++s) M = fmaxf(M, pm[(p0 + s) * TQF + tq]);
        float L = 0.0f, o = 0.0f;
        for (int s = 0; s < nsplit; ++s) {
            float e = __expf(pm[(p0 + s) * TQF + tq] - M);
            L += pl[(p0 + s) * TQF + tq] * e;
            o += pacc[((size_t)(p0 + s) * TQF + tq) * DK + lane] * e;
        }
        att[(size_t)(qt * TQF + tq) * D_DIM + h * DK + lane] = o / L;
    }
}

extern "C" void kernel_launch(void* const* d_in, const int* in_sizes, int n_in,
                              void* d_out, int out_size, void* d_ws, size_t ws_size,
                              hipStream_t stream) {
    const void* model_embed = d_in[0];
    const void* ctx_key     = d_in[1];
    const void* ctx_val     = d_in[2];
    const void* ln1w = d_in[3];  const void* ln1b = d_in[4];
    const void* ln2w = d_in[5];  const void* ln2b = d_in[6];
    const void* ln3w = d_in[7];  const void* ln3b = d_in[8];
    const void* ln4w = d_in[9];  const void* ln4b = d_in[10];
    const void* wq = d_in[11];   const void* bq = d_in[12];
    const void* wk = d_in[13];   const void* bk = d_in[14];
    const void* wv = d_in[15];   const void* bv = d_in[16];
    const void* wo = d_in[17];   const void* bo = d_in[18];
    const void* wp = d_in[19];   const void* bp = d_in[20];

    int*   flagp  = (int*)d_ws;
    float* ws     = (float*)d_ws + 16;
    float* qp     = ws;                    // 524288
    float* kp     = qp + 524288;           // 4194304
    float* vp     = kp + 4194304;          // 1048576
    float* att    = vp + 1048576;          // 524288
    float* o1     = att + 524288;          // 524288
    float* statsQ = o1 + 524288;           // 2048
    float* statsK = statsQ + 2048;         // 16384
    float* statsV = statsK + 16384;        // 4096
    float* statsO = statsV + 4096;         // 2048
    float* ext    = statsO + 2048;         // shared region (path-dependent)

    // decomposed layout in ext:
    float* qT = ext;                       // 8*64*1024  = 524288
    float* kT = qT + 524288;               // 8*64*8192  = 4194304
    float* Sm = kT + 4194304;              // 8*1024*2048 = 16777216
    // flash layout in ext:
    float* pacc = ext;                     // 2097152
    float* pm   = pacc + 2097152;          // 32768
    float* pl   = pm + 32768;              // 32768

    size_t base_fl   = 16 + 6815744 + 24576;          // floats before ext
    size_t need_dec  = (base_fl + 524288 + 4194304 + 16777216) * 4;
    size_t need_fl4  = (base_fl + 2097152 + 65536) * 4;
    int mode = (ws_size >= need_dec) ? 2 : (ws_size >= need_fl4 ? 1 : 0);

    detect_kernel<<<1, 256, 0, stream>>>(model_embed, flagp);

    row_stats_kernel<<<1024, 256, 0, stream>>>(model_embed, 1, statsQ, flagp);
    row_stats_kernel<<<8192, 256, 0, stream>>>(ctx_key, 1, statsK, flagp);
    row_stats_kernel<<<2048, 256, 0, stream>>>(ctx_val, 1, statsV, flagp);

    gemm_ln_kernel<true><<<dim3(8, 16), 256, 0, stream>>>(model_embed, 1, statsQ, ln1w, ln1b, wq, bq, qp, flagp);
    gemm_ln_kernel<true><<<dim3(8, 128), 256, 0, stream>>>(ctx_key, 1, statsK, ln2w, ln2b, wk, bk, kp, flagp);
    gemm_ln_kernel<true><<<dim3(8, 32), 256, 0, stream>>>(ctx_val, 1, statsV, ln3w, ln3b, wv, bv, vp, flagp);

    if (mode == 2) {
        transpose_hd_kernel<<<dim3(16, 8), 256, 0, stream>>>(qp, qT, 1024);
        transpose_hd_kernel<<<dim3(128, 8), 256, 0, stream>>>(kp, kT, 8192);
        score_kernel<<<dim3(128, 16, 8), 256, 0, stream>>>(qT, kT, Sm);
        softmax_kernel<<<8192, 256, 0, stream>>>(Sm);
        pv_kernel<<<dim3(16, 8), 256, 0, stream>>>(Sm, vp, att);
    } else {
        int nsplit = (mode == 1) ? 4 : 1;
        attn_flash_part<<<256 * nsplit, 256, 0, stream>>>(qp, kp, vp, pacc, pm, pl, nsplit, att);
        if (nsplit > 1)
            attn_merge_kernel<<<256, 256, 0, stream>>>(pacc, pm, pl, nsplit, att);
    }

    gemm_ln_kernel<false><<<dim3(8, 16), 256, 0, stream>>>(att, 0, nullptr, nullptr, nullptr, wo, bo, o1, flagp);
    row_stats_kernel<<<1024, 256, 0, stream>>>(o1, 0, statsO, flagp);
    gemm_ln_kernel<true><<<dim3(8, 16), 256, 0, stream>>>(o1, 0, statsO, ln4w, ln4b, wp, bp, (float*)d_out, flagp);
}

// Round 9
// 757.759 us; speedup vs baseline: 6.7497x; 1.1615x over previous
//
#include <hip/hip_runtime.h>
#include <hip/hip_bf16.h>

using bf16 = __hip_bfloat16;

#define D_DIM 512
#define C_DIM 2048
#define U_DIM 4
#define DK 64
#define TQF 32
#define TC 64

__device__ __forceinline__ float dload(const void* p, size_t i, int f) {
    return f ? ((const float*)p)[i] : __bfloat162float(((const bf16*)p)[i]);
}

// ---------------------------------------------------------------------------
__global__ void detect_kernel(const void* __restrict__ x, int* __restrict__ flag) {
    const bf16* xb = (const bf16*)x;
    int tid = threadIdx.x;
    int cnt = 0;
    for (int i = tid; i < 8192; i += 256) {
        float a = fabsf(__bfloat162float(xb[i]));
        if (!(a <= 100.0f)) cnt++;
    }
    #pragma unroll
    for (int o = 32; o > 0; o >>= 1) cnt += __shfl_down(cnt, o);
    __shared__ int sred[4];
    if ((tid & 63) == 0) sred[tid >> 6] = cnt;
    __syncthreads();
    if (tid == 0) {
        int c = sred[0] + sred[1] + sred[2] + sred[3];
        *flag = (c > 400) ? 1 : 0;
    }
}

// ---------------------------------------------------------------------------
__global__ void row_stats_kernel(const void* __restrict__ x, int x_raw,
                                 float* __restrict__ stats, const int* __restrict__ flagp) {
    int f = x_raw ? *flagp : 1;
    int row = blockIdx.x;
    int tid = threadIdx.x;
    size_t base = (size_t)row * D_DIM;
    float v0 = dload(x, base + tid, f);
    float v1 = dload(x, base + tid + 256, f);
    float s  = v0 + v1;
    float ss = v0 * v0 + v1 * v1;
    #pragma unroll
    for (int o = 32; o > 0; o >>= 1) {
        s  += __shfl_down(s, o);
        ss += __shfl_down(ss, o);
    }
    __shared__ float sred[8];
    int wv = tid >> 6, ln = tid & 63;
    if (ln == 0) { sred[wv] = s; sred[wv + 4] = ss; }
    __syncthreads();
    if (tid == 0) {
        float S  = sred[0] + sred[1] + sred[2] + sred[3];
        float SS = sred[4] + sred[5] + sred[6] + sred[7];
        float mu  = S * (1.0f / D_DIM);
        float var = SS * (1.0f / D_DIM) - mu * mu;
        stats[row * 2]     = mu;
        stats[row * 2 + 1] = rsqrtf(var + 1e-5f);
    }
}

// ---------------------------------------------------------------------------
template <bool LN>
__global__ void gemm_ln_kernel(const void* __restrict__ X, int x_raw,
                               const float* __restrict__ stats,
                               const void* __restrict__ lnw, const void* __restrict__ lnb,
                               const void* __restrict__ W, const void* __restrict__ bias,
                               float* __restrict__ Y, const int* __restrict__ flagp) {
    __shared__ float As[16][68];
    __shared__ float Bs[16][68];
    int f = *flagp;
    int xf = x_raw ? f : 1;
    int tid = threadIdx.x;
    int tx = tid & 15, ty = tid >> 4;
    int row0 = blockIdx.y * 64, col0 = blockIdx.x * 64;
    float acc[4][4] = {};
    for (int kt = 0; kt < D_DIM; kt += 16) {
        #pragma unroll
        for (int i = 0; i < 4; ++i) {
            int e = tid + i * 256;
            int r = e >> 4, kk = e & 15;
            float xv = dload(X, (size_t)(row0 + r) * D_DIM + kt + kk, xf);
            if constexpr (LN) {
                float mu = stats[(row0 + r) * 2];
                float rs = stats[(row0 + r) * 2 + 1];
                xv = (xv - mu) * rs * dload(lnw, kt + kk, f) + dload(lnb, kt + kk, f);
            }
            As[kk][r] = xv;
            int kk2 = e >> 6, c2 = e & 63;
            Bs[kk2][c2] = dload(W, (size_t)(kt + kk2) * D_DIM + col0 + c2, f);
        }
        __syncthreads();
        #pragma unroll
        for (int kk = 0; kk < 16; ++kk) {
            float4 a = *(const float4*)&As[kk][ty * 4];
            float4 b = *(const float4*)&Bs[kk][tx * 4];
            acc[0][0] += a.x * b.x; acc[0][1] += a.x * b.y; acc[0][2] += a.x * b.z; acc[0][3] += a.x * b.w;
            acc[1][0] += a.y * b.x; acc[1][1] += a.y * b.y; acc[1][2] += a.y * b.z; acc[1][3] += a.y * b.w;
            acc[2][0] += a.z * b.x; acc[2][1] += a.z * b.y; acc[2][2] += a.z * b.z; acc[2][3] += a.z * b.w;
            acc[3][0] += a.w * b.x; acc[3][1] += a.w * b.y; acc[3][2] += a.w * b.z; acc[3][3] += a.w * b.w;
        }
        __syncthreads();
    }
    #pragma unroll
    for (int i = 0; i < 4; ++i) {
        int r = row0 + ty * 4 + i;
        #pragma unroll
        for (int j = 0; j < 4; ++j) {
            int c = col0 + tx * 4 + j;
            Y[(size_t)r * D_DIM + c] = acc[i][j] + dload(bias, c, f);
        }
    }
}

// ---------------------------------------------------------------------------
// Transpose head-sliced [R][512] -> [8][64][R].
// ---------------------------------------------------------------------------
__global__ void transpose_hd_kernel(const float* __restrict__ in, float* __restrict__ out, int R) {
    __shared__ float t[64][65];
    int h = blockIdx.y;
    int row0 = blockIdx.x * 64;
    int tid = threadIdx.x;
    #pragma unroll
    for (int i = 0; i < 4; ++i) {
        int e = i * 256 + tid;
        int r = e >> 4, c4 = (e & 15) * 4;
        float4 v = *(const float4*)&in[(size_t)(row0 + r) * D_DIM + h * 64 + c4];
        t[r][c4] = v.x; t[r][c4 + 1] = v.y; t[r][c4 + 2] = v.z; t[r][c4 + 3] = v.w;
    }
    __syncthreads();
    #pragma unroll
    for (int i = 0; i < 4; ++i) {
        int e = i * 256 + tid;
        int d = e >> 4, r4 = (e & 15) * 4;
        float4 v = { t[r4][d], t[r4 + 1][d], t[r4 + 2][d], t[r4 + 3][d] };
        *(float4*)&out[((size_t)h * 64 + d) * R + row0 + r4] = v;
    }
}

// ---------------------------------------------------------------------------
// Scores: per head GEMM M=1024 x N=8192 x K=64, epilogue fuses MaxSim + scale.
// ---------------------------------------------------------------------------
__global__ void score_kernel(const float* __restrict__ qT, const float* __restrict__ kT,
                             float* __restrict__ Sm) {
    __shared__ float As[16][68];
    __shared__ float Bs[16][68];
    int h = blockIdx.z;
    int row0 = blockIdx.y * 64;
    int col0 = blockIdx.x * 64;
    int tid = threadIdx.x;
    int tx = tid & 15, ty = tid >> 4;
    const float* Ah = qT + (size_t)h * 64 * 1024;
    const float* Bh = kT + (size_t)h * 64 * 8192;
    float acc[4][4] = {};
    for (int kt = 0; kt < 64; kt += 16) {
        #pragma unroll
        for (int i = 0; i < 4; ++i) {
            int e = i * 256 + tid;
            int kk = e >> 6, rc = e & 63;
            As[kk][rc] = Ah[(size_t)(kt + kk) * 1024 + row0 + rc];
            Bs[kk][rc] = Bh[(size_t)(kt + kk) * 8192 + col0 + rc];
        }
        __syncthreads();
        #pragma unroll
        for (int kk = 0; kk < 16; ++kk) {
            float4 a = *(const float4*)&As[kk][ty * 4];
            float4 b = *(const float4*)&Bs[kk][tx * 4];
            acc[0][0] += a.x * b.x; acc[0][1] += a.x * b.y; acc[0][2] += a.x * b.z; acc[0][3] += a.x * b.w;
            acc[1][0] += a.y * b.x; acc[1][1] += a.y * b.y; acc[1][2] += a.y * b.z; acc[1][3] += a.y * b.w;
            acc[2][0] += a.z * b.x; acc[2][1] += a.z * b.y; acc[2][2] += a.z * b.z; acc[2][3] += a.z * b.w;
            acc[3][0] += a.w * b.x; acc[3][1] += a.w * b.y; acc[3][2] += a.w * b.z; acc[3][3] += a.w * b.w;
        }
        __syncthreads();
    }
    #pragma unroll
    for (int i = 0; i < 4; ++i) {
        float m = fmaxf(fmaxf(acc[i][0], acc[i][1]), fmaxf(acc[i][2], acc[i][3]));
        int t = row0 + ty * 4 + i;
        int c = (col0 >> 2) + tx;
        Sm[((size_t)h * 1024 + t) * C_DIM + c] = m * 0.125f;
    }
}

// ---------------------------------------------------------------------------
// Row softmax over 2048, in place.
// ---------------------------------------------------------------------------
__global__ void softmax_kernel(float* __restrict__ S) {
    size_t base = (size_t)blockIdx.x * C_DIM;
    int tid = threadIdx.x;
    int w = tid >> 6, lane = tid & 63;
    __shared__ float sred[8];
    float v[8];
    float m = -1e30f;
    #pragma unroll
    for (int i = 0; i < 8; ++i) { v[i] = S[base + i * 256 + tid]; m = fmaxf(m, v[i]); }
    #pragma unroll
    for (int o = 32; o > 0; o >>= 1) m = fmaxf(m, __shfl_xor(m, o));
    if (lane == 0) sred[w] = m;
    __syncthreads();
    m = fmaxf(fmaxf(sred[0], sred[1]), fmaxf(sred[2], sred[3]));
    float s = 0.0f;
    #pragma unroll
    for (int i = 0; i < 8; ++i) { v[i] = __expf(v[i] - m); s += v[i]; }
    #pragma unroll
    for (int o = 32; o > 0; o >>= 1) s += __shfl_xor(s, o);
    if (lane == 0) sred[4 + w] = s;
    __syncthreads();
    float inv = 1.0f / (sred[4] + sred[5] + sred[6] + sred[7]);
    #pragma unroll
    for (int i = 0; i < 8; ++i) S[base + i * 256 + tid] = v[i] * inv;
}

// ---------------------------------------------------------------------------
// PV split-K: grid (16 row-tiles, 8 heads, NSEG segs). Each block: 64x64
// partial over 256 k. part[seg][t][h*64+c] laid out full-width so reduce is
// a contiguous sum. Round-8 postmortem: unsplit pv was 128 blocks ->
// 5.7% occupancy, 164 us.
// ---------------------------------------------------------------------------
#define NSEG 8
__global__ void pv_part_kernel(const float* __restrict__ P, const float* __restrict__ vp,
                               float* __restrict__ part) {
    __shared__ float As[16][68];
    __shared__ float Bs[16][68];
    int h = blockIdx.y;
    int seg = blockIdx.z;
    int row0 = blockIdx.x * 64;
    int tid = threadIdx.x;
    int tx = tid & 15, ty = tid >> 4;
    const float* Ph = P + (size_t)h * 1024 * C_DIM;
    float acc[4][4] = {};
    int k0 = seg * (C_DIM / NSEG);
    for (int kt = k0; kt < k0 + C_DIM / NSEG; kt += 16) {
        #pragma unroll
        for (int i = 0; i < 4; ++i) {
            int e = i * 256 + tid;
            int r = e >> 4, kk = e & 15;
            As[kk][r] = Ph[(size_t)(row0 + r) * C_DIM + kt + kk];
            int kk2 = e >> 6, c2 = e & 63;
            Bs[kk2][c2] = vp[(size_t)(kt + kk2) * D_DIM + h * 64 + c2];
        }
        __syncthreads();
        #pragma unroll
        for (int kk = 0; kk < 16; ++kk) {
            float4 a = *(const float4*)&As[kk][ty * 4];
            float4 b = *(const float4*)&Bs[kk][tx * 4];
            acc[0][0] += a.x * b.x; acc[0][1] += a.x * b.y; acc[0][2] += a.x * b.z; acc[0][3] += a.x * b.w;
            acc[1][0] += a.y * b.x; acc[1][1] += a.y * b.y; acc[1][2] += a.y * b.z; acc[1][3] += a.y * b.w;
            acc[2][0] += a.z * b.x; acc[2][1] += a.z * b.y; acc[2][2] += a.z * b.z; acc[2][3] += a.z * b.w;
            acc[3][0] += a.w * b.x; acc[3][1] += a.w * b.y; acc[3][2] += a.w * b.z; acc[3][3] += a.w * b.w;
        }
        __syncthreads();
    }
    float* pseg = part + (size_t)seg * 1024 * D_DIM;
    #pragma unroll
    for (int i = 0; i < 4; ++i)
        #pragma unroll
        for (int j = 0; j < 4; ++j)
            pseg[(size_t)(row0 + ty * 4 + i) * D_DIM + h * 64 + tx * 4 + j] = acc[i][j];
}

__global__ void pv_reduce_kernel(const float* __restrict__ part, float* __restrict__ att) {
    size_t idx = ((size_t)blockIdx.x * 256 + threadIdx.x) * 4;
    float4 s = *(const float4*)&part[idx];
    #pragma unroll
    for (int seg = 1; seg < NSEG; ++seg) {
        float4 v = *(const float4*)&part[(size_t)seg * 1024 * D_DIM + idx];
        s.x += v.x; s.y += v.y; s.z += v.z; s.w += v.w;
    }
    *(float4*)&att[idx] = s;
}

// ---------------------------------------------------------------------------
// Fallback flash attention (round 7) for small workspaces.
// ---------------------------------------------------------------------------
__global__ __launch_bounds__(256, 1)
void attn_flash_part(const float* __restrict__ qp, const float* __restrict__ kp,
                     const float* __restrict__ vp,
                     float* __restrict__ pacc, float* __restrict__ pm,
                     float* __restrict__ pl, int nsplit, float* __restrict__ att) {
    __shared__ float sq[TQF][DK];
    __shared__ float sp[TQF][TC + 4];
    __shared__ float sv[TC][DK];
    __shared__ float sm[TQF], sl[TQF];

    int tid = threadIdx.x;
    int b = blockIdx.x;
    int s = b & (nsplit - 1);
    int h = (b / nsplit) & 7;
    int qt = b / (nsplit * 8);
    int bt0 = qt * TQF;
    int w = tid >> 6, lane = tid & 63;

    #pragma unroll
    for (int i = 0; i < 2; ++i) {
        int e4 = i * 256 + tid;
        int tq = e4 >> 4, dq = (e4 & 15) * 4;
        *(float4*)&sq[tq][dq] = *(const float4*)&qp[(size_t)(bt0 + tq) * D_DIM + h * DK + dq];
    }
    if (tid < TQF) { sm[tid] = -1e30f; sl[tid] = 0.0f; }
    __syncthreads();

    float acc[8] = {};
    int u = tid & 3, csub = tid >> 2;
    int cs = C_DIM / nsplit;
    int ntile = cs / TC;

    for (int tile = 0; tile < ntile; ++tile) {
        int c0 = s * cs + tile * TC;
        const float* kvp = kp + ((size_t)(c0 + csub) * U_DIM + u) * D_DIM + h * DK;
        float4 kr[16];
        #pragma unroll
        for (int dd = 0; dd < 16; ++dd) kr[dd] = ((const float4*)kvp)[dd];
        #pragma unroll
        for (int i = 0; i < 4; ++i) {
            int e4 = i * 256 + tid;
            int c = e4 >> 4, dq = (e4 & 15) * 4;
            *(float4*)&sv[c][dq] = *(const float4*)&vp[(size_t)(c0 + c) * D_DIM + h * DK + dq];
        }
        #pragma unroll 4
        for (int tq = 0; tq < TQF; ++tq) {
            float sc = 0.0f;
            #pragma unroll
            for (int dd = 0; dd < 16; ++dd) {
                float4 qv = *(const float4*)&sq[tq][dd * 4];
                sc += qv.x * kr[dd].x + qv.y * kr[dd].y + qv.z * kr[dd].z + qv.w * kr[dd].w;
            }
            sc = fmaxf(sc, __shfl_xor(sc, 1));
            sc = fmaxf(sc, __shfl_xor(sc, 2));
            if (u == 0) sp[tq][csub] = sc * 0.125f;
        }
        __syncthreads();
        #pragma unroll
        for (int j = 0; j < 8; ++j) {
            int tq = w * 8 + j;
            float sval = sp[tq][lane];
            float tmax = sval;
            #pragma unroll
            for (int o = 1; o < 64; o <<= 1) tmax = fmaxf(tmax, __shfl_xor(tmax, o));
            float mold = sm[tq];
            float mnew = fmaxf(mold, tmax);
            float alpha = __expf(mold - mnew);
            float p = __expf(sval - mnew);
            float rsum = p;
            #pragma unroll
            for (int o = 1; o < 64; o <<= 1) rsum += __shfl_xor(rsum, o);
            if (lane == 0) { sm[tq] = mnew; sl[tq] = sl[tq] * alpha + rsum; }
            sp[tq][lane] = p;
            acc[j] *= alpha;
            #pragma unroll
            for (int c4 = 0; c4 < TC / 4; ++c4) {
                float4 pv = *(const float4*)&sp[tq][c4 * 4];
                acc[j] += pv.x * sv[c4 * 4 + 0][lane];
                acc[j] += pv.y * sv[c4 * 4 + 1][lane];
                acc[j] += pv.z * sv[c4 * 4 + 2][lane];
                acc[j] += pv.w * sv[c4 * 4 + 3][lane];
            }
        }
        __syncthreads();
    }

    if (nsplit == 1) {
        #pragma unroll
        for (int j = 0; j < 8; ++j) {
            int tq = w * 8 + j;
            att[(size_t)(bt0 + tq) * D_DIM + h * DK + lane] = acc[j] / sl[tq];
        }
    } else {
        int p = (qt * 8 + h) * nsplit + s;
        #pragma unroll
        for (int j = 0; j < 8; ++j) {
            int tq = w * 8 + j;
            pacc[((size_t)p * TQF + tq) * DK + lane] = acc[j];
            if (lane == 0) { pm[p * TQF + tq] = sm[tq]; pl[p * TQF + tq] = sl[tq]; }
        }
    }
}

__global__ void attn_merge_kernel(const float* __restrict__ pacc, const float* __restrict__ pm,
                                  const float* __restrict__ pl, int nsplit,
                                  float* __restrict__ att) {
    int b = blockIdx.x;
    int qt = b >> 3, h = b & 7;
    int tid = threadIdx.x;
    int w = tid >> 6, lane = tid & 63;
    int p0 = b * nsplit;
    #pragma unroll
    for (int j = 0; j < 8; ++j) {
        int tq = w * 8 + j;
        float M = -1e30f;
        for (int s = 0; s < nsplit; ++s) M = fmaxf(M, pm[(p0 + s) * TQF + tq]);
        float L = 0.0f, o = 0.0f;
        for (int s = 0; s < nsplit; ++s) {
            float e = __expf(pm[(p0 + s) * TQF + tq] - M);
            L += pl[(p0 + s) * TQF + tq] * e;
            o += pacc[((size_t)(p0 + s) * TQF + tq) * DK + lane] * e;
        }
        att[(size_t)(qt * TQF + tq) * D_DIM + h * DK + lane] = o / L;
    }
}

extern "C" void kernel_launch(void* const* d_in, const int* in_sizes, int n_in,
                              void* d_out, int out_size, void* d_ws, size_t ws_size,
                              hipStream_t stream) {
    const void* model_embed = d_in[0];
    const void* ctx_key     = d_in[1];
    const void* ctx_val     = d_in[2];
    const void* ln1w = d_in[3];  const void* ln1b = d_in[4];
    const void* ln2w = d_in[5];  const void* ln2b = d_in[6];
    const void* ln3w = d_in[7];  const void* ln3b = d_in[8];
    const void* ln4w = d_in[9];  const void* ln4b = d_in[10];
    const void* wq = d_in[11];   const void* bq = d_in[12];
    const void* wk = d_in[13];   const void* bk = d_in[14];
    const void* wv = d_in[15];   const void* bv = d_in[16];
    const void* wo = d_in[17];   const void* bo = d_in[18];
    const void* wp = d_in[19];   const void* bp = d_in[20];

    int*   flagp  = (int*)d_ws;
    float* ws     = (float*)d_ws + 16;
    float* qp     = ws;                    // 524288
    float* kp     = qp + 524288;           // 4194304
    float* vp     = kp + 4194304;          // 1048576
    float* att    = vp + 1048576;          // 524288
    float* o1     = att + 524288;          // 524288
    float* statsQ = o1 + 524288;           // 2048
    float* statsK = statsQ + 2048;         // 16384
    float* statsV = statsK + 16384;        // 4096
    float* statsO = statsV + 4096;         // 2048
    float* ext    = statsO + 2048;

    // decomposed layout in ext:
    float* qT = ext;                       // 524288
    float* kT = qT + 524288;               // 4194304 (reused as pv partials)
    float* Sm = kT + 4194304;              // 16777216
    // flash layout in ext:
    float* pacc = ext;
    float* pm   = pacc + 2097152;
    float* pl   = pm + 32768;

    size_t base_fl   = 16 + 6815744 + 24576;
    size_t need_dec  = (base_fl + 524288 + 4194304 + 16777216) * 4;
    size_t need_fl4  = (base_fl + 2097152 + 65536) * 4;
    int mode = (ws_size >= need_dec) ? 2 : (ws_size >= need_fl4 ? 1 : 0);

    detect_kernel<<<1, 256, 0, stream>>>(model_embed, flagp);

    row_stats_kernel<<<1024, 256, 0, stream>>>(model_embed, 1, statsQ, flagp);
    row_stats_kernel<<<8192, 256, 0, stream>>>(ctx_key, 1, statsK, flagp);
    row_stats_kernel<<<2048, 256, 0, stream>>>(ctx_val, 1, statsV, flagp);

    gemm_ln_kernel<true><<<dim3(8, 16), 256, 0, stream>>>(model_embed, 1, statsQ, ln1w, ln1b, wq, bq, qp, flagp);
    gemm_ln_kernel<true><<<dim3(8, 128), 256, 0, stream>>>(ctx_key, 1, statsK, ln2w, ln2b, wk, bk, kp, flagp);
    gemm_ln_kernel<true><<<dim3(8, 32), 256, 0, stream>>>(ctx_val, 1, statsV, ln3w, ln3b, wv, bv, vp, flagp);

    if (mode == 2) {
        transpose_hd_kernel<<<dim3(16, 8), 256, 0, stream>>>(qp, qT, 1024);
        transpose_hd_kernel<<<dim3(128, 8), 256, 0, stream>>>(kp, kT, 8192);
        score_kernel<<<dim3(128, 16, 8), 256, 0, stream>>>(qT, kT, Sm);
        softmax_kernel<<<8192, 256, 0, stream>>>(Sm);
        // kT is dead now; reuse as 8-way pv partials (exactly 4194304 floats)
        pv_part_kernel<<<dim3(16, 8, NSEG), 256, 0, stream>>>(Sm, vp, kT);
        pv_reduce_kernel<<<512, 256, 0, stream>>>(kT, att);
    } else {
        int nsplit = (mode == 1) ? 4 : 1;
        attn_flash_part<<<256 * nsplit, 256, 0, stream>>>(qp, kp, vp, pacc, pm, pl, nsplit, att);
        if (nsplit > 1)
            attn_merge_kernel<<<256, 256, 0, stream>>>(pacc, pm, pl, nsplit, att);
    }

    gemm_ln_kernel<false><<<dim3(8, 16), 256, 0, stream>>>(att, 0, nullptr, nullptr, nullptr, wo, bo, o1, flagp);
    row_stats_kernel<<<1024, 256, 0, stream>>>(o1, 0, statsO, flagp);
    gemm_ln_kernel<true><<<dim3(8, 16), 256, 0, stream>>>(o1, 0, statsO, ln4w, ln4b, wp, bp, (float*)d_out, flagp);
}

// Round 10
// 698.493 us; speedup vs baseline: 7.3224x; 1.0848x over previous
//
#include <hip/hip_runtime.h>
#include <hip/hip_bf16.h>

using bf16 = __hip_bfloat16;

#define D_DIM 512
#define C_DIM 2048
#define U_DIM 4
#define DK 64
#define TQF 32
#define TC 64

typedef __attribute__((ext_vector_type(8))) short short8;
typedef __attribute__((ext_vector_type(4))) float f32x4;

__device__ __forceinline__ float dload(const void* p, size_t i, int f) {
    return f ? ((const float*)p)[i] : __bfloat162float(((const bf16*)p)[i]);
}
__device__ __forceinline__ unsigned f2bf(float x) {
    bf16 b = __float2bfloat16(x);
    return (unsigned)*(unsigned short*)&b;
}

// ---------------------------------------------------------------------------
__global__ void detect_kernel(const void* __restrict__ x, int* __restrict__ flag) {
    const bf16* xb = (const bf16*)x;
    int tid = threadIdx.x;
    int cnt = 0;
    for (int i = tid; i < 8192; i += 256) {
        float a = fabsf(__bfloat162float(xb[i]));
        if (!(a <= 100.0f)) cnt++;
    }
    #pragma unroll
    for (int o = 32; o > 0; o >>= 1) cnt += __shfl_down(cnt, o);
    __shared__ int sred[4];
    if ((tid & 63) == 0) sred[tid >> 6] = cnt;
    __syncthreads();
    if (tid == 0) {
        int c = sred[0] + sred[1] + sred[2] + sred[3];
        *flag = (c > 400) ? 1 : 0;
    }
}

// ---------------------------------------------------------------------------
__global__ void row_stats_kernel(const void* __restrict__ x, int x_raw,
                                 float* __restrict__ stats, const int* __restrict__ flagp) {
    int f = x_raw ? *flagp : 1;
    int row = blockIdx.x;
    int tid = threadIdx.x;
    size_t base = (size_t)row * D_DIM;
    float v0 = dload(x, base + tid, f);
    float v1 = dload(x, base + tid + 256, f);
    float s  = v0 + v1;
    float ss = v0 * v0 + v1 * v1;
    #pragma unroll
    for (int o = 32; o > 0; o >>= 1) {
        s  += __shfl_down(s, o);
        ss += __shfl_down(ss, o);
    }
    __shared__ float sred[8];
    int wv = tid >> 6, ln = tid & 63;
    if (ln == 0) { sred[wv] = s; sred[wv + 4] = ss; }
    __syncthreads();
    if (tid == 0) {
        float S  = sred[0] + sred[1] + sred[2] + sred[3];
        float SS = sred[4] + sred[5] + sred[6] + sred[7];
        float mu  = S * (1.0f / D_DIM);
        float var = SS * (1.0f / D_DIM) - mu * mu;
        stats[row * 2]     = mu;
        stats[row * 2 + 1] = rsqrtf(var + 1e-5f);
    }
}

// ---------------------------------------------------------------------------
template <bool LN>
__global__ void gemm_ln_kernel(const void* __restrict__ X, int x_raw,
                               const float* __restrict__ stats,
                               const void* __restrict__ lnw, const void* __restrict__ lnb,
                               const void* __restrict__ W, const void* __restrict__ bias,
                               float* __restrict__ Y, const int* __restrict__ flagp) {
    __shared__ float As[16][68];
    __shared__ float Bs[16][68];
    int f = *flagp;
    int xf = x_raw ? f : 1;
    int tid = threadIdx.x;
    int tx = tid & 15, ty = tid >> 4;
    int row0 = blockIdx.y * 64, col0 = blockIdx.x * 64;
    float acc[4][4] = {};
    for (int kt = 0; kt < D_DIM; kt += 16) {
        #pragma unroll
        for (int i = 0; i < 4; ++i) {
            int e = tid + i * 256;
            int r = e >> 4, kk = e & 15;
            float xv = dload(X, (size_t)(row0 + r) * D_DIM + kt + kk, xf);
            if constexpr (LN) {
                float mu = stats[(row0 + r) * 2];
                float rs = stats[(row0 + r) * 2 + 1];
                xv = (xv - mu) * rs * dload(lnw, kt + kk, f) + dload(lnb, kt + kk, f);
            }
            As[kk][r] = xv;
            int kk2 = e >> 6, c2 = e & 63;
            Bs[kk2][c2] = dload(W, (size_t)(kt + kk2) * D_DIM + col0 + c2, f);
        }
        __syncthreads();
        #pragma unroll
        for (int kk = 0; kk < 16; ++kk) {
            float4 a = *(const float4*)&As[kk][ty * 4];
            float4 b = *(const float4*)&Bs[kk][tx * 4];
            acc[0][0] += a.x * b.x; acc[0][1] += a.x * b.y; acc[0][2] += a.x * b.z; acc[0][3] += a.x * b.w;
            acc[1][0] += a.y * b.x; acc[1][1] += a.y * b.y; acc[1][2] += a.y * b.z; acc[1][3] += a.y * b.w;
            acc[2][0] += a.z * b.x; acc[2][1] += a.z * b.y; acc[2][2] += a.z * b.z; acc[2][3] += a.z * b.w;
            acc[3][0] += a.w * b.x; acc[3][1] += a.w * b.y; acc[3][2] += a.w * b.z; acc[3][3] += a.w * b.w;
        }
        __syncthreads();
    }
    #pragma unroll
    for (int i = 0; i < 4; ++i) {
        int r = row0 + ty * 4 + i;
        #pragma unroll
        for (int j = 0; j < 4; ++j) {
            int c = col0 + tx * 4 + j;
            Y[(size_t)r * D_DIM + c] = acc[i][j] + dload(bias, c, f);
        }
    }
}

// ---------------------------------------------------------------------------
// Pack head-sliced fp32 [R][512] into bf16 MFMA fragments:
// out frag block per (h, tt=row/16, kb=k/8): 16 m x 8 k bf16 (16B per m).
// uint4 index = ((h*(R/16)+tt)*8 + kb)*16 + m.  Lane then loads its A/B
// fragment for mfma_16x16x32_bf16 with ONE coalesced 16B global read.
// ---------------------------------------------------------------------------
__global__ void pack_frag_kernel(const float* __restrict__ in, uint4* __restrict__ out, int R) {
    int h = blockIdx.y;
    int tid = threadIdx.x;
    int kb = tid & 7;
    int r  = blockIdx.x * 32 + (tid >> 3);
    int tt = r >> 4, m = r & 15;
    const float* src = in + (size_t)r * D_DIM + h * 64 + kb * 8;
    float4 v0 = *(const float4*)src;
    float4 v1 = *(const float4*)(src + 4);
    uint4 w;
    w.x = f2bf(v0.x) | (f2bf(v0.y) << 16);
    w.y = f2bf(v0.z) | (f2bf(v0.w) << 16);
    w.z = f2bf(v1.x) | (f2bf(v1.y) << 16);
    w.w = f2bf(v1.z) | (f2bf(v1.w) << 16);
    out[(((size_t)h * (R >> 4) + tt) * 8 + kb) * 16 + m] = w;
}

// ---------------------------------------------------------------------------
// Scores via MFMA bf16: per head M=1024 x N=8192 x K=64, no LDS.
// Wave w covers tokens tt*16..+15, cols blockIdx.x*64..+63 (4 n-tiles).
// Epilogue: MaxSim over u (adjacent C/D cols) via shfl_xor 1,2 + 0.125 scale.
// C/D layout: col=lane&15, row=(lane>>4)*4+reg  [m89/m91].
// ---------------------------------------------------------------------------
__global__ __launch_bounds__(256)
void score_mfma_kernel(const uint4* __restrict__ qf, const uint4* __restrict__ kf,
                       float* __restrict__ Sm) {
    int h = blockIdx.z;
    int w = threadIdx.x >> 6, lane = threadIdx.x & 63;
    int tt  = blockIdx.y * 4 + w;      // 16-token tile (0..63)
    int nt0 = blockIdx.x * 4;          // first 16-n tile (0..511)
    int q = lane >> 4, nm = lane & 15;

    short8 a0 = *(const short8*)(qf + (((size_t)h * 64 + tt) * 8 + q) * 16 + nm);
    short8 a1 = *(const short8*)(qf + (((size_t)h * 64 + tt) * 8 + 4 + q) * 16 + nm);

    #pragma unroll
    for (int i = 0; i < 4; ++i) {
        int nt = nt0 + i;
        short8 b0 = *(const short8*)(kf + (((size_t)h * 512 + nt) * 8 + q) * 16 + nm);
        short8 b1 = *(const short8*)(kf + (((size_t)h * 512 + nt) * 8 + 4 + q) * 16 + nm);
        f32x4 acc = {0.0f, 0.0f, 0.0f, 0.0f};
        acc = __builtin_amdgcn_mfma_f32_16x16x32_bf16(a0, b0, acc, 0, 0, 0);
        acc = __builtin_amdgcn_mfma_f32_16x16x32_bf16(a1, b1, acc, 0, 0, 0);
        #pragma unroll
        for (int r = 0; r < 4; ++r) {
            float v = acc[r];
            v = fmaxf(v, __shfl_xor(v, 1));
            v = fmaxf(v, __shfl_xor(v, 2));
            if ((lane & 3) == 0) {
                int t = tt * 16 + q * 4 + r;
                int c = (nt * 16 + nm) >> 2;
                Sm[((size_t)h * 1024 + t) * C_DIM + c] = v * 0.125f;
            }
        }
    }
}

// ---------------------------------------------------------------------------
// Row softmax over 2048, in place.
// ---------------------------------------------------------------------------
__global__ void softmax_kernel(float* __restrict__ S) {
    size_t base = (size_t)blockIdx.x * C_DIM;
    int tid = threadIdx.x;
    int w = tid >> 6, lane = tid & 63;
    __shared__ float sred[8];
    float v[8];
    float m = -1e30f;
    #pragma unroll
    for (int i = 0; i < 8; ++i) { v[i] = S[base + i * 256 + tid]; m = fmaxf(m, v[i]); }
    #pragma unroll
    for (int o = 32; o > 0; o >>= 1) m = fmaxf(m, __shfl_xor(m, o));
    if (lane == 0) sred[w] = m;
    __syncthreads();
    m = fmaxf(fmaxf(sred[0], sred[1]), fmaxf(sred[2], sred[3]));
    float s = 0.0f;
    #pragma unroll
    for (int i = 0; i < 8; ++i) { v[i] = __expf(v[i] - m); s += v[i]; }
    #pragma unroll
    for (int o = 32; o > 0; o >>= 1) s += __shfl_xor(s, o);
    if (lane == 0) sred[4 + w] = s;
    __syncthreads();
    float inv = 1.0f / (sred[4] + sred[5] + sred[6] + sred[7]);
    #pragma unroll
    for (int i = 0; i < 8; ++i) S[base + i * 256 + tid] = v[i] * inv;
}

// ---------------------------------------------------------------------------
// PV split-K (round 8): grid (16 row-tiles, 8 heads, NSEG segs).
// ---------------------------------------------------------------------------
#define NSEG 8
__global__ void pv_part_kernel(const float* __restrict__ P, const float* __restrict__ vp,
                               float* __restrict__ part) {
    __shared__ float As[16][68];
    __shared__ float Bs[16][68];
    int h = blockIdx.y;
    int seg = blockIdx.z;
    int row0 = blockIdx.x * 64;
    int tid = threadIdx.x;
    int tx = tid & 15, ty = tid >> 4;
    const float* Ph = P + (size_t)h * 1024 * C_DIM;
    float acc[4][4] = {};
    int k0 = seg * (C_DIM / NSEG);
    for (int kt = k0; kt < k0 + C_DIM / NSEG; kt += 16) {
        #pragma unroll
        for (int i = 0; i < 4; ++i) {
            int e = i * 256 + tid;
            int r = e >> 4, kk = e & 15;
            As[kk][r] = Ph[(size_t)(row0 + r) * C_DIM + kt + kk];
            int kk2 = e >> 6, c2 = e & 63;
            Bs[kk2][c2] = vp[(size_t)(kt + kk2) * D_DIM + h * 64 + c2];
        }
        __syncthreads();
        #pragma unroll
        for (int kk = 0; kk < 16; ++kk) {
            float4 a = *(const float4*)&As[kk][ty * 4];
            float4 b = *(const float4*)&Bs[kk][tx * 4];
            acc[0][0] += a.x * b.x; acc[0][1] += a.x * b.y; acc[0][2] += a.x * b.z; acc[0][3] += a.x * b.w;
            acc[1][0] += a.y * b.x; acc[1][1] += a.y * b.y; acc[1][2] += a.y * b.z; acc[1][3] += a.y * b.w;
            acc[2][0] += a.z * b.x; acc[2][1] += a.z * b.y; acc[2][2] += a.z * b.z; acc[2][3] += a.z * b.w;
            acc[3][0] += a.w * b.x; acc[3][1] += a.w * b.y; acc[3][2] += a.w * b.z; acc[3][3] += a.w * b.w;
        }
        __syncthreads();
    }
    float* pseg = part + (size_t)seg * 1024 * D_DIM;
    #pragma unroll
    for (int i = 0; i < 4; ++i)
        #pragma unroll
        for (int j = 0; j < 4; ++j)
            pseg[(size_t)(row0 + ty * 4 + i) * D_DIM + h * 64 + tx * 4 + j] = acc[i][j];
}

__global__ void pv_reduce_kernel(const float* __restrict__ part, float* __restrict__ att) {
    size_t idx = ((size_t)blockIdx.x * 256 + threadIdx.x) * 4;
    float4 s = *(const float4*)&part[idx];
    #pragma unroll
    for (int seg = 1; seg < NSEG; ++seg) {
        float4 v = *(const float4*)&part[(size_t)seg * 1024 * D_DIM + idx];
        s.x += v.x; s.y += v.y; s.z += v.z; s.w += v.w;
    }
    *(float4*)&att[idx] = s;
}

// ---------------------------------------------------------------------------
// Fallback flash attention (round 7) for small workspaces.
// ---------------------------------------------------------------------------
__global__ __launch_bounds__(256, 1)
void attn_flash_part(const float* __restrict__ qp, const float* __restrict__ kp,
                     const float* __restrict__ vp,
                     float* __restrict__ pacc, float* __restrict__ pm,
                     float* __restrict__ pl, int nsplit, float* __restrict__ att) {
    __shared__ float sq[TQF][DK];
    __shared__ float sp[TQF][TC + 4];
    __shared__ float sv[TC][DK];
    __shared__ float sm[TQF], sl[TQF];

    int tid = threadIdx.x;
    int b = blockIdx.x;
    int s = b & (nsplit - 1);
    int h = (b / nsplit) & 7;
    int qt = b / (nsplit * 8);
    int bt0 = qt * TQF;
    int w = tid >> 6, lane = tid & 63;

    #pragma unroll
    for (int i = 0; i < 2; ++i) {
        int e4 = i * 256 + tid;
        int tq = e4 >> 4, dq = (e4 & 15) * 4;
        *(float4*)&sq[tq][dq] = *(const float4*)&qp[(size_t)(bt0 + tq) * D_DIM + h * DK + dq];
    }
    if (tid < TQF) { sm[tid] = -1e30f; sl[tid] = 0.0f; }
    __syncthreads();

    float acc[8] = {};
    int u = tid & 3, csub = tid >> 2;
    int cs = C_DIM / nsplit;
    int ntile = cs / TC;

    for (int tile = 0; tile < ntile; ++tile) {
        int c0 = s * cs + tile * TC;
        const float* kvp = kp + ((size_t)(c0 + csub) * U_DIM + u) * D_DIM + h * DK;
        float4 kr[16];
        #pragma unroll
        for (int dd = 0; dd < 16; ++dd) kr[dd] = ((const float4*)kvp)[dd];
        #pragma unroll
        for (int i = 0; i < 4; ++i) {
            int e4 = i * 256 + tid;
            int c = e4 >> 4, dq = (e4 & 15) * 4;
            *(float4*)&sv[c][dq] = *(const float4*)&vp[(size_t)(c0 + c) * D_DIM + h * DK + dq];
        }
        #pragma unroll 4
        for (int tq = 0; tq < TQF; ++tq) {
            float sc = 0.0f;
            #pragma unroll
            for (int dd = 0; dd < 16; ++dd) {
                float4 qv = *(const float4*)&sq[tq][dd * 4];
                sc += qv.x * kr[dd].x + qv.y * kr[dd].y + qv.z * kr[dd].z + qv.w * kr[dd].w;
            }
            sc = fmaxf(sc, __shfl_xor(sc, 1));
            sc = fmaxf(sc, __shfl_xor(sc, 2));
            if (u == 0) sp[tq][csub] = sc * 0.125f;
        }
        __syncthreads();
        #pragma unroll
        for (int j = 0; j < 8; ++j) {
            int tq = w * 8 + j;
            float sval = sp[tq][lane];
            float tmax = sval;
            #pragma unroll
            for (int o = 1; o < 64; o <<= 1) tmax = fmaxf(tmax, __shfl_xor(tmax, o));
            float mold = sm[tq];
            float mnew = fmaxf(mold, tmax);
            float alpha = __expf(mold - mnew);
            float p = __expf(sval - mnew);
            float rsum = p;
            #pragma unroll
            for (int o = 1; o < 64; o <<= 1) rsum += __shfl_xor(rsum, o);
            if (lane == 0) { sm[tq] = mnew; sl[tq] = sl[tq] * alpha + rsum; }
            sp[tq][lane] = p;
            acc[j] *= alpha;
            #pragma unroll
            for (int c4 = 0; c4 < TC / 4; ++c4) {
                float4 pv = *(const float4*)&sp[tq][c4 * 4];
                acc[j] += pv.x * sv[c4 * 4 + 0][lane];
                acc[j] += pv.y * sv[c4 * 4 + 1][lane];
                acc[j] += pv.z * sv[c4 * 4 + 2][lane];
                acc[j] += pv.w * sv[c4 * 4 + 3][lane];
            }
        }
        __syncthreads();
    }

    if (nsplit == 1) {
        #pragma unroll
        for (int j = 0; j < 8; ++j) {
            int tq = w * 8 + j;
            att[(size_t)(bt0 + tq) * D_DIM + h * DK + lane] = acc[j] / sl[tq];
        }
    } else {
        int p = (qt * 8 + h) * nsplit + s;
        #pragma unroll
        for (int j = 0; j < 8; ++j) {
            int tq = w * 8 + j;
            pacc[((size_t)p * TQF + tq) * DK + lane] = acc[j];
            if (lane == 0) { pm[p * TQF + tq] = sm[tq]; pl[p * TQF + tq] = sl[tq]; }
        }
    }
}

__global__ void attn_merge_kernel(const float* __restrict__ pacc, const float* __restrict__ pm,
                                  const float* __restrict__ pl, int nsplit,
                                  float* __restrict__ att) {
    int b = blockIdx.x;
    int qt = b >> 3, h = b & 7;
    int tid = threadIdx.x;
    int w = tid >> 6, lane = tid & 63;
    int p0 = b * nsplit;
    #pragma unroll
    for (int j = 0; j < 8; ++j) {
        int tq = w * 8 + j;
        float M = -1e30f;
        for (int s = 0; s < nsplit; ++s) M = fmaxf(M, pm[(p0 + s) * TQF + tq]);
        float L = 0.0f, o = 0.0f;
        for (int s = 0; s < nsplit; ++s) {
            float e = __expf(pm[(p0 + s) * TQF + tq] - M);
            L += pl[(p0 + s) * TQF + tq] * e;
            o += pacc[((size_t)(p0 + s) * TQF + tq) * DK + lane] * e;
        }
        att[(size_t)(qt * TQF + tq) * D_DIM + h * DK + lane] = o / L;
    }
}

extern "C" void kernel_launch(void* const* d_in, const int* in_sizes, int n_in,
                              void* d_out, int out_size, void* d_ws, size_t ws_size,
                              hipStream_t stream) {
    const void* model_embed = d_in[0];
    const void* ctx_key     = d_in[1];
    const void* ctx_val     = d_in[2];
    const void* ln1w = d_in[3];  const void* ln1b = d_in[4];
    const void* ln2w = d_in[5];  const void* ln2b = d_in[6];
    const void* ln3w = d_in[7];  const void* ln3b = d_in[8];
    const void* ln4w = d_in[9];  const void* ln4b = d_in[10];
    const void* wq = d_in[11];   const void* bq = d_in[12];
    const void* wk = d_in[13];   const void* bk = d_in[14];
    const void* wv = d_in[15];   const void* bv = d_in[16];
    const void* wo = d_in[17];   const void* bo = d_in[18];
    const void* wp = d_in[19];   const void* bp = d_in[20];

    int*   flagp  = (int*)d_ws;
    float* ws     = (float*)d_ws + 16;
    float* qp     = ws;                    // 524288
    float* kp     = qp + 524288;           // 4194304
    float* vp     = kp + 4194304;          // 1048576
    float* att    = vp + 1048576;          // 524288
    float* o1     = att + 524288;          // 524288
    float* statsQ = o1 + 524288;           // 2048
    float* statsK = statsQ + 2048;         // 16384
    float* statsV = statsK + 16384;        // 4096
    float* statsO = statsV + 4096;         // 2048
    float* ext    = statsO + 2048;

    // decomposed layout in ext (qf/kf bf16 frags fit inside old qT/kT regions):
    float* qT = ext;                       // 524288 floats (qf uses 1 MB)
    float* kT = qT + 524288;               // 4194304 floats (kf uses 8 MB; reused as pv partials)
    float* Sm = kT + 4194304;              // 16777216
    // flash layout in ext:
    float* pacc = ext;
    float* pm   = pacc + 2097152;
    float* pl   = pm + 32768;

    size_t base_fl   = 16 + 6815744 + 24576;
    size_t need_dec  = (base_fl + 524288 + 4194304 + 16777216) * 4;
    size_t need_fl4  = (base_fl + 2097152 + 65536) * 4;
    int mode = (ws_size >= need_dec) ? 2 : (ws_size >= need_fl4 ? 1 : 0);

    detect_kernel<<<1, 256, 0, stream>>>(model_embed, flagp);

    row_stats_kernel<<<1024, 256, 0, stream>>>(model_embed, 1, statsQ, flagp);
    row_stats_kernel<<<8192, 256, 0, stream>>>(ctx_key, 1, statsK, flagp);
    row_stats_kernel<<<2048, 256, 0, stream>>>(ctx_val, 1, statsV, flagp);

    gemm_ln_kernel<true><<<dim3(8, 16), 256, 0, stream>>>(model_embed, 1, statsQ, ln1w, ln1b, wq, bq, qp, flagp);
    gemm_ln_kernel<true><<<dim3(8, 128), 256, 0, stream>>>(ctx_key, 1, statsK, ln2w, ln2b, wk, bk, kp, flagp);
    gemm_ln_kernel<true><<<dim3(8, 32), 256, 0, stream>>>(ctx_val, 1, statsV, ln3w, ln3b, wv, bv, vp, flagp);

    if (mode == 2) {
        uint4* qf = (uint4*)qT;
        uint4* kf = (uint4*)kT;
        pack_frag_kernel<<<dim3(32, 8), 256, 0, stream>>>(qp, qf, 1024);
        pack_frag_kernel<<<dim3(256, 8), 256, 0, stream>>>(kp, kf, 8192);
        score_mfma_kernel<<<dim3(128, 16, 8), 256, 0, stream>>>(qf, kf, Sm);
        softmax_kernel<<<8192, 256, 0, stream>>>(Sm);
        // kf is dead now; reuse region as 8-way pv partials (4194304 floats)
        pv_part_kernel<<<dim3(16, 8, NSEG), 256, 0, stream>>>(Sm, vp, kT);
        pv_reduce_kernel<<<512, 256, 0, stream>>>(kT, att);
    } else {
        int nsplit = (mode == 1) ? 4 : 1;
        attn_flash_part<<<256 * nsplit, 256, 0, stream>>>(qp, kp, vp, pacc, pm, pl, nsplit, att);
        if (nsplit > 1)
            attn_merge_kernel<<<256, 256, 0, stream>>>(pacc, pm, pl, nsplit, att);
    }

    gemm_ln_kernel<false><<<dim3(8, 16), 256, 0, stream>>>(att, 0, nullptr, nullptr, nullptr, wo, bo, o1, flagp);
    row_stats_kernel<<<1024, 256, 0, stream>>>(o1, 0, statsO, flagp);
    gemm_ln_kernel<true><<<dim3(8, 16), 256, 0, stream>>>(o1, 0, statsO, ln4w, ln4b, wp, bp, (float*)d_out, flagp);
}

// Round 11
// 380.214 us; speedup vs baseline: 13.4520x; 1.8371x over previous
//
#include <hip/hip_runtime.h>
#include <hip/hip_bf16.h>

using bf16 = __hip_bfloat16;

#define D_DIM 512
#define C_DIM 2048
#define U_DIM 4
#define DK 64
#define TQF 32
#define TC 64

typedef __attribute__((ext_vector_type(8))) short short8;
typedef __attribute__((ext_vector_type(4))) float f32x4;

__device__ __forceinline__ float dload(const void* p, size_t i, int f) {
    return f ? ((const float*)p)[i] : __bfloat162float(((const bf16*)p)[i]);
}
__device__ __forceinline__ unsigned f2bf(float x) {
    bf16 b = __float2bfloat16(x);
    return (unsigned)*(unsigned short*)&b;
}

// ---------------------------------------------------------------------------
__global__ void detect_kernel(const void* __restrict__ x, int* __restrict__ flag) {
    const bf16* xb = (const bf16*)x;
    int tid = threadIdx.x;
    int cnt = 0;
    for (int i = tid; i < 8192; i += 256) {
        float a = fabsf(__bfloat162float(xb[i]));
        if (!(a <= 100.0f)) cnt++;
    }
    #pragma unroll
    for (int o = 32; o > 0; o >>= 1) cnt += __shfl_down(cnt, o);
    __shared__ int sred[4];
    if ((tid & 63) == 0) sred[tid >> 6] = cnt;
    __syncthreads();
    if (tid == 0) {
        int c = sred[0] + sred[1] + sred[2] + sred[3];
        *flag = (c > 400) ? 1 : 0;
    }
}

// ---------------------------------------------------------------------------
__global__ void row_stats_kernel(const void* __restrict__ x, int x_raw,
                                 float* __restrict__ stats, const int* __restrict__ flagp) {
    int f = x_raw ? *flagp : 1;
    int row = blockIdx.x;
    int tid = threadIdx.x;
    size_t base = (size_t)row * D_DIM;
    float v0 = dload(x, base + tid, f);
    float v1 = dload(x, base + tid + 256, f);
    float s  = v0 + v1;
    float ss = v0 * v0 + v1 * v1;
    #pragma unroll
    for (int o = 32; o > 0; o >>= 1) {
        s  += __shfl_down(s, o);
        ss += __shfl_down(ss, o);
    }
    __shared__ float sred[8];
    int wv = tid >> 6, ln = tid & 63;
    if (ln == 0) { sred[wv] = s; sred[wv + 4] = ss; }
    __syncthreads();
    if (tid == 0) {
        float S  = sred[0] + sred[1] + sred[2] + sred[3];
        float SS = sred[4] + sred[5] + sred[6] + sred[7];
        float mu  = S * (1.0f / D_DIM);
        float var = SS * (1.0f / D_DIM) - mu * mu;
        stats[row * 2]     = mu;
        stats[row * 2 + 1] = rsqrtf(var + 1e-5f);
    }
}

// ---------------------------------------------------------------------------
// fp32 fallback GEMM (mode<3).
// ---------------------------------------------------------------------------
template <bool LN>
__global__ void gemm_ln_kernel(const void* __restrict__ X, int x_raw,
                               const float* __restrict__ stats,
                               const void* __restrict__ lnw, const void* __restrict__ lnb,
                               const void* __restrict__ W, const void* __restrict__ bias,
                               float* __restrict__ Y, const int* __restrict__ flagp) {
    __shared__ float As[16][68];
    __shared__ float Bs[16][68];
    int f = *flagp;
    int xf = x_raw ? f : 1;
    int tid = threadIdx.x;
    int tx = tid & 15, ty = tid >> 4;
    int row0 = blockIdx.y * 64, col0 = blockIdx.x * 64;
    float acc[4][4] = {};
    for (int kt = 0; kt < D_DIM; kt += 16) {
        #pragma unroll
        for (int i = 0; i < 4; ++i) {
            int e = tid + i * 256;
            int r = e >> 4, kk = e & 15;
            float xv = dload(X, (size_t)(row0 + r) * D_DIM + kt + kk, xf);
            if constexpr (LN) {
                float mu = stats[(row0 + r) * 2];
                float rs = stats[(row0 + r) * 2 + 1];
                xv = (xv - mu) * rs * dload(lnw, kt + kk, f) + dload(lnb, kt + kk, f);
            }
            As[kk][r] = xv;
            int kk2 = e >> 6, c2 = e & 63;
            Bs[kk2][c2] = dload(W, (size_t)(kt + kk2) * D_DIM + col0 + c2, f);
        }
        __syncthreads();
        #pragma unroll
        for (int kk = 0; kk < 16; ++kk) {
            float4 a = *(const float4*)&As[kk][ty * 4];
            float4 b = *(const float4*)&Bs[kk][tx * 4];
            acc[0][0] += a.x * b.x; acc[0][1] += a.x * b.y; acc[0][2] += a.x * b.z; acc[0][3] += a.x * b.w;
            acc[1][0] += a.y * b.x; acc[1][1] += a.y * b.y; acc[1][2] += a.y * b.z; acc[1][3] += a.y * b.w;
            acc[2][0] += a.z * b.x; acc[2][1] += a.z * b.y; acc[2][2] += a.z * b.z; acc[2][3] += a.z * b.w;
            acc[3][0] += a.w * b.x; acc[3][1] += a.w * b.y; acc[3][2] += a.w * b.z; acc[3][3] += a.w * b.w;
        }
        __syncthreads();
    }
    #pragma unroll
    for (int i = 0; i < 4; ++i) {
        int r = row0 + ty * 4 + i;
        #pragma unroll
        for (int j = 0; j < 4; ++j) {
            int c = col0 + tx * 4 + j;
            Y[(size_t)r * D_DIM + c] = acc[i][j] + dload(bias, c, f);
        }
    }
}

// ---------------------------------------------------------------------------
// Pack activation [M][512] (optional fused LN) into bf16 A-fragments:
// Af[(tt*64 + kb)*16 + m] = 16B of row tt*16+m, k = kb*8..+7.
// ---------------------------------------------------------------------------
template <bool LN>
__global__ void pack_a_kernel(const void* __restrict__ X, int x_raw,
                              const float* __restrict__ stats,
                              const void* __restrict__ lnw, const void* __restrict__ lnb,
                              uint4* __restrict__ Af, const int* __restrict__ flagp) {
    int f = *flagp;
    int xf = x_raw ? f : 1;
    int tt = blockIdx.x;
    int m = threadIdx.x >> 4;
    int kbL = threadIdx.x & 15;
    int row = tt * 16 + m;
    float mu = 0.0f, rs = 1.0f;
    if (LN) { mu = stats[row * 2]; rs = stats[row * 2 + 1]; }
    #pragma unroll
    for (int i = 0; i < 4; ++i) {
        int kb = kbL + i * 16;
        unsigned pk[4];
        #pragma unroll
        for (int jp = 0; jp < 4; ++jp) {
            int k0 = kb * 8 + jp * 2;
            float v0 = dload(X, (size_t)row * D_DIM + k0, xf);
            float v1 = dload(X, (size_t)row * D_DIM + k0 + 1, xf);
            if (LN) {
                v0 = (v0 - mu) * rs * dload(lnw, k0, f) + dload(lnb, k0, f);
                v1 = (v1 - mu) * rs * dload(lnw, k0 + 1, f) + dload(lnb, k0 + 1, f);
            }
            pk[jp] = f2bf(v0) | (f2bf(v1) << 16);
        }
        uint4 wv = {pk[0], pk[1], pk[2], pk[3]};
        Af[((size_t)tt * 64 + kb) * 16 + m] = wv;
    }
}

// ---------------------------------------------------------------------------
// Pack weight W[k=512][n=512] into bf16 B-fragments (transposed):
// Bf[(nt*64 + kb)*16 + n] = 16B of col nt*16+n, k = kb*8..+7.
// ---------------------------------------------------------------------------
__global__ void pack_w_kernel(const void* __restrict__ W, uint4* __restrict__ Bf,
                              const int* __restrict__ flagp) {
    __shared__ float t[64][65];
    int f = *flagp;
    int b = blockIdx.x;
    int n0 = (b & 7) * 64, k0 = (b >> 3) * 64;
    int tid = threadIdx.x;
    for (int i = 0; i < 16; ++i) {
        int e = i * 256 + tid;
        int r = e >> 6, c = e & 63;
        t[r][c] = dload(W, (size_t)(k0 + r) * D_DIM + n0 + c, f);
    }
    __syncthreads();
    #pragma unroll
    for (int i = 0; i < 2; ++i) {
        int e = i * 256 + tid;
        int nl = e & 63, kbl = e >> 6;   // 0..7
        unsigned pk[4];
        #pragma unroll
        for (int jp = 0; jp < 4; ++jp)
            pk[jp] = f2bf(t[kbl * 8 + jp * 2][nl]) | (f2bf(t[kbl * 8 + jp * 2 + 1][nl]) << 16);
        uint4 wv = {pk[0], pk[1], pk[2], pk[3]};
        int n = n0 + nl;
        Bf[(((size_t)(n >> 4)) * 64 + (k0 / 8 + kbl)) * 16 + (n & 15)] = wv;
    }
}

// ---------------------------------------------------------------------------
// Fragment MFMA GEMM: Y[M][512] = A @ W + bias, fp32 out. No LDS.
// grid (8, M/64): wave = 16m x 64n, 16 k-windows of 32.
// ---------------------------------------------------------------------------
__global__ __launch_bounds__(256, 1)
void mfma_gemm_kernel(const uint4* __restrict__ Af, const uint4* __restrict__ Bf,
                      const void* __restrict__ bias, float* __restrict__ Y,
                      const int* __restrict__ flagp) {
    int f = *flagp;
    int w = threadIdx.x >> 6, lane = threadIdx.x & 63;
    int q = lane >> 4, mn = lane & 15;
    int mt = blockIdx.y * 4 + w;
    int nt0 = blockIdx.x * 4;
    f32x4 acc[4] = {{0.f,0.f,0.f,0.f},{0.f,0.f,0.f,0.f},{0.f,0.f,0.f,0.f},{0.f,0.f,0.f,0.f}};
    for (int kw = 0; kw < 16; ++kw) {
        short8 a = *(const short8*)(Af + ((size_t)mt * 64 + kw * 4 + q) * 16 + mn);
        #pragma unroll
        for (int i = 0; i < 4; ++i) {
            short8 b = *(const short8*)(Bf + (((size_t)(nt0 + i)) * 64 + kw * 4 + q) * 16 + mn);
            acc[i] = __builtin_amdgcn_mfma_f32_16x16x32_bf16(a, b, acc[i], 0, 0, 0);
        }
    }
    #pragma unroll
    for (int i = 0; i < 4; ++i) {
        int col = (nt0 + i) * 16 + mn;
        float bv = dload(bias, col, f);
        #pragma unroll
        for (int r = 0; r < 4; ++r)
            Y[(size_t)(mt * 16 + q * 4 + r) * D_DIM + col] = acc[i][r] + bv;
    }
}

// ---------------------------------------------------------------------------
// Pack head-sliced fp32 [R][512] into bf16 score fragments (round 9).
// ---------------------------------------------------------------------------
__global__ void pack_frag_kernel(const float* __restrict__ in, uint4* __restrict__ out, int R) {
    int h = blockIdx.y;
    int tid = threadIdx.x;
    int kb = tid & 7;
    int r  = blockIdx.x * 32 + (tid >> 3);
    int tt = r >> 4, m = r & 15;
    const float* src = in + (size_t)r * D_DIM + h * 64 + kb * 8;
    float4 v0 = *(const float4*)src;
    float4 v1 = *(const float4*)(src + 4);
    uint4 w;
    w.x = f2bf(v0.x) | (f2bf(v0.y) << 16);
    w.y = f2bf(v0.z) | (f2bf(v0.w) << 16);
    w.z = f2bf(v1.x) | (f2bf(v1.y) << 16);
    w.w = f2bf(v1.z) | (f2bf(v1.w) << 16);
    out[(((size_t)h * (R >> 4) + tt) * 8 + kb) * 16 + m] = w;
}

// ---------------------------------------------------------------------------
// Scores via MFMA bf16 (round 9): per head M=1024 x N=8192 x K=64.
// ---------------------------------------------------------------------------
__global__ __launch_bounds__(256)
void score_mfma_kernel(const uint4* __restrict__ qf, const uint4* __restrict__ kf,
                       float* __restrict__ Sm) {
    int h = blockIdx.z;
    int w = threadIdx.x >> 6, lane = threadIdx.x & 63;
    int tt  = blockIdx.y * 4 + w;
    int nt0 = blockIdx.x * 4;
    int q = lane >> 4, nm = lane & 15;

    short8 a0 = *(const short8*)(qf + (((size_t)h * 64 + tt) * 8 + q) * 16 + nm);
    short8 a1 = *(const short8*)(qf + (((size_t)h * 64 + tt) * 8 + 4 + q) * 16 + nm);

    #pragma unroll
    for (int i = 0; i < 4; ++i) {
        int nt = nt0 + i;
        short8 b0 = *(const short8*)(kf + (((size_t)h * 512 + nt) * 8 + q) * 16 + nm);
        short8 b1 = *(const short8*)(kf + (((size_t)h * 512 + nt) * 8 + 4 + q) * 16 + nm);
        f32x4 acc = {0.0f, 0.0f, 0.0f, 0.0f};
        acc = __builtin_amdgcn_mfma_f32_16x16x32_bf16(a0, b0, acc, 0, 0, 0);
        acc = __builtin_amdgcn_mfma_f32_16x16x32_bf16(a1, b1, acc, 0, 0, 0);
        #pragma unroll
        for (int r = 0; r < 4; ++r) {
            float v = acc[r];
            v = fmaxf(v, __shfl_xor(v, 1));
            v = fmaxf(v, __shfl_xor(v, 2));
            if ((lane & 3) == 0) {
                int t = tt * 16 + q * 4 + r;
                int c = (nt * 16 + nm) >> 2;
                Sm[((size_t)h * 1024 + t) * C_DIM + c] = v * 0.125f;
            }
        }
    }
}

// ---------------------------------------------------------------------------
__global__ void softmax_kernel(float* __restrict__ S) {
    size_t base = (size_t)blockIdx.x * C_DIM;
    int tid = threadIdx.x;
    int w = tid >> 6, lane = tid & 63;
    __shared__ float sred[8];
    float v[8];
    float m = -1e30f;
    #pragma unroll
    for (int i = 0; i < 8; ++i) { v[i] = S[base + i * 256 + tid]; m = fmaxf(m, v[i]); }
    #pragma unroll
    for (int o = 32; o > 0; o >>= 1) m = fmaxf(m, __shfl_xor(m, o));
    if (lane == 0) sred[w] = m;
    __syncthreads();
    m = fmaxf(fmaxf(sred[0], sred[1]), fmaxf(sred[2], sred[3]));
    float s = 0.0f;
    #pragma unroll
    for (int i = 0; i < 8; ++i) { v[i] = __expf(v[i] - m); s += v[i]; }
    #pragma unroll
    for (int o = 32; o > 0; o >>= 1) s += __shfl_xor(s, o);
    if (lane == 0) sred[4 + w] = s;
    __syncthreads();
    float inv = 1.0f / (sred[4] + sred[5] + sred[6] + sred[7]);
    #pragma unroll
    for (int i = 0; i < 8; ++i) S[base + i * 256 + tid] = v[i] * inv;
}

// ---------------------------------------------------------------------------
#define NSEG 8
__global__ void pv_part_kernel(const float* __restrict__ P, const float* __restrict__ vp,
                               float* __restrict__ part) {
    __shared__ float As[16][68];
    __shared__ float Bs[16][68];
    int h = blockIdx.y;
    int seg = blockIdx.z;
    int row0 = blockIdx.x * 64;
    int tid = threadIdx.x;
    int tx = tid & 15, ty = tid >> 4;
    const float* Ph = P + (size_t)h * 1024 * C_DIM;
    float acc[4][4] = {};
    int k0 = seg * (C_DIM / NSEG);
    for (int kt = k0; kt < k0 + C_DIM / NSEG; kt += 16) {
        #pragma unroll
        for (int i = 0; i < 4; ++i) {
            int e = i * 256 + tid;
            int r = e >> 4, kk = e & 15;
            As[kk][r] = Ph[(size_t)(row0 + r) * C_DIM + kt + kk];
            int kk2 = e >> 6, c2 = e & 63;
            Bs[kk2][c2] = vp[(size_t)(kt + kk2) * D_DIM + h * 64 + c2];
        }
        __syncthreads();
        #pragma unroll
        for (int kk = 0; kk < 16; ++kk) {
            float4 a = *(const float4*)&As[kk][ty * 4];
            float4 b = *(const float4*)&Bs[kk][tx * 4];
            acc[0][0] += a.x * b.x; acc[0][1] += a.x * b.y; acc[0][2] += a.x * b.z; acc[0][3] += a.x * b.w;
            acc[1][0] += a.y * b.x; acc[1][1] += a.y * b.y; acc[1][2] += a.y * b.z; acc[1][3] += a.y * b.w;
            acc[2][0] += a.z * b.x; acc[2][1] += a.z * b.y; acc[2][2] += a.z * b.z; acc[2][3] += a.z * b.w;
            acc[3][0] += a.w * b.x; acc[3][1] += a.w * b.y; acc[3][2] += a.w * b.z; acc[3][3] += a.w * b.w;
        }
        __syncthreads();
    }
    float* pseg = part + (size_t)seg * 1024 * D_DIM;
    #pragma unroll
    for (int i = 0; i < 4; ++i)
        #pragma unroll
        for (int j = 0; j < 4; ++j)
            pseg[(size_t)(row0 + ty * 4 + i) * D_DIM + h * 64 + tx * 4 + j] = acc[i][j];
}

__global__ void pv_reduce_kernel(const float* __restrict__ part, float* __restrict__ att) {
    size_t idx = ((size_t)blockIdx.x * 256 + threadIdx.x) * 4;
    float4 s = *(const float4*)&part[idx];
    #pragma unroll
    for (int seg = 1; seg < NSEG; ++seg) {
        float4 v = *(const float4*)&part[(size_t)seg * 1024 * D_DIM + idx];
        s.x += v.x; s.y += v.y; s.z += v.z; s.w += v.w;
    }
    *(float4*)&att[idx] = s;
}

// ---------------------------------------------------------------------------
// Fallback flash attention (round 7) for small workspaces.
// ---------------------------------------------------------------------------
__global__ __launch_bounds__(256, 1)
void attn_flash_part(const float* __restrict__ qp, const float* __restrict__ kp,
                     const float* __restrict__ vp,
                     float* __restrict__ pacc, float* __restrict__ pm,
                     float* __restrict__ pl, int nsplit, float* __restrict__ att) {
    __shared__ float sq[TQF][DK];
    __shared__ float sp[TQF][TC + 4];
    __shared__ float sv[TC][DK];
    __shared__ float sm[TQF], sl[TQF];

    int tid = threadIdx.x;
    int b = blockIdx.x;
    int s = b & (nsplit - 1);
    int h = (b / nsplit) & 7;
    int qt = b / (nsplit * 8);
    int bt0 = qt * TQF;
    int w = tid >> 6, lane = tid & 63;

    #pragma unroll
    for (int i = 0; i < 2; ++i) {
        int e4 = i * 256 + tid;
        int tq = e4 >> 4, dq = (e4 & 15) * 4;
        *(float4*)&sq[tq][dq] = *(const float4*)&qp[(size_t)(bt0 + tq) * D_DIM + h * DK + dq];
    }
    if (tid < TQF) { sm[tid] = -1e30f; sl[tid] = 0.0f; }
    __syncthreads();

    float acc[8] = {};
    int u = tid & 3, csub = tid >> 2;
    int cs = C_DIM / nsplit;
    int ntile = cs / TC;

    for (int tile = 0; tile < ntile; ++tile) {
        int c0 = s * cs + tile * TC;
        const float* kvp = kp + ((size_t)(c0 + csub) * U_DIM + u) * D_DIM + h * DK;
        float4 kr[16];
        #pragma unroll
        for (int dd = 0; dd < 16; ++dd) kr[dd] = ((const float4*)kvp)[dd];
        #pragma unroll
        for (int i = 0; i < 4; ++i) {
            int e4 = i * 256 + tid;
            int c = e4 >> 4, dq = (e4 & 15) * 4;
            *(float4*)&sv[c][dq] = *(const float4*)&vp[(size_t)(c0 + c) * D_DIM + h * DK + dq];
        }
        #pragma unroll 4
        for (int tq = 0; tq < TQF; ++tq) {
            float sc = 0.0f;
            #pragma unroll
            for (int dd = 0; dd < 16; ++dd) {
                float4 qv = *(const float4*)&sq[tq][dd * 4];
                sc += qv.x * kr[dd].x + qv.y * kr[dd].y + qv.z * kr[dd].z + qv.w * kr[dd].w;
            }
            sc = fmaxf(sc, __shfl_xor(sc, 1));
            sc = fmaxf(sc, __shfl_xor(sc, 2));
            if (u == 0) sp[tq][csub] = sc * 0.125f;
        }
        __syncthreads();
        #pragma unroll
        for (int j = 0; j < 8; ++j) {
            int tq = w * 8 + j;
            float sval = sp[tq][lane];
            float tmax = sval;
            #pragma unroll
            for (int o = 1; o < 64; o <<= 1) tmax = fmaxf(tmax, __shfl_xor(tmax, o));
            float mold = sm[tq];
            float mnew = fmaxf(mold, tmax);
            float alpha = __expf(mold - mnew);
            float p = __expf(sval - mnew);
            float rsum = p;
            #pragma unroll
            for (int o = 1; o < 64; o <<= 1) rsum += __shfl_xor(rsum, o);
            if (lane == 0) { sm[tq] = mnew; sl[tq] = sl[tq] * alpha + rsum; }
            sp[tq][lane] = p;
            acc[j] *= alpha;
            #pragma unroll
            for (int c4 = 0; c4 < TC / 4; ++c4) {
                float4 pv = *(const float4*)&sp[tq][c4 * 4];
                acc[j] += pv.x * sv[c4 * 4 + 0][lane];
                acc[j] += pv.y * sv[c4 * 4 + 1][lane];
                acc[j] += pv.z * sv[c4 * 4 + 2][lane];
                acc[j] += pv.w * sv[c4 * 4 + 3][lane];
            }
        }
        __syncthreads();
    }

    if (nsplit == 1) {
        #pragma unroll
        for (int j = 0; j < 8; ++j) {
            int tq = w * 8 + j;
            att[(size_t)(bt0 + tq) * D_DIM + h * DK + lane] = acc[j] / sl[tq];
        }
    } else {
        int p = (qt * 8 + h) * nsplit + s;
        #pragma unroll
        for (int j = 0; j < 8; ++j) {
            int tq = w * 8 + j;
            pacc[((size_t)p * TQF + tq) * DK + lane] = acc[j];
            if (lane == 0) { pm[p * TQF + tq] = sm[tq]; pl[p * TQF + tq] = sl[tq]; }
        }
    }
}

__global__ void attn_merge_kernel(const float* __restrict__ pacc, const float* __restrict__ pm,
                                  const float* __restrict__ pl, int nsplit,
                                  float* __restrict__ att) {
    int b = blockIdx.x;
    int qt = b >> 3, h = b & 7;
    int tid = threadIdx.x;
    int w = tid >> 6, lane = tid & 63;
    int p0 = b * nsplit;
    #pragma unroll
    for (int j = 0; j < 8; ++j) {
        int tq = w * 8 + j;
        float M = -1e30f;
        for (int s = 0; s < nsplit; ++s) M = fmaxf(M, pm[(p0 + s) * TQF + tq]);
        float L = 0.0f, o = 0.0f;
        for (int s = 0; s < nsplit; ++s) {
            float e = __expf(pm[(p0 + s) * TQF + tq] - M);
            L += pl[(p0 + s) * TQF + tq] * e;
            o += pacc[((size_t)(p0 + s) * TQF + tq) * DK + lane] * e;
        }
        att[(size_t)(qt * TQF + tq) * D_DIM + h * DK + lane] = o / L;
    }
}

extern "C" void kernel_launch(void* const* d_in, const int* in_sizes, int n_in,
                              void* d_out, int out_size, void* d_ws, size_t ws_size,
                              hipStream_t stream) {
    const void* model_embed = d_in[0];
    const void* ctx_key     = d_in[1];
    const void* ctx_val     = d_in[2];
    const void* ln1w = d_in[3];  const void* ln1b = d_in[4];
    const void* ln2w = d_in[5];  const void* ln2b = d_in[6];
    const void* ln3w = d_in[7];  const void* ln3b = d_in[8];
    const void* ln4w = d_in[9];  const void* ln4b = d_in[10];
    const void* wq = d_in[11];   const void* bq = d_in[12];
    const void* wk = d_in[13];   const void* bk = d_in[14];
    const void* wv = d_in[15];   const void* bv = d_in[16];
    const void* wo = d_in[17];   const void* bo = d_in[18];
    const void* wp = d_in[19];   const void* bp = d_in[20];

    int*   flagp  = (int*)d_ws;
    float* ws     = (float*)d_ws + 16;
    float* qp     = ws;                    // 524288
    float* kp     = qp + 524288;           // 4194304
    float* vp     = kp + 4194304;          // 1048576
    float* att    = vp + 1048576;          // 524288
    float* o1     = att + 524288;          // 524288
    float* statsQ = o1 + 524288;           // 2048
    float* statsK = statsQ + 2048;         // 16384
    float* statsV = statsK + 16384;        // 4096
    float* statsO = statsV + 4096;         // 2048
    float* ext    = statsO + 2048;

    // decomposed layout in ext:
    float* qT = ext;                       // 524288 (qf 1 MB)
    float* kT = qT + 524288;               // 4194304 (kf 8 MB; later pv partials)
    float* Sm = kT + 4194304;              // 16777216 (also transient A-frags, mode 3)
    float* wfrag = Sm + 16777216;          // 655360 floats = 5 x 32768 uint4 (mode 3 only)
    // flash layout in ext:
    float* pacc = ext;
    float* pm   = pacc + 2097152;
    float* pl   = pm + 32768;

    size_t base_fl   = 16 + 6815744 + 24576;
    size_t need_dec  = (base_fl + 524288 + 4194304 + 16777216) * 4;
    size_t need_mfma = need_dec + 655360 * 4;
    size_t need_fl4  = (base_fl + 2097152 + 65536) * 4;
    int mode = (ws_size >= need_mfma) ? 3 : (ws_size >= need_dec) ? 2
             : (ws_size >= need_fl4) ? 1 : 0;

    detect_kernel<<<1, 256, 0, stream>>>(model_embed, flagp);

    row_stats_kernel<<<1024, 256, 0, stream>>>(model_embed, 1, statsQ, flagp);
    row_stats_kernel<<<8192, 256, 0, stream>>>(ctx_key, 1, statsK, flagp);
    row_stats_kernel<<<2048, 256, 0, stream>>>(ctx_val, 1, statsV, flagp);

    uint4* fragA = (uint4*)Sm;             // transient A-frags (mode 3)
    uint4* wfq = (uint4*)wfrag;
    uint4* wfk = wfq + 32768;
    uint4* wfv = wfk + 32768;
    uint4* wfo = wfv + 32768;
    uint4* wfp = wfo + 32768;

    if (mode == 3) {
        pack_w_kernel<<<64, 256, 0, stream>>>(wq, wfq, flagp);
        pack_w_kernel<<<64, 256, 0, stream>>>(wk, wfk, flagp);
        pack_w_kernel<<<64, 256, 0, stream>>>(wv, wfv, flagp);
        pack_w_kernel<<<64, 256, 0, stream>>>(wo, wfo, flagp);
        pack_w_kernel<<<64, 256, 0, stream>>>(wp, wfp, flagp);

        pack_a_kernel<true><<<64, 256, 0, stream>>>(model_embed, 1, statsQ, ln1w, ln1b, fragA, flagp);
        mfma_gemm_kernel<<<dim3(8, 16), 256, 0, stream>>>(fragA, wfq, bq, qp, flagp);
        pack_a_kernel<true><<<512, 256, 0, stream>>>(ctx_key, 1, statsK, ln2w, ln2b, fragA, flagp);
        mfma_gemm_kernel<<<dim3(8, 128), 256, 0, stream>>>(fragA, wfk, bk, kp, flagp);
        pack_a_kernel<true><<<128, 256, 0, stream>>>(ctx_val, 1, statsV, ln3w, ln3b, fragA, flagp);
        mfma_gemm_kernel<<<dim3(8, 32), 256, 0, stream>>>(fragA, wfv, bv, vp, flagp);
    } else {
        gemm_ln_kernel<true><<<dim3(8, 16), 256, 0, stream>>>(model_embed, 1, statsQ, ln1w, ln1b, wq, bq, qp, flagp);
        gemm_ln_kernel<true><<<dim3(8, 128), 256, 0, stream>>>(ctx_key, 1, statsK, ln2w, ln2b, wk, bk, kp, flagp);
        gemm_ln_kernel<true><<<dim3(8, 32), 256, 0, stream>>>(ctx_val, 1, statsV, ln3w, ln3b, wv, bv, vp, flagp);
    }

    if (mode >= 2) {
        uint4* qf = (uint4*)qT;
        uint4* kf = (uint4*)kT;
        pack_frag_kernel<<<dim3(32, 8), 256, 0, stream>>>(qp, qf, 1024);
        pack_frag_kernel<<<dim3(256, 8), 256, 0, stream>>>(kp, kf, 8192);
        score_mfma_kernel<<<dim3(128, 16, 8), 256, 0, stream>>>(qf, kf, Sm);
        softmax_kernel<<<8192, 256, 0, stream>>>(Sm);
        pv_part_kernel<<<dim3(16, 8, NSEG), 256, 0, stream>>>(Sm, vp, kT);
        pv_reduce_kernel<<<512, 256, 0, stream>>>(kT, att);
    } else {
        int nsplit = (mode == 1) ? 4 : 1;
        attn_flash_part<<<256 * nsplit, 256, 0, stream>>>(qp, kp, vp, pacc, pm, pl, nsplit, att);
        if (nsplit > 1)
            attn_merge_kernel<<<256, 256, 0, stream>>>(pacc, pm, pl, nsplit, att);
    }

    if (mode == 3) {
        pack_a_kernel<false><<<64, 256, 0, stream>>>(att, 0, nullptr, nullptr, nullptr, fragA, flagp);
        mfma_gemm_kernel<<<dim3(8, 16), 256, 0, stream>>>(fragA, wfo, bo, o1, flagp);
        row_stats_kernel<<<1024, 256, 0, stream>>>(o1, 0, statsO, flagp);
        pack_a_kernel<true><<<64, 256, 0, stream>>>(o1, 0, statsO, ln4w, ln4b, fragA, flagp);
        mfma_gemm_kernel<<<dim3(8, 16), 256, 0, stream>>>(fragA, wfp, bp, (float*)d_out, flagp);
    } else {
        gemm_ln_kernel<false><<<dim3(8, 16), 256, 0, stream>>>(att, 0, nullptr, nullptr, nullptr, wo, bo, o1, flagp);
        row_stats_kernel<<<1024, 256, 0, stream>>>(o1, 0, statsO, flagp);
        gemm_ln_kernel<true><<<dim3(8, 16), 256, 0, stream>>>(o1, 0, statsO, ln4w, ln4b, wp, bp, (float*)d_out, flagp);
    }
}

// Round 12
// 349.292 us; speedup vs baseline: 14.6429x; 1.0885x over previous
//
#include <hip/hip_runtime.h>
#include <hip/hip_bf16.h>

using bf16 = __hip_bfloat16;

#define D_DIM 512
#define C_DIM 2048
#define U_DIM 4
#define DK 64
#define TQF 32
#define TC 64

typedef __attribute__((ext_vector_type(8))) short short8;
typedef __attribute__((ext_vector_type(4))) float f32x4;

__device__ __forceinline__ float dload(const void* p, size_t i, int f) {
    return f ? ((const float*)p)[i] : __bfloat162float(((const bf16*)p)[i]);
}
__device__ __forceinline__ unsigned f2bf(float x) {
    bf16 b = __float2bfloat16(x);
    return (unsigned)*(unsigned short*)&b;
}

// ---------------------------------------------------------------------------
__global__ void detect_kernel(const void* __restrict__ x, int* __restrict__ flag) {
    const bf16* xb = (const bf16*)x;
    int tid = threadIdx.x;
    int cnt = 0;
    for (int i = tid; i < 8192; i += 256) {
        float a = fabsf(__bfloat162float(xb[i]));
        if (!(a <= 100.0f)) cnt++;
    }
    #pragma unroll
    for (int o = 32; o > 0; o >>= 1) cnt += __shfl_down(cnt, o);
    __shared__ int sred[4];
    if ((tid & 63) == 0) sred[tid >> 6] = cnt;
    __syncthreads();
    if (tid == 0) {
        int c = sred[0] + sred[1] + sred[2] + sred[3];
        *flag = (c > 400) ? 1 : 0;
    }
}

// ---------------------------------------------------------------------------
__global__ void row_stats_kernel(const void* __restrict__ x, int x_raw,
                                 float* __restrict__ stats, const int* __restrict__ flagp) {
    int f = x_raw ? *flagp : 1;
    int row = blockIdx.x;
    int tid = threadIdx.x;
    size_t base = (size_t)row * D_DIM;
    float v0 = dload(x, base + tid, f);
    float v1 = dload(x, base + tid + 256, f);
    float s  = v0 + v1;
    float ss = v0 * v0 + v1 * v1;
    #pragma unroll
    for (int o = 32; o > 0; o >>= 1) {
        s  += __shfl_down(s, o);
        ss += __shfl_down(ss, o);
    }
    __shared__ float sred[8];
    int wv = tid >> 6, ln = tid & 63;
    if (ln == 0) { sred[wv] = s; sred[wv + 4] = ss; }
    __syncthreads();
    if (tid == 0) {
        float S  = sred[0] + sred[1] + sred[2] + sred[3];
        float SS = sred[4] + sred[5] + sred[6] + sred[7];
        float mu  = S * (1.0f / D_DIM);
        float var = SS * (1.0f / D_DIM) - mu * mu;
        stats[row * 2]     = mu;
        stats[row * 2 + 1] = rsqrtf(var + 1e-5f);
    }
}

// ---------------------------------------------------------------------------
// fp32 fallback GEMM (mode<3).
// ---------------------------------------------------------------------------
template <bool LN>
__global__ void gemm_ln_kernel(const void* __restrict__ X, int x_raw,
                               const float* __restrict__ stats,
                               const void* __restrict__ lnw, const void* __restrict__ lnb,
                               const void* __restrict__ W, const void* __restrict__ bias,
                               float* __restrict__ Y, const int* __restrict__ flagp) {
    __shared__ float As[16][68];
    __shared__ float Bs[16][68];
    int f = *flagp;
    int xf = x_raw ? f : 1;
    int tid = threadIdx.x;
    int tx = tid & 15, ty = tid >> 4;
    int row0 = blockIdx.y * 64, col0 = blockIdx.x * 64;
    float acc[4][4] = {};
    for (int kt = 0; kt < D_DIM; kt += 16) {
        #pragma unroll
        for (int i = 0; i < 4; ++i) {
            int e = tid + i * 256;
            int r = e >> 4, kk = e & 15;
            float xv = dload(X, (size_t)(row0 + r) * D_DIM + kt + kk, xf);
            if constexpr (LN) {
                float mu = stats[(row0 + r) * 2];
                float rs = stats[(row0 + r) * 2 + 1];
                xv = (xv - mu) * rs * dload(lnw, kt + kk, f) + dload(lnb, kt + kk, f);
            }
            As[kk][r] = xv;
            int kk2 = e >> 6, c2 = e & 63;
            Bs[kk2][c2] = dload(W, (size_t)(kt + kk2) * D_DIM + col0 + c2, f);
        }
        __syncthreads();
        #pragma unroll
        for (int kk = 0; kk < 16; ++kk) {
            float4 a = *(const float4*)&As[kk][ty * 4];
            float4 b = *(const float4*)&Bs[kk][tx * 4];
            acc[0][0] += a.x * b.x; acc[0][1] += a.x * b.y; acc[0][2] += a.x * b.z; acc[0][3] += a.x * b.w;
            acc[1][0] += a.y * b.x; acc[1][1] += a.y * b.y; acc[1][2] += a.y * b.z; acc[1][3] += a.y * b.w;
            acc[2][0] += a.z * b.x; acc[2][1] += a.z * b.y; acc[2][2] += a.z * b.z; acc[2][3] += a.z * b.w;
            acc[3][0] += a.w * b.x; acc[3][1] += a.w * b.y; acc[3][2] += a.w * b.z; acc[3][3] += a.w * b.w;
        }
        __syncthreads();
    }
    #pragma unroll
    for (int i = 0; i < 4; ++i) {
        int r = row0 + ty * 4 + i;
        #pragma unroll
        for (int j = 0; j < 4; ++j) {
            int c = col0 + tx * 4 + j;
            Y[(size_t)r * D_DIM + c] = acc[i][j] + dload(bias, c, f);
        }
    }
}

// ---------------------------------------------------------------------------
// Pack activation [M][512] (optional fused LN) into bf16 A-fragments.
// ---------------------------------------------------------------------------
template <bool LN>
__global__ void pack_a_kernel(const void* __restrict__ X, int x_raw,
                              const float* __restrict__ stats,
                              const void* __restrict__ lnw, const void* __restrict__ lnb,
                              uint4* __restrict__ Af, const int* __restrict__ flagp) {
    int f = *flagp;
    int xf = x_raw ? f : 1;
    int tt = blockIdx.x;
    int m = threadIdx.x >> 4;
    int kbL = threadIdx.x & 15;
    int row = tt * 16 + m;
    float mu = 0.0f, rs = 1.0f;
    if (LN) { mu = stats[row * 2]; rs = stats[row * 2 + 1]; }
    #pragma unroll
    for (int i = 0; i < 4; ++i) {
        int kb = kbL + i * 16;
        unsigned pk[4];
        #pragma unroll
        for (int jp = 0; jp < 4; ++jp) {
            int k0 = kb * 8 + jp * 2;
            float v0 = dload(X, (size_t)row * D_DIM + k0, xf);
            float v1 = dload(X, (size_t)row * D_DIM + k0 + 1, xf);
            if (LN) {
                v0 = (v0 - mu) * rs * dload(lnw, k0, f) + dload(lnb, k0, f);
                v1 = (v1 - mu) * rs * dload(lnw, k0 + 1, f) + dload(lnb, k0 + 1, f);
            }
            pk[jp] = f2bf(v0) | (f2bf(v1) << 16);
        }
        uint4 wv = {pk[0], pk[1], pk[2], pk[3]};
        Af[((size_t)tt * 64 + kb) * 16 + m] = wv;
    }
}

// ---------------------------------------------------------------------------
// Pack weight W[k=512][n=512] into bf16 B-fragments (transposed).
// ---------------------------------------------------------------------------
__global__ void pack_w_kernel(const void* __restrict__ W, uint4* __restrict__ Bf,
                              const int* __restrict__ flagp) {
    __shared__ float t[64][65];
    int f = *flagp;
    int b = blockIdx.x;
    int n0 = (b & 7) * 64, k0 = (b >> 3) * 64;
    int tid = threadIdx.x;
    for (int i = 0; i < 16; ++i) {
        int e = i * 256 + tid;
        int r = e >> 6, c = e & 63;
        t[r][c] = dload(W, (size_t)(k0 + r) * D_DIM + n0 + c, f);
    }
    __syncthreads();
    #pragma unroll
    for (int i = 0; i < 2; ++i) {
        int e = i * 256 + tid;
        int nl = e & 63, kbl = e >> 6;
        unsigned pk[4];
        #pragma unroll
        for (int jp = 0; jp < 4; ++jp)
            pk[jp] = f2bf(t[kbl * 8 + jp * 2][nl]) | (f2bf(t[kbl * 8 + jp * 2 + 1][nl]) << 16);
        uint4 wv = {pk[0], pk[1], pk[2], pk[3]};
        int n = n0 + nl;
        Bf[(((size_t)(n >> 4)) * 64 + (k0 / 8 + kbl)) * 16 + (n & 15)] = wv;
    }
}

// ---------------------------------------------------------------------------
// Fragment MFMA GEMM (round 10, validated).
// ---------------------------------------------------------------------------
__global__ __launch_bounds__(256, 1)
void mfma_gemm_kernel(const uint4* __restrict__ Af, const uint4* __restrict__ Bf,
                      const void* __restrict__ bias, float* __restrict__ Y,
                      const int* __restrict__ flagp) {
    int f = *flagp;
    int w = threadIdx.x >> 6, lane = threadIdx.x & 63;
    int q = lane >> 4, mn = lane & 15;
    int mt = blockIdx.y * 4 + w;
    int nt0 = blockIdx.x * 4;
    f32x4 acc[4] = {{0.f,0.f,0.f,0.f},{0.f,0.f,0.f,0.f},{0.f,0.f,0.f,0.f},{0.f,0.f,0.f,0.f}};
    for (int kw = 0; kw < 16; ++kw) {
        short8 a = *(const short8*)(Af + ((size_t)mt * 64 + kw * 4 + q) * 16 + mn);
        #pragma unroll
        for (int i = 0; i < 4; ++i) {
            short8 b = *(const short8*)(Bf + (((size_t)(nt0 + i)) * 64 + kw * 4 + q) * 16 + mn);
            acc[i] = __builtin_amdgcn_mfma_f32_16x16x32_bf16(a, b, acc[i], 0, 0, 0);
        }
    }
    #pragma unroll
    for (int i = 0; i < 4; ++i) {
        int col = (nt0 + i) * 16 + mn;
        float bv = dload(bias, col, f);
        #pragma unroll
        for (int r = 0; r < 4; ++r)
            Y[(size_t)(mt * 16 + q * 4 + r) * D_DIM + col] = acc[i][r] + bv;
    }
}

// ---------------------------------------------------------------------------
// Pack head-sliced fp32 [R][512] into bf16 score fragments (round 9).
// ---------------------------------------------------------------------------
__global__ void pack_frag_kernel(const float* __restrict__ in, uint4* __restrict__ out, int R) {
    int h = blockIdx.y;
    int tid = threadIdx.x;
    int kb = tid & 7;
    int r  = blockIdx.x * 32 + (tid >> 3);
    int tt = r >> 4, m = r & 15;
    const float* src = in + (size_t)r * D_DIM + h * 64 + kb * 8;
    float4 v0 = *(const float4*)src;
    float4 v1 = *(const float4*)(src + 4);
    uint4 w;
    w.x = f2bf(v0.x) | (f2bf(v0.y) << 16);
    w.y = f2bf(v0.z) | (f2bf(v0.w) << 16);
    w.z = f2bf(v1.x) | (f2bf(v1.y) << 16);
    w.w = f2bf(v1.z) | (f2bf(v1.w) << 16);
    out[(((size_t)h * (R >> 4) + tt) * 8 + kb) * 16 + m] = w;
}

// ---------------------------------------------------------------------------
// Pack V [2048][512] head-slice into bf16 B-fragments for PV MFMA:
// vf[((h*64+ct)*4+nt)*64 + lane] = B[k=ctx_loc][n=dim] fragment, 16B/lane.
// ---------------------------------------------------------------------------
__global__ void pack_v_kernel(const float* __restrict__ vp, uint4* __restrict__ vf) {
    int ct = blockIdx.x;
    int h = blockIdx.y;
    int tid = threadIdx.x;
    int nt = tid >> 6, lane = tid & 63;
    int n = nt * 16 + (lane & 15);
    int c0 = ct * 32 + (lane >> 4) * 8;
    unsigned pk[4];
    #pragma unroll
    for (int jp = 0; jp < 4; ++jp) {
        float v0 = vp[(size_t)(c0 + jp * 2) * D_DIM + h * 64 + n];
        float v1 = vp[(size_t)(c0 + jp * 2 + 1) * D_DIM + h * 64 + n];
        pk[jp] = f2bf(v0) | (f2bf(v1) << 16);
    }
    uint4 wv = {pk[0], pk[1], pk[2], pk[3]};
    vf[(((size_t)h * 64 + ct) * 4 + nt) * 64 + lane] = wv;
}

// ---------------------------------------------------------------------------
// FUSED MFMA flash attention. Grid 512 = 16 q-blocks x 8 heads x 4 c-splits.
// Wave = 16 tokens; ctx tile = 32 contexts (8 krow n-tiles). Score MFMA ->
// u-max (shfl 1,2) -> row tile-max (shfl 4,8) -> online (m,l,alpha) ->
// P->LDS (per-wave, 16x36 pad) -> bf16 A-frag -> 4 PV MFMAs vs packed V.
// Writes unnormalized partials (O, m, l); merge kernel combines splits.
// ---------------------------------------------------------------------------
__global__ __launch_bounds__(256, 1)
void attn_fused_kernel(const uint4* __restrict__ qf, const uint4* __restrict__ kf,
                       const uint4* __restrict__ vf,
                       float* __restrict__ pacc, float* __restrict__ pm,
                       float* __restrict__ pl) {
    __shared__ float sp[4][16][36];
    int tid = threadIdx.x;
    int w = tid >> 6, lane = tid & 63;
    int q = lane >> 4, nm = lane & 15;
    int b = blockIdx.x;
    int s = b & 3;
    int h = (b >> 2) & 7;
    int qb = b >> 5;
    int mt = qb * 4 + w;

    short8 a0 = *(const short8*)(qf + (((size_t)h * 64 + mt) * 8 + q) * 16 + nm);
    short8 a1 = *(const short8*)(qf + (((size_t)h * 64 + mt) * 8 + 4 + q) * 16 + nm);

    float mrow[4], lrow[4];
    f32x4 acc_o[4] = {{0.f,0.f,0.f,0.f},{0.f,0.f,0.f,0.f},{0.f,0.f,0.f,0.f},{0.f,0.f,0.f,0.f}};
    #pragma unroll
    for (int r = 0; r < 4; ++r) { mrow[r] = -1e30f; lrow[r] = 0.0f; }

    for (int ct = s * 16; ct < s * 16 + 16; ++ct) {
        // scores for 32 contexts: 8 n-tiles of 16 krows, MaxSim over u.
        float sc[8][4];
        #pragma unroll
        for (int i = 0; i < 8; ++i) {
            int nt = ct * 8 + i;
            short8 b0 = *(const short8*)(kf + (((size_t)h * 512 + nt) * 8 + q) * 16 + nm);
            short8 b1 = *(const short8*)(kf + (((size_t)h * 512 + nt) * 8 + 4 + q) * 16 + nm);
            f32x4 acc = {0.0f, 0.0f, 0.0f, 0.0f};
            acc = __builtin_amdgcn_mfma_f32_16x16x32_bf16(a0, b0, acc, 0, 0, 0);
            acc = __builtin_amdgcn_mfma_f32_16x16x32_bf16(a1, b1, acc, 0, 0, 0);
            #pragma unroll
            for (int r = 0; r < 4; ++r) {
                float v = acc[r];
                v = fmaxf(v, __shfl_xor(v, 1));
                v = fmaxf(v, __shfl_xor(v, 2));
                sc[i][r] = v * 0.125f;           // 1/sqrt(dk)
            }
        }
        // online softmax per row; P to LDS for PV A-fragments
        #pragma unroll
        for (int r = 0; r < 4; ++r) {
            float tmax = sc[0][r];
            #pragma unroll
            for (int i = 1; i < 8; ++i) tmax = fmaxf(tmax, sc[i][r]);
            tmax = fmaxf(tmax, __shfl_xor(tmax, 4));
            tmax = fmaxf(tmax, __shfl_xor(tmax, 8));
            float mnew = fmaxf(mrow[r], tmax);
            float alpha = __expf(mrow[r] - mnew);
            mrow[r] = mnew;
            float ps = 0.0f;
            float pv[8];
            #pragma unroll
            for (int i = 0; i < 8; ++i) { pv[i] = __expf(sc[i][r] - mnew); ps += pv[i]; }
            if ((nm & 3) == 0) {
                #pragma unroll
                for (int i = 0; i < 8; ++i) sp[w][q * 4 + r][i * 4 + (nm >> 2)] = pv[i];
            } else ps = 0.0f;
            ps += __shfl_xor(ps, 1);
            ps += __shfl_xor(ps, 2);
            ps += __shfl_xor(ps, 4);
            ps += __shfl_xor(ps, 8);
            lrow[r] = lrow[r] * alpha + ps;
            acc_o[0][r] *= alpha; acc_o[1][r] *= alpha;
            acc_o[2][r] *= alpha; acc_o[3][r] *= alpha;
        }
        // P A-fragment: A[m=nm][k=q*8+j] from per-wave LDS (same-wave RAW,
        // ordered by lgkmcnt — round-7-validated pattern).
        float4 pa0 = *(const float4*)&sp[w][nm][q * 8];
        float4 pa1 = *(const float4*)&sp[w][nm][q * 8 + 4];
        uint4 av;
        av.x = f2bf(pa0.x) | (f2bf(pa0.y) << 16);
        av.y = f2bf(pa0.z) | (f2bf(pa0.w) << 16);
        av.z = f2bf(pa1.x) | (f2bf(pa1.y) << 16);
        av.w = f2bf(pa1.z) | (f2bf(pa1.w) << 16);
        short8 ap = *(short8*)&av;
        #pragma unroll
        for (int nt2 = 0; nt2 < 4; ++nt2) {
            short8 bv = *(const short8*)(vf + (((size_t)h * 64 + ct) * 4 + nt2) * 64 + lane);
            acc_o[nt2] = __builtin_amdgcn_mfma_f32_16x16x32_bf16(ap, bv, acc_o[nt2], 0, 0, 0);
        }
    }

    int p_idx = (qb * 8 + h) * 4 + s;
    float* po = pacc + ((size_t)p_idx * 64 + w * 16) * 64;
    #pragma unroll
    for (int nt2 = 0; nt2 < 4; ++nt2)
        #pragma unroll
        for (int r = 0; r < 4; ++r)
            po[(q * 4 + r) * 64 + nt2 * 16 + nm] = acc_o[nt2][r];
    if (nm == 0) {
        #pragma unroll
        for (int r = 0; r < 4; ++r) {
            pm[p_idx * 64 + w * 16 + q * 4 + r] = mrow[r];
            pl[p_idx * 64 + w * 16 + q * 4 + r] = lrow[r];
        }
    }
}

// Merge 4 c-split partials per (q-block, head). Grid 128, 256 thr.
__global__ void attn_merge2_kernel(const float* __restrict__ pacc, const float* __restrict__ pm,
                                   const float* __restrict__ pl, float* __restrict__ att) {
    int b = blockIdx.x;                // qb*8 + h
    int qb = b >> 3, h = b & 7;
    int tid = threadIdx.x;
    int t_loc = tid & 63, dg = tid >> 6;
    int p0 = b * 4;
    float M = -1e30f;
    #pragma unroll
    for (int s = 0; s < 4; ++s) M = fmaxf(M, pm[(p0 + s) * 64 + t_loc]);
    float L = 0.0f;
    float4 o[4] = {};
    #pragma unroll
    for (int s = 0; s < 4; ++s) {
        float e = __expf(pm[(p0 + s) * 64 + t_loc] - M);
        L += pl[(p0 + s) * 64 + t_loc] * e;
        const float4* po = (const float4*)(pacc + ((size_t)(p0 + s) * 64 + t_loc) * 64 + dg * 16);
        #pragma unroll
        for (int d = 0; d < 4; ++d) {
            float4 v = po[d];
            o[d].x += v.x * e; o[d].y += v.y * e; o[d].z += v.z * e; o[d].w += v.w * e;
        }
    }
    float inv = 1.0f / L;
    float4* ao = (float4*)(att + (size_t)(qb * 64 + t_loc) * D_DIM + h * 64 + dg * 16);
    #pragma unroll
    for (int d = 0; d < 4; ++d) {
        float4 v = o[d];
        v.x *= inv; v.y *= inv; v.z *= inv; v.w *= inv;
        ao[d] = v;
    }
}

// ---------------------------------------------------------------------------
// Mode-2 fallback pieces (rounds 9-10, kept intact).
// ---------------------------------------------------------------------------
__global__ __launch_bounds__(256)
void score_mfma_kernel(const uint4* __restrict__ qf, const uint4* __restrict__ kf,
                       float* __restrict__ Sm) {
    int h = blockIdx.z;
    int w = threadIdx.x >> 6, lane = threadIdx.x & 63;
    int tt  = blockIdx.y * 4 + w;
    int nt0 = blockIdx.x * 4;
    int q = lane >> 4, nm = lane & 15;
    short8 a0 = *(const short8*)(qf + (((size_t)h * 64 + tt) * 8 + q) * 16 + nm);
    short8 a1 = *(const short8*)(qf + (((size_t)h * 64 + tt) * 8 + 4 + q) * 16 + nm);
    #pragma unroll
    for (int i = 0; i < 4; ++i) {
        int nt = nt0 + i;
        short8 b0 = *(const short8*)(kf + (((size_t)h * 512 + nt) * 8 + q) * 16 + nm);
        short8 b1 = *(const short8*)(kf + (((size_t)h * 512 + nt) * 8 + 4 + q) * 16 + nm);
        f32x4 acc = {0.0f, 0.0f, 0.0f, 0.0f};
        acc = __builtin_amdgcn_mfma_f32_16x16x32_bf16(a0, b0, acc, 0, 0, 0);
        acc = __builtin_amdgcn_mfma_f32_16x16x32_bf16(a1, b1, acc, 0, 0, 0);
        #pragma unroll
        for (int r = 0; r < 4; ++r) {
            float v = acc[r];
            v = fmaxf(v, __shfl_xor(v, 1));
            v = fmaxf(v, __shfl_xor(v, 2));
            if ((lane & 3) == 0) {
                int t = tt * 16 + q * 4 + r;
                int c = (nt * 16 + nm) >> 2;
                Sm[((size_t)h * 1024 + t) * C_DIM + c] = v * 0.125f;
            }
        }
    }
}

__global__ void softmax_kernel(float* __restrict__ S) {
    size_t base = (size_t)blockIdx.x * C_DIM;
    int tid = threadIdx.x;
    int w = tid >> 6, lane = tid & 63;
    __shared__ float sred[8];
    float v[8];
    float m = -1e30f;
    #pragma unroll
    for (int i = 0; i < 8; ++i) { v[i] = S[base + i * 256 + tid]; m = fmaxf(m, v[i]); }
    #pragma unroll
    for (int o = 32; o > 0; o >>= 1) m = fmaxf(m, __shfl_xor(m, o));
    if (lane == 0) sred[w] = m;
    __syncthreads();
    m = fmaxf(fmaxf(sred[0], sred[1]), fmaxf(sred[2], sred[3]));
    float s = 0.0f;
    #pragma unroll
    for (int i = 0; i < 8; ++i) { v[i] = __expf(v[i] - m); s += v[i]; }
    #pragma unroll
    for (int o = 32; o > 0; o >>= 1) s += __shfl_xor(s, o);
    if (lane == 0) sred[4 + w] = s;
    __syncthreads();
    float inv = 1.0f / (sred[4] + sred[5] + sred[6] + sred[7]);
    #pragma unroll
    for (int i = 0; i < 8; ++i) S[base + i * 256 + tid] = v[i] * inv;
}

#define NSEG 8
__global__ void pv_part_kernel(const float* __restrict__ P, const float* __restrict__ vp,
                               float* __restrict__ part) {
    __shared__ float As[16][68];
    __shared__ float Bs[16][68];
    int h = blockIdx.y;
    int seg = blockIdx.z;
    int row0 = blockIdx.x * 64;
    int tid = threadIdx.x;
    int tx = tid & 15, ty = tid >> 4;
    const float* Ph = P + (size_t)h * 1024 * C_DIM;
    float acc[4][4] = {};
    int k0 = seg * (C_DIM / NSEG);
    for (int kt = k0; kt < k0 + C_DIM / NSEG; kt += 16) {
        #pragma unroll
        for (int i = 0; i < 4; ++i) {
            int e = i * 256 + tid;
            int r = e >> 4, kk = e & 15;
            As[kk][r] = Ph[(size_t)(row0 + r) * C_DIM + kt + kk];
            int kk2 = e >> 6, c2 = e & 63;
            Bs[kk2][c2] = vp[(size_t)(kt + kk2) * D_DIM + h * 64 + c2];
        }
        __syncthreads();
        #pragma unroll
        for (int kk = 0; kk < 16; ++kk) {
            float4 a = *(const float4*)&As[kk][ty * 4];
            float4 b = *(const float4*)&Bs[kk][tx * 4];
            acc[0][0] += a.x * b.x; acc[0][1] += a.x * b.y; acc[0][2] += a.x * b.z; acc[0][3] += a.x * b.w;
            acc[1][0] += a.y * b.x; acc[1][1] += a.y * b.y; acc[1][2] += a.y * b.z; acc[1][3] += a.y * b.w;
            acc[2][0] += a.z * b.x; acc[2][1] += a.z * b.y; acc[2][2] += a.z * b.z; acc[2][3] += a.z * b.w;
            acc[3][0] += a.w * b.x; acc[3][1] += a.w * b.y; acc[3][2] += a.w * b.z; acc[3][3] += a.w * b.w;
        }
        __syncthreads();
    }
    float* pseg = part + (size_t)seg * 1024 * D_DIM;
    #pragma unroll
    for (int i = 0; i < 4; ++i)
        #pragma unroll
        for (int j = 0; j < 4; ++j)
            pseg[(size_t)(row0 + ty * 4 + i) * D_DIM + h * 64 + tx * 4 + j] = acc[i][j];
}

__global__ void pv_reduce_kernel(const float* __restrict__ part, float* __restrict__ att) {
    size_t idx = ((size_t)blockIdx.x * 256 + threadIdx.x) * 4;
    float4 s = *(const float4*)&part[idx];
    #pragma unroll
    for (int seg = 1; seg < NSEG; ++seg) {
        float4 v = *(const float4*)&part[(size_t)seg * 1024 * D_DIM + idx];
        s.x += v.x; s.y += v.y; s.z += v.z; s.w += v.w;
    }
    *(float4*)&att[idx] = s;
}

extern "C" void kernel_launch(void* const* d_in, const int* in_sizes, int n_in,
                              void* d_out, int out_size, void* d_ws, size_t ws_size,
                              hipStream_t stream) {
    const void* model_embed = d_in[0];
    const void* ctx_key     = d_in[1];
    const void* ctx_val     = d_in[2];
    const void* ln1w = d_in[3];  const void* ln1b = d_in[4];
    const void* ln2w = d_in[5];  const void* ln2b = d_in[6];
    const void* ln3w = d_in[7];  const void* ln3b = d_in[8];
    const void* ln4w = d_in[9];  const void* ln4b = d_in[10];
    const void* wq = d_in[11];   const void* bq = d_in[12];
    const void* wk = d_in[13];   const void* bk = d_in[14];
    const void* wv = d_in[15];   const void* bv = d_in[16];
    const void* wo = d_in[17];   const void* bo = d_in[18];
    const void* wp = d_in[19];   const void* bp = d_in[20];

    int*   flagp  = (int*)d_ws;
    float* ws     = (float*)d_ws + 16;
    float* qp     = ws;                    // 524288
    float* kp     = qp + 524288;           // 4194304
    float* vp     = kp + 4194304;          // 1048576
    float* att    = vp + 1048576;          // 524288
    float* o1     = att + 524288;          // 524288
    float* statsQ = o1 + 524288;           // 2048
    float* statsK = statsQ + 2048;         // 16384
    float* statsV = statsK + 16384;        // 4096
    float* statsO = statsV + 4096;         // 2048
    float* ext    = statsO + 2048;

    float* qT = ext;                       // 524288  (qf)
    float* kT = qT + 524288;               // 4194304 (kf; mode-2: pv partials)
    float* Sm = kT + 4194304;              // 16777216 (mode-3 scratch region)
    float* wfrag = Sm + 16777216;          // 655360 (5 x W-frags)

    // mode-3 carve-out inside the (unused) Sm region:
    uint4* fragA = (uint4*)Sm;             // projection A-frags (<= 2M floats)
    float* vfr   = Sm + 4194304;           // V B-frags (524288 floats)
    float* pacc2 = Sm + 6291456;           // 2097152 floats
    float* pm2   = Sm + 8388608;           // 32768
    float* pl2   = pm2 + 32768;            // 32768

    size_t base_fl   = 16 + 6815744 + 24576;
    size_t need_dec  = (base_fl + 524288 + 4194304 + 16777216) * 4;
    size_t need_mfma = need_dec + 655360 * 4;
    int mode = (ws_size >= need_mfma) ? 3 : (ws_size >= need_dec) ? 2 : 2;

    detect_kernel<<<1, 256, 0, stream>>>(model_embed, flagp);

    row_stats_kernel<<<1024, 256, 0, stream>>>(model_embed, 1, statsQ, flagp);
    row_stats_kernel<<<8192, 256, 0, stream>>>(ctx_key, 1, statsK, flagp);
    row_stats_kernel<<<2048, 256, 0, stream>>>(ctx_val, 1, statsV, flagp);

    uint4* wfq = (uint4*)wfrag;
    uint4* wfk = wfq + 32768;
    uint4* wfv = wfk + 32768;
    uint4* wfo = wfv + 32768;
    uint4* wfp = wfo + 32768;
    uint4* qf = (uint4*)qT;
    uint4* kf = (uint4*)kT;

    if (mode == 3) {
        pack_w_kernel<<<64, 256, 0, stream>>>(wq, wfq, flagp);
        pack_w_kernel<<<64, 256, 0, stream>>>(wk, wfk, flagp);
        pack_w_kernel<<<64, 256, 0, stream>>>(wv, wfv, flagp);
        pack_w_kernel<<<64, 256, 0, stream>>>(wo, wfo, flagp);
        pack_w_kernel<<<64, 256, 0, stream>>>(wp, wfp, flagp);

        pack_a_kernel<true><<<64, 256, 0, stream>>>(model_embed, 1, statsQ, ln1w, ln1b, fragA, flagp);
        mfma_gemm_kernel<<<dim3(8, 16), 256, 0, stream>>>(fragA, wfq, bq, qp, flagp);
        pack_a_kernel<true><<<512, 256, 0, stream>>>(ctx_key, 1, statsK, ln2w, ln2b, fragA, flagp);
        mfma_gemm_kernel<<<dim3(8, 128), 256, 0, stream>>>(fragA, wfk, bk, kp, flagp);
        pack_a_kernel<true><<<128, 256, 0, stream>>>(ctx_val, 1, statsV, ln3w, ln3b, fragA, flagp);
        mfma_gemm_kernel<<<dim3(8, 32), 256, 0, stream>>>(fragA, wfv, bv, vp, flagp);

        pack_frag_kernel<<<dim3(32, 8), 256, 0, stream>>>(qp, qf, 1024);
        pack_frag_kernel<<<dim3(256, 8), 256, 0, stream>>>(kp, kf, 8192);
        pack_v_kernel<<<dim3(64, 8), 256, 0, stream>>>(vp, (uint4*)vfr);
        attn_fused_kernel<<<512, 256, 0, stream>>>(qf, kf, (uint4*)vfr, pacc2, pm2, pl2);
        attn_merge2_kernel<<<128, 256, 0, stream>>>(pacc2, pm2, pl2, att);

        pack_a_kernel<false><<<64, 256, 0, stream>>>(att, 0, nullptr, nullptr, nullptr, fragA, flagp);
        mfma_gemm_kernel<<<dim3(8, 16), 256, 0, stream>>>(fragA, wfo, bo, o1, flagp);
        row_stats_kernel<<<1024, 256, 0, stream>>>(o1, 0, statsO, flagp);
        pack_a_kernel<true><<<64, 256, 0, stream>>>(o1, 0, statsO, ln4w, ln4b, fragA, flagp);
        mfma_gemm_kernel<<<dim3(8, 16), 256, 0, stream>>>(fragA, wfp, bp, (float*)d_out, flagp);
    } else {
        gemm_ln_kernel<true><<<dim3(8, 16), 256, 0, stream>>>(model_embed, 1, statsQ, ln1w, ln1b, wq, bq, qp, flagp);
        gemm_ln_kernel<true><<<dim3(8, 128), 256, 0, stream>>>(ctx_key, 1, statsK, ln2w, ln2b, wk, bk, kp, flagp);
        gemm_ln_kernel<true><<<dim3(8, 32), 256, 0, stream>>>(ctx_val, 1, statsV, ln3w, ln3b, wv, bv, vp, flagp);

        pack_frag_kernel<<<dim3(32, 8), 256, 0, stream>>>(qp, qf, 1024);
        pack_frag_kernel<<<dim3(256, 8), 256, 0, stream>>>(kp, kf, 8192);
        score_mfma_kernel<<<dim3(128, 16, 8), 256, 0, stream>>>(qf, kf, Sm);
        softmax_kernel<<<8192, 256, 0, stream>>>(Sm);
        pv_part_kernel<<<dim3(16, 8, NSEG), 256, 0, stream>>>(Sm, vp, kT);
        pv_reduce_kernel<<<512, 256, 0, stream>>>(kT, att);

        gemm_ln_kernel<false><<<dim3(8, 16), 256, 0, stream>>>(att, 0, nullptr, nullptr, nullptr, wo, bo, o1, flagp);
        row_stats_kernel<<<1024, 256, 0, stream>>>(o1, 0, statsO, flagp);
        gemm_ln_kernel<true><<<dim3(8, 16), 256, 0, stream>>>(o1, 0, statsO, ln4w, ln4b, wp, bp, (float*)d_out, flagp);
    }
}

// Round 13
// 310.707 us; speedup vs baseline: 16.4613x; 1.1242x over previous
//
#include <hip/hip_runtime.h>
#include <hip/hip_bf16.h>

using bf16 = __hip_bfloat16;

#define D_DIM 512
#define C_DIM 2048
#define U_DIM 4
#define DK 64

typedef __attribute__((ext_vector_type(8))) short short8;
typedef __attribute__((ext_vector_type(4))) float f32x4;

__device__ __forceinline__ float dload(const void* p, size_t i, int f) {
    return f ? ((const float*)p)[i] : __bfloat162float(((const bf16*)p)[i]);
}
__device__ __forceinline__ unsigned f2bf(float x) {
    bf16 b = __float2bfloat16(x);
    return (unsigned)*(unsigned short*)&b;
}

// ---------------------------------------------------------------------------
__global__ void detect_kernel(const void* __restrict__ x, int* __restrict__ flag) {
    const bf16* xb = (const bf16*)x;
    int tid = threadIdx.x;
    int cnt = 0;
    for (int i = tid; i < 8192; i += 256) {
        float a = fabsf(__bfloat162float(xb[i]));
        if (!(a <= 100.0f)) cnt++;
    }
    #pragma unroll
    for (int o = 32; o > 0; o >>= 1) cnt += __shfl_down(cnt, o);
    __shared__ int sred[4];
    if ((tid & 63) == 0) sred[tid >> 6] = cnt;
    __syncthreads();
    if (tid == 0) {
        int c = sred[0] + sred[1] + sred[2] + sred[3];
        *flag = (c > 400) ? 1 : 0;
    }
}

// ---------------------------------------------------------------------------
// Pack activation [M][512] into bf16 A-fragments, with LN stats computed
// IN-KERNEL (16 threads own one row; shfl_xor 1/2/4/8 reduce within the
// 16-lane group). Replaces row_stats + pack_a pair (round-12 postmortem).
// ---------------------------------------------------------------------------
template <bool LN>
__global__ __launch_bounds__(256, 1)
void pack_a_kernel(const void* __restrict__ X, int x_raw,
                   const void* __restrict__ lnw, const void* __restrict__ lnb,
                   uint4* __restrict__ Af, const int* __restrict__ flagp) {
    int f = *flagp;
    int xf = x_raw ? f : 1;
    int tt = blockIdx.x;
    int m = threadIdx.x >> 4;
    int kbL = threadIdx.x & 15;
    int row = tt * 16 + m;
    float v[32];
    float s = 0.0f, ss = 0.0f;
    #pragma unroll
    for (int i = 0; i < 4; ++i) {
        int k0 = (kbL + i * 16) * 8;
        #pragma unroll
        for (int j = 0; j < 8; ++j) {
            float x = dload(X, (size_t)row * D_DIM + k0 + j, xf);
            v[i * 8 + j] = x;
            s += x; ss += x * x;
        }
    }
    float mu = 0.0f, rs = 1.0f;
    if (LN) {
        #pragma unroll
        for (int o = 1; o < 16; o <<= 1) { s += __shfl_xor(s, o); ss += __shfl_xor(ss, o); }
        mu = s * (1.0f / D_DIM);
        float var = ss * (1.0f / D_DIM) - mu * mu;
        rs = rsqrtf(var + 1e-5f);
    }
    #pragma unroll
    for (int i = 0; i < 4; ++i) {
        int kb = kbL + i * 16;
        unsigned pk[4];
        #pragma unroll
        for (int jp = 0; jp < 4; ++jp) {
            int k0 = kb * 8 + jp * 2;
            float v0 = v[i * 8 + jp * 2];
            float v1 = v[i * 8 + jp * 2 + 1];
            if (LN) {
                v0 = (v0 - mu) * rs * dload(lnw, k0, f) + dload(lnb, k0, f);
                v1 = (v1 - mu) * rs * dload(lnw, k0 + 1, f) + dload(lnb, k0 + 1, f);
            }
            pk[jp] = f2bf(v0) | (f2bf(v1) << 16);
        }
        uint4 wv = {pk[0], pk[1], pk[2], pk[3]};
        Af[((size_t)tt * 64 + kb) * 16 + m] = wv;
    }
}

// ---------------------------------------------------------------------------
// Pack weight W[k=512][n=512] into bf16 B-fragments (transposed).
// ---------------------------------------------------------------------------
__global__ void pack_w_kernel(const void* __restrict__ W, uint4* __restrict__ Bf,
                              const int* __restrict__ flagp) {
    __shared__ float t[64][65];
    int f = *flagp;
    int b = blockIdx.x;
    int n0 = (b & 7) * 64, k0 = (b >> 3) * 64;
    int tid = threadIdx.x;
    for (int i = 0; i < 16; ++i) {
        int e = i * 256 + tid;
        int r = e >> 6, c = e & 63;
        t[r][c] = dload(W, (size_t)(k0 + r) * D_DIM + n0 + c, f);
    }
    __syncthreads();
    #pragma unroll
    for (int i = 0; i < 2; ++i) {
        int e = i * 256 + tid;
        int nl = e & 63, kbl = e >> 6;
        unsigned pk[4];
        #pragma unroll
        for (int jp = 0; jp < 4; ++jp)
            pk[jp] = f2bf(t[kbl * 8 + jp * 2][nl]) | (f2bf(t[kbl * 8 + jp * 2 + 1][nl]) << 16);
        uint4 wv = {pk[0], pk[1], pk[2], pk[3]};
        int n = n0 + nl;
        Bf[(((size_t)(n >> 4)) * 64 + (k0 / 8 + kbl)) * 16 + (n & 15)] = wv;
    }
}

// ---------------------------------------------------------------------------
// Fragment MFMA GEMM with templated epilogue (round-12 postmortem: kill the
// fp32 Y round-trip). OUT=0: fp32 Y. OUT=1: score-frag layout (q/k), head =
// blockIdx.x, Rtt = rows/16. OUT=2: PV B-frag layout (v).
// ---------------------------------------------------------------------------
template <int OUT>
__global__ __launch_bounds__(256, 1)
void mfma_gemm_kernel(const uint4* __restrict__ Af, const uint4* __restrict__ Bf,
                      const void* __restrict__ bias, float* __restrict__ Y,
                      uint4* __restrict__ Fout, int Rtt,
                      const int* __restrict__ flagp) {
    __shared__ float t[64][65];
    int f = *flagp;
    int w = threadIdx.x >> 6, lane = threadIdx.x & 63;
    int q = lane >> 4, mn = lane & 15;
    int mt = blockIdx.y * 4 + w;
    int nt0 = blockIdx.x * 4;
    f32x4 acc[4] = {{0.f,0.f,0.f,0.f},{0.f,0.f,0.f,0.f},{0.f,0.f,0.f,0.f},{0.f,0.f,0.f,0.f}};
    for (int kw = 0; kw < 16; ++kw) {
        short8 a = *(const short8*)(Af + ((size_t)mt * 64 + kw * 4 + q) * 16 + mn);
        #pragma unroll
        for (int i = 0; i < 4; ++i) {
            short8 b = *(const short8*)(Bf + (((size_t)(nt0 + i)) * 64 + kw * 4 + q) * 16 + mn);
            acc[i] = __builtin_amdgcn_mfma_f32_16x16x32_bf16(a, b, acc[i], 0, 0, 0);
        }
    }
    if constexpr (OUT == 0) {
        #pragma unroll
        for (int i = 0; i < 4; ++i) {
            int col = (nt0 + i) * 16 + mn;
            float bv = dload(bias, col, f);
            #pragma unroll
            for (int r = 0; r < 4; ++r)
                Y[(size_t)(mt * 16 + q * 4 + r) * D_DIM + col] = acc[i][r] + bv;
        }
    } else {
        #pragma unroll
        for (int i = 0; i < 4; ++i) {
            float bv = dload(bias, (nt0 + i) * 16 + mn, f);
            #pragma unroll
            for (int r = 0; r < 4; ++r)
                t[w * 16 + q * 4 + r][i * 16 + mn] = acc[i][r] + bv;
        }
        __syncthreads();
        int h = blockIdx.x;
        if constexpr (OUT == 1) {
            // score-frag: Fout[((h*Rtt + tt)*8 + kb)*16 + m] = row tt*16+m, k kb*8..+7
            #pragma unroll
            for (int e0 = 0; e0 < 2; ++e0) {
                int e = e0 * 256 + threadIdx.x;
                int m = e & 15, kb = (e >> 4) & 7, ttl = e >> 7;
                const float* src = &t[ttl * 16 + m][kb * 8];
                uint4 wv;
                wv.x = f2bf(src[0]) | (f2bf(src[1]) << 16);
                wv.y = f2bf(src[2]) | (f2bf(src[3]) << 16);
                wv.z = f2bf(src[4]) | (f2bf(src[5]) << 16);
                wv.w = f2bf(src[6]) | (f2bf(src[7]) << 16);
                Fout[(((size_t)h * Rtt + blockIdx.y * 4 + ttl) * 8 + kb) * 16 + m] = wv;
            }
        } else {
            // PV B-frag: Fout[((h*64+ct)*4+nt)*64+lane2]; k = ctx, n = dim
            #pragma unroll
            for (int e0 = 0; e0 < 2; ++e0) {
                int e = e0 * 256 + threadIdx.x;
                int lane2 = e & 63, nt = (e >> 6) & 3, ctl = e >> 8;
                int nm2 = lane2 & 15, q2 = lane2 >> 4;
                int col = nt * 16 + nm2;
                int rb = ctl * 32 + q2 * 8;
                uint4 wv;
                wv.x = f2bf(t[rb + 0][col]) | (f2bf(t[rb + 1][col]) << 16);
                wv.y = f2bf(t[rb + 2][col]) | (f2bf(t[rb + 3][col]) << 16);
                wv.z = f2bf(t[rb + 4][col]) | (f2bf(t[rb + 5][col]) << 16);
                wv.w = f2bf(t[rb + 6][col]) | (f2bf(t[rb + 7][col]) << 16);
                Fout[(((size_t)h * 64 + blockIdx.y * 2 + ctl) * 4 + nt) * 64 + lane2] = wv;
            }
        }
    }
}

// ---------------------------------------------------------------------------
// FUSED MFMA flash attention, 8 c-splits (round-12 postmortem: occupancy).
// Grid 1024 = 16 q-blocks x 8 heads x 8 c-splits; 4 blocks/CU.
// ---------------------------------------------------------------------------
__global__ __launch_bounds__(256, 1)
void attn_fused_kernel(const uint4* __restrict__ qf, const uint4* __restrict__ kf,
                       const uint4* __restrict__ vf,
                       float* __restrict__ pacc, float* __restrict__ pm,
                       float* __restrict__ pl) {
    __shared__ float sp[4][16][36];
    int tid = threadIdx.x;
    int w = tid >> 6, lane = tid & 63;
    int q = lane >> 4, nm = lane & 15;
    int b = blockIdx.x;
    int s = b & 7;
    int h = (b >> 3) & 7;
    int qb = b >> 6;
    int mt = qb * 4 + w;

    short8 a0 = *(const short8*)(qf + (((size_t)h * 64 + mt) * 8 + q) * 16 + nm);
    short8 a1 = *(const short8*)(qf + (((size_t)h * 64 + mt) * 8 + 4 + q) * 16 + nm);

    float mrow[4], lrow[4];
    f32x4 acc_o[4] = {{0.f,0.f,0.f,0.f},{0.f,0.f,0.f,0.f},{0.f,0.f,0.f,0.f},{0.f,0.f,0.f,0.f}};
    #pragma unroll
    for (int r = 0; r < 4; ++r) { mrow[r] = -1e30f; lrow[r] = 0.0f; }

    for (int ct = s * 8; ct < s * 8 + 8; ++ct) {
        float sc[8][4];
        #pragma unroll
        for (int i = 0; i < 8; ++i) {
            int nt = ct * 8 + i;
            short8 b0 = *(const short8*)(kf + (((size_t)h * 512 + nt) * 8 + q) * 16 + nm);
            short8 b1 = *(const short8*)(kf + (((size_t)h * 512 + nt) * 8 + 4 + q) * 16 + nm);
            f32x4 acc = {0.0f, 0.0f, 0.0f, 0.0f};
            acc = __builtin_amdgcn_mfma_f32_16x16x32_bf16(a0, b0, acc, 0, 0, 0);
            acc = __builtin_amdgcn_mfma_f32_16x16x32_bf16(a1, b1, acc, 0, 0, 0);
            #pragma unroll
            for (int r = 0; r < 4; ++r) {
                float v = acc[r];
                v = fmaxf(v, __shfl_xor(v, 1));
                v = fmaxf(v, __shfl_xor(v, 2));
                sc[i][r] = v * 0.125f;
            }
        }
        #pragma unroll
        for (int r = 0; r < 4; ++r) {
            float tmax = sc[0][r];
            #pragma unroll
            for (int i = 1; i < 8; ++i) tmax = fmaxf(tmax, sc[i][r]);
            tmax = fmaxf(tmax, __shfl_xor(tmax, 4));
            tmax = fmaxf(tmax, __shfl_xor(tmax, 8));
            float mnew = fmaxf(mrow[r], tmax);
            float alpha = __expf(mrow[r] - mnew);
            mrow[r] = mnew;
            float ps = 0.0f;
            float pv[8];
            #pragma unroll
            for (int i = 0; i < 8; ++i) { pv[i] = __expf(sc[i][r] - mnew); ps += pv[i]; }
            if ((nm & 3) == 0) {
                #pragma unroll
                for (int i = 0; i < 8; ++i) sp[w][q * 4 + r][i * 4 + (nm >> 2)] = pv[i];
            } else ps = 0.0f;
            ps += __shfl_xor(ps, 1);
            ps += __shfl_xor(ps, 2);
            ps += __shfl_xor(ps, 4);
            ps += __shfl_xor(ps, 8);
            lrow[r] = lrow[r] * alpha + ps;
            acc_o[0][r] *= alpha; acc_o[1][r] *= alpha;
            acc_o[2][r] *= alpha; acc_o[3][r] *= alpha;
        }
        float4 pa0 = *(const float4*)&sp[w][nm][q * 8];
        float4 pa1 = *(const float4*)&sp[w][nm][q * 8 + 4];
        uint4 av;
        av.x = f2bf(pa0.x) | (f2bf(pa0.y) << 16);
        av.y = f2bf(pa0.z) | (f2bf(pa0.w) << 16);
        av.z = f2bf(pa1.x) | (f2bf(pa1.y) << 16);
        av.w = f2bf(pa1.z) | (f2bf(pa1.w) << 16);
        short8 ap = *(short8*)&av;
        #pragma unroll
        for (int nt2 = 0; nt2 < 4; ++nt2) {
            short8 bv = *(const short8*)(vf + (((size_t)h * 64 + ct) * 4 + nt2) * 64 + lane);
            acc_o[nt2] = __builtin_amdgcn_mfma_f32_16x16x32_bf16(ap, bv, acc_o[nt2], 0, 0, 0);
        }
    }

    int p_idx = ((qb * 8 + h) << 3) + s;
    float* po = pacc + ((size_t)p_idx * 64 + w * 16) * 64;
    #pragma unroll
    for (int nt2 = 0; nt2 < 4; ++nt2)
        #pragma unroll
        for (int r = 0; r < 4; ++r)
            po[(q * 4 + r) * 64 + nt2 * 16 + nm] = acc_o[nt2][r];
    if (nm == 0) {
        #pragma unroll
        for (int r = 0; r < 4; ++r) {
            pm[p_idx * 64 + w * 16 + q * 4 + r] = mrow[r];
            pl[p_idx * 64 + w * 16 + q * 4 + r] = lrow[r];
        }
    }
}

// Merge 8 c-split partials and emit wo-GEMM A-fragments directly.
__global__ void attn_merge2_kernel(const float* __restrict__ pacc, const float* __restrict__ pm,
                                   const float* __restrict__ pl, uint4* __restrict__ oAf) {
    int b = blockIdx.x;                // qb*8 + h
    int qb = b >> 3, h = b & 7;
    int tid = threadIdx.x;
    int t_loc = tid & 63, dg = tid >> 6;
    int p0 = b * 8;
    float M = -1e30f;
    #pragma unroll
    for (int s = 0; s < 8; ++s) M = fmaxf(M, pm[(p0 + s) * 64 + t_loc]);
    float L = 0.0f;
    float4 o[4] = {};
    #pragma unroll
    for (int s = 0; s < 8; ++s) {
        float e = __expf(pm[(p0 + s) * 64 + t_loc] - M);
        L += pl[(p0 + s) * 64 + t_loc] * e;
        const float4* po = (const float4*)(pacc + ((size_t)(p0 + s) * 64 + t_loc) * 64 + dg * 16);
        #pragma unroll
        for (int d = 0; d < 4; ++d) {
            float4 v = po[d];
            o[d].x += v.x * e; o[d].y += v.y * e; o[d].z += v.z * e; o[d].w += v.w * e;
        }
    }
    float inv = 1.0f / L;
    int t = qb * 64 + t_loc;
    int tt = t >> 4, m = t & 15;
    int kb0 = h * 8 + dg * 2;
    uint4 u0, u1;
    u0.x = f2bf(o[0].x * inv) | (f2bf(o[0].y * inv) << 16);
    u0.y = f2bf(o[0].z * inv) | (f2bf(o[0].w * inv) << 16);
    u0.z = f2bf(o[1].x * inv) | (f2bf(o[1].y * inv) << 16);
    u0.w = f2bf(o[1].z * inv) | (f2bf(o[1].w * inv) << 16);
    u1.x = f2bf(o[2].x * inv) | (f2bf(o[2].y * inv) << 16);
    u1.y = f2bf(o[2].z * inv) | (f2bf(o[2].w * inv) << 16);
    u1.z = f2bf(o[3].x * inv) | (f2bf(o[3].y * inv) << 16);
    u1.w = f2bf(o[3].z * inv) | (f2bf(o[3].w * inv) << 16);
    oAf[((size_t)tt * 64 + kb0) * 16 + m] = u0;
    oAf[((size_t)tt * 64 + kb0 + 1) * 16 + m] = u1;
}

extern "C" void kernel_launch(void* const* d_in, const int* in_sizes, int n_in,
                              void* d_out, int out_size, void* d_ws, size_t ws_size,
                              hipStream_t stream) {
    const void* model_embed = d_in[0];
    const void* ctx_key     = d_in[1];
    const void* ctx_val     = d_in[2];
    const void* ln1w = d_in[3];  const void* ln1b = d_in[4];
    const void* ln2w = d_in[5];  const void* ln2b = d_in[6];
    const void* ln3w = d_in[7];  const void* ln3b = d_in[8];
    const void* ln4w = d_in[9];  const void* ln4b = d_in[10];
    const void* wq = d_in[11];   const void* bq = d_in[12];
    const void* wk = d_in[13];   const void* bk = d_in[14];
    const void* wv = d_in[15];   const void* bv = d_in[16];
    const void* wo = d_in[17];   const void* bo = d_in[18];
    const void* wp = d_in[19];   const void* bp = d_in[20];

    int*   flagp  = (int*)d_ws;
    float* ws     = (float*)d_ws + 16;
    float* qp     = ws;                    // legacy region (kept for layout stability)
    float* kp     = qp + 524288;
    float* vp     = kp + 4194304;
    float* att    = vp + 1048576;
    float* o1     = att + 524288;          // fp32 o1 (wo output)
    float* statsQ = o1 + 524288;
    float* ext    = statsQ + 2048 + 16384 + 4096 + 2048;

    float* qT = ext;                       // qf: score q-frags (1 MB)
    float* kT = qT + 524288;               // kf: score k-frags (8 MB)
    float* Sm = kT + 4194304;              // 64 MB scratch region, carved:
    float* wfrag = Sm + 16777216;          // 5 x W-frags (2.5 MB)

    uint4* fragA = (uint4*)Sm;                  // projection A-frags (8 MB)
    float* vfr   = Sm + 2097152;                // V B-frags (2 MB); later oAf
    float* pacc2 = Sm + 2621440;                // 16 MB partials (8 splits)
    float* pm2   = pacc2 + 4194304;             // 65536
    float* pl2   = pm2 + 65536;                 // 65536

    detect_kernel<<<1, 256, 0, stream>>>(model_embed, flagp);

    uint4* wfq = (uint4*)wfrag;
    uint4* wfk = wfq + 32768;
    uint4* wfv = wfk + 32768;
    uint4* wfo = wfv + 32768;
    uint4* wfp = wfo + 32768;
    uint4* qf = (uint4*)qT;
    uint4* kf = (uint4*)kT;
    uint4* vf = (uint4*)vfr;
    uint4* oAf = (uint4*)vfr;              // reuse after attn_fused consumes vf

    pack_w_kernel<<<64, 256, 0, stream>>>(wq, wfq, flagp);
    pack_w_kernel<<<64, 256, 0, stream>>>(wk, wfk, flagp);
    pack_w_kernel<<<64, 256, 0, stream>>>(wv, wfv, flagp);
    pack_w_kernel<<<64, 256, 0, stream>>>(wo, wfo, flagp);
    pack_w_kernel<<<64, 256, 0, stream>>>(wp, wfp, flagp);

    // Q/K/V projections: LN-fused A-pack -> MFMA GEMM -> fragment-direct out
    pack_a_kernel<true><<<64, 256, 0, stream>>>(model_embed, 1, ln1w, ln1b, fragA, flagp);
    mfma_gemm_kernel<1><<<dim3(8, 16), 256, 0, stream>>>(fragA, wfq, bq, nullptr, qf, 64, flagp);
    pack_a_kernel<true><<<512, 256, 0, stream>>>(ctx_key, 1, ln2w, ln2b, fragA, flagp);
    mfma_gemm_kernel<1><<<dim3(8, 128), 256, 0, stream>>>(fragA, wfk, bk, nullptr, kf, 512, flagp);
    pack_a_kernel<true><<<128, 256, 0, stream>>>(ctx_val, 1, ln3w, ln3b, fragA, flagp);
    mfma_gemm_kernel<2><<<dim3(8, 32), 256, 0, stream>>>(fragA, wfv, bv, nullptr, vf, 0, flagp);

    attn_fused_kernel<<<1024, 256, 0, stream>>>(qf, kf, vf, pacc2, pm2, pl2);
    attn_merge2_kernel<<<128, 256, 0, stream>>>(pacc2, pm2, pl2, oAf);

    mfma_gemm_kernel<0><<<dim3(8, 16), 256, 0, stream>>>(oAf, wfo, bo, o1, nullptr, 0, flagp);
    pack_a_kernel<true><<<64, 256, 0, stream>>>(o1, 0, ln4w, ln4b, fragA, flagp);
    mfma_gemm_kernel<0><<<dim3(8, 16), 256, 0, stream>>>(fragA, wfp, bp, (float*)d_out, nullptr, 0, flagp);

    (void)qp; (void)kp; (void)vp; (void)att; (void)ws_size;
}

// Round 14
// 263.002 us; speedup vs baseline: 19.4471x; 1.1814x over previous
//
#include <hip/hip_runtime.h>
#include <hip/hip_bf16.h>

using bf16 = __hip_bfloat16;

#define D_DIM 512
#define C_DIM 2048
#define U_DIM 4
#define DK 64

typedef __attribute__((ext_vector_type(8))) short short8;
typedef __attribute__((ext_vector_type(4))) float f32x4;

__device__ __forceinline__ float dload(const void* p, size_t i, int f) {
    return f ? ((const float*)p)[i] : __bfloat162float(((const bf16*)p)[i]);
}
__device__ __forceinline__ unsigned f2bf(float x) {
    bf16 b = __float2bfloat16(x);
    return (unsigned)*(unsigned short*)&b;
}

// ---------------------------------------------------------------------------
__global__ void detect_kernel(const void* __restrict__ x, int* __restrict__ flag) {
    const bf16* xb = (const bf16*)x;
    int tid = threadIdx.x;
    int cnt = 0;
    for (int i = tid; i < 8192; i += 256) {
        float a = fabsf(__bfloat162float(xb[i]));
        if (!(a <= 100.0f)) cnt++;
    }
    #pragma unroll
    for (int o = 32; o > 0; o >>= 1) cnt += __shfl_down(cnt, o);
    __shared__ int sred[4];
    if ((tid & 63) == 0) sred[tid >> 6] = cnt;
    __syncthreads();
    if (tid == 0) {
        int c = sred[0] + sred[1] + sred[2] + sred[3];
        *flag = (c > 400) ? 1 : 0;
    }
}

// ---------------------------------------------------------------------------
// A-fragment pack body: LN stats in-register (16 lanes per row, shfl reduce).
// ---------------------------------------------------------------------------
template <bool LN>
__device__ __forceinline__ void pack_a_body(const void* __restrict__ X, int xf, int f,
                                            const void* __restrict__ lnw,
                                            const void* __restrict__ lnb,
                                            uint4* __restrict__ Af, int tt) {
    int m = threadIdx.x >> 4;
    int kbL = threadIdx.x & 15;
    int row = tt * 16 + m;
    float v[32];
    float s = 0.0f, ss = 0.0f;
    #pragma unroll
    for (int i = 0; i < 4; ++i) {
        int k0 = (kbL + i * 16) * 8;
        #pragma unroll
        for (int j = 0; j < 8; ++j) {
            float x = dload(X, (size_t)row * D_DIM + k0 + j, xf);
            v[i * 8 + j] = x;
            s += x; ss += x * x;
        }
    }
    float mu = 0.0f, rs = 1.0f;
    if (LN) {
        #pragma unroll
        for (int o = 1; o < 16; o <<= 1) { s += __shfl_xor(s, o); ss += __shfl_xor(ss, o); }
        mu = s * (1.0f / D_DIM);
        float var = ss * (1.0f / D_DIM) - mu * mu;
        rs = rsqrtf(var + 1e-5f);
    }
    #pragma unroll
    for (int i = 0; i < 4; ++i) {
        int kb = kbL + i * 16;
        unsigned pk[4];
        #pragma unroll
        for (int jp = 0; jp < 4; ++jp) {
            int k0 = kb * 8 + jp * 2;
            float v0 = v[i * 8 + jp * 2];
            float v1 = v[i * 8 + jp * 2 + 1];
            if (LN) {
                v0 = (v0 - mu) * rs * dload(lnw, k0, f) + dload(lnb, k0, f);
                v1 = (v1 - mu) * rs * dload(lnw, k0 + 1, f) + dload(lnb, k0 + 1, f);
            }
            pk[jp] = f2bf(v0) | (f2bf(v1) << 16);
        }
        uint4 wv = {pk[0], pk[1], pk[2], pk[3]};
        Af[((size_t)tt * 64 + kb) * 16 + m] = wv;
    }
}

template <bool LN>
__global__ __launch_bounds__(256, 1)
void pack_a_kernel(const void* __restrict__ X, int x_raw,
                   const void* __restrict__ lnw, const void* __restrict__ lnb,
                   uint4* __restrict__ Af, const int* __restrict__ flagp) {
    int f = *flagp;
    pack_a_body<LN>(X, x_raw ? f : 1, f, lnw, lnb, Af, blockIdx.x);
}

// Combined q/k/v A-pack: ranges [0,64) me, [64,576) ck, [576,704) cv.
__global__ __launch_bounds__(256, 1)
void pack_a3_kernel(const void* __restrict__ me, const void* __restrict__ l1w, const void* __restrict__ l1b,
                    const void* __restrict__ ck, const void* __restrict__ l2w, const void* __restrict__ l2b,
                    const void* __restrict__ cv, const void* __restrict__ l3w, const void* __restrict__ l3b,
                    uint4* __restrict__ Aq, uint4* __restrict__ Ak, uint4* __restrict__ Av,
                    const int* __restrict__ flagp) {
    int f = *flagp;
    int b = blockIdx.x;
    if (b < 64)       pack_a_body<true>(me, f, f, l1w, l1b, Aq, b);
    else if (b < 576) pack_a_body<true>(ck, f, f, l2w, l2b, Ak, b - 64);
    else              pack_a_body<true>(cv, f, f, l3w, l3b, Av, b - 576);
}

// ---------------------------------------------------------------------------
// Pack all 5 weights into bf16 B-fragments (one launch, blockIdx.y selects).
// ---------------------------------------------------------------------------
__global__ void pack_w_kernel(const void* W0, const void* W1, const void* W2,
                              const void* W3, const void* W4,
                              uint4* B0, uint4* B1, uint4* B2, uint4* B3, uint4* B4,
                              const int* __restrict__ flagp) {
    __shared__ float t[64][65];
    const void* Ws[5] = {W0, W1, W2, W3, W4};
    uint4* Bs[5] = {B0, B1, B2, B3, B4};
    const void* W = Ws[blockIdx.y];
    uint4* Bf = Bs[blockIdx.y];
    int f = *flagp;
    int b = blockIdx.x;
    int n0 = (b & 7) * 64, k0 = (b >> 3) * 64;
    int tid = threadIdx.x;
    for (int i = 0; i < 16; ++i) {
        int e = i * 256 + tid;
        int r = e >> 6, c = e & 63;
        t[r][c] = dload(W, (size_t)(k0 + r) * D_DIM + n0 + c, f);
    }
    __syncthreads();
    #pragma unroll
    for (int i = 0; i < 2; ++i) {
        int e = i * 256 + tid;
        int nl = e & 63, kbl = e >> 6;
        unsigned pk[4];
        #pragma unroll
        for (int jp = 0; jp < 4; ++jp)
            pk[jp] = f2bf(t[kbl * 8 + jp * 2][nl]) | (f2bf(t[kbl * 8 + jp * 2 + 1][nl]) << 16);
        uint4 wv = {pk[0], pk[1], pk[2], pk[3]};
        int n = n0 + nl;
        Bf[(((size_t)(n >> 4)) * 64 + (k0 / 8 + kbl)) * 16 + (n & 15)] = wv;
    }
}

// ---------------------------------------------------------------------------
// Fragment MFMA GEMM, templated epilogue:
// OUT=0 fp32 Y; OUT=1 score-frag (q); OUT=2 PV B-frag (v);
// OUT=3 u-split score-B frag (k): nt = ctx_tile*4 + u, 16 contexts/tile at
// fixed u (round-13 postmortem: kills u-max shuffles + 4x redundant exps).
// ---------------------------------------------------------------------------
template <int OUT>
__global__ __launch_bounds__(256, 1)
void mfma_gemm_kernel(const uint4* __restrict__ Af, const uint4* __restrict__ Bf,
                      const void* __restrict__ bias, float* __restrict__ Y,
                      uint4* __restrict__ Fout, int Rtt,
                      const int* __restrict__ flagp) {
    __shared__ float t[64][65];
    int f = *flagp;
    int w = threadIdx.x >> 6, lane = threadIdx.x & 63;
    int q = lane >> 4, mn = lane & 15;
    int mt = blockIdx.y * 4 + w;
    int nt0 = blockIdx.x * 4;
    f32x4 acc[4] = {{0.f,0.f,0.f,0.f},{0.f,0.f,0.f,0.f},{0.f,0.f,0.f,0.f},{0.f,0.f,0.f,0.f}};
    for (int kw = 0; kw < 16; ++kw) {
        short8 a = *(const short8*)(Af + ((size_t)mt * 64 + kw * 4 + q) * 16 + mn);
        #pragma unroll
        for (int i = 0; i < 4; ++i) {
            short8 b = *(const short8*)(Bf + (((size_t)(nt0 + i)) * 64 + kw * 4 + q) * 16 + mn);
            acc[i] = __builtin_amdgcn_mfma_f32_16x16x32_bf16(a, b, acc[i], 0, 0, 0);
        }
    }
    if constexpr (OUT == 0) {
        #pragma unroll
        for (int i = 0; i < 4; ++i) {
            int col = (nt0 + i) * 16 + mn;
            float bv = dload(bias, col, f);
            #pragma unroll
            for (int r = 0; r < 4; ++r)
                Y[(size_t)(mt * 16 + q * 4 + r) * D_DIM + col] = acc[i][r] + bv;
        }
    } else {
        #pragma unroll
        for (int i = 0; i < 4; ++i) {
            float bv = dload(bias, (nt0 + i) * 16 + mn, f);
            #pragma unroll
            for (int r = 0; r < 4; ++r)
                t[w * 16 + q * 4 + r][i * 16 + mn] = acc[i][r] + bv;
        }
        __syncthreads();
        int h = blockIdx.x;
        if constexpr (OUT == 1) {
            #pragma unroll
            for (int e0 = 0; e0 < 2; ++e0) {
                int e = e0 * 256 + threadIdx.x;
                int m = e & 15, kb = (e >> 4) & 7, ttl = e >> 7;
                const float* src = &t[ttl * 16 + m][kb * 8];
                uint4 wv;
                wv.x = f2bf(src[0]) | (f2bf(src[1]) << 16);
                wv.y = f2bf(src[2]) | (f2bf(src[3]) << 16);
                wv.z = f2bf(src[4]) | (f2bf(src[5]) << 16);
                wv.w = f2bf(src[6]) | (f2bf(src[7]) << 16);
                Fout[(((size_t)h * Rtt + blockIdx.y * 4 + ttl) * 8 + kb) * 16 + m] = wv;
            }
        } else if constexpr (OUT == 2) {
            #pragma unroll
            for (int e0 = 0; e0 < 2; ++e0) {
                int e = e0 * 256 + threadIdx.x;
                int lane2 = e & 63, nt = (e >> 6) & 3, ctl = e >> 8;
                int nm2 = lane2 & 15, q2 = lane2 >> 4;
                int col = nt * 16 + nm2;
                int rb = ctl * 32 + q2 * 8;
                uint4 wv;
                wv.x = f2bf(t[rb + 0][col]) | (f2bf(t[rb + 1][col]) << 16);
                wv.y = f2bf(t[rb + 2][col]) | (f2bf(t[rb + 3][col]) << 16);
                wv.z = f2bf(t[rb + 4][col]) | (f2bf(t[rb + 5][col]) << 16);
                wv.w = f2bf(t[rb + 6][col]) | (f2bf(t[rb + 7][col]) << 16);
                Fout[(((size_t)h * 64 + blockIdx.y * 2 + ctl) * 4 + nt) * 64 + lane2] = wv;
            }
        } else {
            // OUT=3: rows are krows (ctx*4+u); contexts blockIdx.y*16..+15.
            #pragma unroll
            for (int e0 = 0; e0 < 2; ++e0) {
                int e = e0 * 256 + threadIdx.x;
                int m2 = e & 15, kb = (e >> 4) & 7, u = e >> 7;
                const float* src = &t[m2 * 4 + u][kb * 8];
                uint4 wv;
                wv.x = f2bf(src[0]) | (f2bf(src[1]) << 16);
                wv.y = f2bf(src[2]) | (f2bf(src[3]) << 16);
                wv.z = f2bf(src[4]) | (f2bf(src[5]) << 16);
                wv.w = f2bf(src[6]) | (f2bf(src[7]) << 16);
                int nt = blockIdx.y * 4 + u;
                Fout[(((size_t)h * 512 + nt) * 8 + kb) * 16 + m2] = wv;
            }
        }
    }
}

// ---------------------------------------------------------------------------
// FUSED MFMA flash attention, u-split layout. Grid 1024 = 16 qb x 8 h x 8 s.
// Per 32-ctx super-tile: 2 halves x 4 u-MFMA-pairs -> elementwise MaxSim ->
// online softmax (each lane owns DISTINCT contexts; 12 exps, 32 shfl) ->
// P via per-wave LDS -> 4 PV MFMAs (K=32).
// ---------------------------------------------------------------------------
__global__ __launch_bounds__(256, 1)
void attn_fused_kernel(const uint4* __restrict__ qf, const uint4* __restrict__ kf,
                       const uint4* __restrict__ vf,
                       float* __restrict__ pacc, float* __restrict__ pm,
                       float* __restrict__ pl) {
    __shared__ float sp[4][16][36];
    int tid = threadIdx.x;
    int w = tid >> 6, lane = tid & 63;
    int q = lane >> 4, nm = lane & 15;
    int b = blockIdx.x;
    int s = b & 7;
    int h = (b >> 3) & 7;
    int qb = b >> 6;
    int mt = qb * 4 + w;

    short8 a0 = *(const short8*)(qf + (((size_t)h * 64 + mt) * 8 + q) * 16 + nm);
    short8 a1 = *(const short8*)(qf + (((size_t)h * 64 + mt) * 8 + 4 + q) * 16 + nm);

    float mrow[4], lrow[4];
    f32x4 acc_o[4] = {{0.f,0.f,0.f,0.f},{0.f,0.f,0.f,0.f},{0.f,0.f,0.f,0.f},{0.f,0.f,0.f,0.f}};
    #pragma unroll
    for (int r = 0; r < 4; ++r) { mrow[r] = -1e30f; lrow[r] = 0.0f; }

    for (int st = 0; st < 8; ++st) {
        int ct32 = s * 8 + st;
        f32x4 sc[2];
        #pragma unroll
        for (int hh = 0; hh < 2; ++hh) {
            int ct16 = ct32 * 2 + hh;
            f32x4 scv = {-1e30f, -1e30f, -1e30f, -1e30f};
            #pragma unroll
            for (int u = 0; u < 4; ++u) {
                int nt = ct16 * 4 + u;
                short8 b0 = *(const short8*)(kf + (((size_t)h * 512 + nt) * 8 + q) * 16 + nm);
                short8 b1 = *(const short8*)(kf + (((size_t)h * 512 + nt) * 8 + 4 + q) * 16 + nm);
                f32x4 acc = {0.0f, 0.0f, 0.0f, 0.0f};
                acc = __builtin_amdgcn_mfma_f32_16x16x32_bf16(a0, b0, acc, 0, 0, 0);
                acc = __builtin_amdgcn_mfma_f32_16x16x32_bf16(a1, b1, acc, 0, 0, 0);
                #pragma unroll
                for (int r = 0; r < 4; ++r) scv[r] = fmaxf(scv[r], acc[r]);
            }
            #pragma unroll
            for (int r = 0; r < 4; ++r) sc[hh][r] = scv[r] * 0.125f;   // 1/sqrt(dk)
        }
        #pragma unroll
        for (int r = 0; r < 4; ++r) {
            float lmax = fmaxf(sc[0][r], sc[1][r]);
            lmax = fmaxf(lmax, __shfl_xor(lmax, 1));
            lmax = fmaxf(lmax, __shfl_xor(lmax, 2));
            lmax = fmaxf(lmax, __shfl_xor(lmax, 4));
            lmax = fmaxf(lmax, __shfl_xor(lmax, 8));
            float mnew = fmaxf(mrow[r], lmax);
            float alpha = __expf(mrow[r] - mnew);
            mrow[r] = mnew;
            float p0 = __expf(sc[0][r] - mnew);
            float p1 = __expf(sc[1][r] - mnew);
            sp[w][q * 4 + r][nm] = p0;
            sp[w][q * 4 + r][16 + nm] = p1;
            float ps = p0 + p1;
            ps += __shfl_xor(ps, 1);
            ps += __shfl_xor(ps, 2);
            ps += __shfl_xor(ps, 4);
            ps += __shfl_xor(ps, 8);
            lrow[r] = lrow[r] * alpha + ps;
            acc_o[0][r] *= alpha; acc_o[1][r] *= alpha;
            acc_o[2][r] *= alpha; acc_o[3][r] *= alpha;
        }
        // P A-fragment (K=32) from per-wave LDS (same-wave RAW, validated)
        float4 pa0 = *(const float4*)&sp[w][nm][q * 8];
        float4 pa1 = *(const float4*)&sp[w][nm][q * 8 + 4];
        uint4 av;
        av.x = f2bf(pa0.x) | (f2bf(pa0.y) << 16);
        av.y = f2bf(pa0.z) | (f2bf(pa0.w) << 16);
        av.z = f2bf(pa1.x) | (f2bf(pa1.y) << 16);
        av.w = f2bf(pa1.z) | (f2bf(pa1.w) << 16);
        short8 ap = *(short8*)&av;
        #pragma unroll
        for (int nt2 = 0; nt2 < 4; ++nt2) {
            short8 bv = *(const short8*)(vf + (((size_t)h * 64 + ct32) * 4 + nt2) * 64 + lane);
            acc_o[nt2] = __builtin_amdgcn_mfma_f32_16x16x32_bf16(ap, bv, acc_o[nt2], 0, 0, 0);
        }
    }

    int p_idx = ((qb * 8 + h) << 3) + s;
    float* po = pacc + ((size_t)p_idx * 64 + w * 16) * 64;
    #pragma unroll
    for (int nt2 = 0; nt2 < 4; ++nt2)
        #pragma unroll
        for (int r = 0; r < 4; ++r)
            po[(q * 4 + r) * 64 + nt2 * 16 + nm] = acc_o[nt2][r];
    if (nm == 0) {
        #pragma unroll
        for (int r = 0; r < 4; ++r) {
            pm[p_idx * 64 + w * 16 + q * 4 + r] = mrow[r];
            pl[p_idx * 64 + w * 16 + q * 4 + r] = lrow[r];
        }
    }
}

// Merge 8 c-split partials; emit wo-GEMM A-fragments directly.
__global__ void attn_merge2_kernel(const float* __restrict__ pacc, const float* __restrict__ pm,
                                   const float* __restrict__ pl, uint4* __restrict__ oAf) {
    int b = blockIdx.x;                // qb*8 + h
    int qb = b >> 3, h = b & 7;
    int tid = threadIdx.x;
    int t_loc = tid & 63, dg = tid >> 6;
    int p0 = b * 8;
    float M = -1e30f;
    #pragma unroll
    for (int s = 0; s < 8; ++s) M = fmaxf(M, pm[(p0 + s) * 64 + t_loc]);
    float L = 0.0f;
    float4 o[4] = {};
    #pragma unroll
    for (int s = 0; s < 8; ++s) {
        float e = __expf(pm[(p0 + s) * 64 + t_loc] - M);
        L += pl[(p0 + s) * 64 + t_loc] * e;
        const float4* po = (const float4*)(pacc + ((size_t)(p0 + s) * 64 + t_loc) * 64 + dg * 16);
        #pragma unroll
        for (int d = 0; d < 4; ++d) {
            float4 v = po[d];
            o[d].x += v.x * e; o[d].y += v.y * e; o[d].z += v.z * e; o[d].w += v.w * e;
        }
    }
    float inv = 1.0f / L;
    int t = qb * 64 + t_loc;
    int tt = t >> 4, m = t & 15;
    int kb0 = h * 8 + dg * 2;
    uint4 u0, u1;
    u0.x = f2bf(o[0].x * inv) | (f2bf(o[0].y * inv) << 16);
    u0.y = f2bf(o[0].z * inv) | (f2bf(o[0].w * inv) << 16);
    u0.z = f2bf(o[1].x * inv) | (f2bf(o[1].y * inv) << 16);
    u0.w = f2bf(o[1].z * inv) | (f2bf(o[1].w * inv) << 16);
    u1.x = f2bf(o[2].x * inv) | (f2bf(o[2].y * inv) << 16);
    u1.y = f2bf(o[2].z * inv) | (f2bf(o[2].w * inv) << 16);
    u1.z = f2bf(o[3].x * inv) | (f2bf(o[3].y * inv) << 16);
    u1.w = f2bf(o[3].z * inv) | (f2bf(o[3].w * inv) << 16);
    oAf[((size_t)tt * 64 + kb0) * 16 + m] = u0;
    oAf[((size_t)tt * 64 + kb0 + 1) * 16 + m] = u1;
}

extern "C" void kernel_launch(void* const* d_in, const int* in_sizes, int n_in,
                              void* d_out, int out_size, void* d_ws, size_t ws_size,
                              hipStream_t stream) {
    const void* model_embed = d_in[0];
    const void* ctx_key     = d_in[1];
    const void* ctx_val     = d_in[2];
    const void* ln1w = d_in[3];  const void* ln1b = d_in[4];
    const void* ln2w = d_in[5];  const void* ln2b = d_in[6];
    const void* ln3w = d_in[7];  const void* ln3b = d_in[8];
    const void* ln4w = d_in[9];  const void* ln4b = d_in[10];
    const void* wq = d_in[11];   const void* bq = d_in[12];
    const void* wk = d_in[13];   const void* bk = d_in[14];
    const void* wv = d_in[15];   const void* bv = d_in[16];
    const void* wo = d_in[17];   const void* bo = d_in[18];
    const void* wp = d_in[19];   const void* bp = d_in[20];

    int*   flagp = (int*)d_ws;
    float* ws    = (float*)d_ws + 16;
    float* o1    = ws;                         // 524288 fp32
    float* qTf   = o1 + 524288;                // qf   262144 fl (1 MB)
    float* kTf   = qTf + 262144;               // kf  2097152 fl (8 MB)
    float* Aqf   = kTf + 2097152;              // Aq   262144 fl
    float* Akf   = Aqf + 262144;               // Ak  2097152 fl
    float* Avf   = Akf + 2097152;              // Av   524288 fl
    float* vff   = Avf + 524288;               // vf   524288 fl (also oAf)
    float* pacc2 = vff + 524288;               // 4194304 fl (16 MB)
    float* pm2   = pacc2 + 4194304;            // 65536
    float* pl2   = pm2 + 65536;                // 65536
    float* wfr   = pl2 + 65536;                // 655360 fl (5 W-frags)

    uint4* qf  = (uint4*)qTf;
    uint4* kf  = (uint4*)kTf;
    uint4* Aq  = (uint4*)Aqf;
    uint4* Ak  = (uint4*)Akf;
    uint4* Av  = (uint4*)Avf;
    uint4* vf  = (uint4*)vff;
    uint4* oAf = (uint4*)vff;                  // reuse after attn consumes vf
    uint4* wfq = (uint4*)wfr;
    uint4* wfk = wfq + 32768;
    uint4* wfv = wfk + 32768;
    uint4* wfo = wfv + 32768;
    uint4* wfp = wfo + 32768;

    detect_kernel<<<1, 256, 0, stream>>>(model_embed, flagp);

    pack_w_kernel<<<dim3(64, 5), 256, 0, stream>>>(wq, wk, wv, wo, wp,
                                                   wfq, wfk, wfv, wfo, wfp, flagp);
    pack_a3_kernel<<<704, 256, 0, stream>>>(model_embed, ln1w, ln1b,
                                            ctx_key, ln2w, ln2b,
                                            ctx_val, ln3w, ln3b,
                                            Aq, Ak, Av, flagp);

    mfma_gemm_kernel<1><<<dim3(8, 16), 256, 0, stream>>>(Aq, wfq, bq, nullptr, qf, 64, flagp);
    mfma_gemm_kernel<3><<<dim3(8, 128), 256, 0, stream>>>(Ak, wfk, bk, nullptr, kf, 512, flagp);
    mfma_gemm_kernel<2><<<dim3(8, 32), 256, 0, stream>>>(Av, wfv, bv, nullptr, vf, 0, flagp);

    attn_fused_kernel<<<1024, 256, 0, stream>>>(qf, kf, vf, pacc2, pm2, pl2);
    attn_merge2_kernel<<<128, 256, 0, stream>>>(pacc2, pm2, pl2, oAf);

    mfma_gemm_kernel<0><<<dim3(8, 16), 256, 0, stream>>>(oAf, wfo, bo, o1, nullptr, 0, flagp);
    pack_a_kernel<true><<<64, 256, 0, stream>>>(o1, 0, ln4w, ln4b, Aq, flagp);
    mfma_gemm_kernel<0><<<dim3(8, 16), 256, 0, stream>>>(Aq, wfp, bp, (float*)d_out, nullptr, 0, flagp);

    (void)ws_size;
}

// Round 15
// 247.114 us; speedup vs baseline: 20.6975x; 1.0643x over previous
//
#include <hip/hip_runtime.h>
#include <hip/hip_bf16.h>

using bf16 = __hip_bfloat16;

#define D_DIM 512
#define C_DIM 2048
#define U_DIM 4
#define DK 64

typedef __attribute__((ext_vector_type(8))) short short8;
typedef __attribute__((ext_vector_type(4))) float f32x4;

__device__ __forceinline__ float dload(const void* p, size_t i, int f) {
    return f ? ((const float*)p)[i] : __bfloat162float(((const bf16*)p)[i]);
}
__device__ __forceinline__ unsigned f2bf(float x) {
    bf16 b = __float2bfloat16(x);
    return (unsigned)*(unsigned short*)&b;
}

// ---------------------------------------------------------------------------
__global__ void detect_kernel(const void* __restrict__ x, int* __restrict__ flag) {
    const bf16* xb = (const bf16*)x;
    int tid = threadIdx.x;
    int cnt = 0;
    for (int i = tid; i < 8192; i += 256) {
        float a = fabsf(__bfloat162float(xb[i]));
        if (!(a <= 100.0f)) cnt++;
    }
    #pragma unroll
    for (int o = 32; o > 0; o >>= 1) cnt += __shfl_down(cnt, o);
    __shared__ int sred[4];
    if ((tid & 63) == 0) sred[tid >> 6] = cnt;
    __syncthreads();
    if (tid == 0) {
        int c = sred[0] + sred[1] + sred[2] + sred[3];
        *flag = (c > 400) ? 1 : 0;
    }
}

// ---------------------------------------------------------------------------
// A-fragment pack body: LN stats in-register (16 lanes per row, shfl reduce).
// ---------------------------------------------------------------------------
template <bool LN>
__device__ __forceinline__ void pack_a_body(const void* __restrict__ X, int xf, int f,
                                            const void* __restrict__ lnw,
                                            const void* __restrict__ lnb,
                                            uint4* __restrict__ Af, int tt) {
    int m = threadIdx.x >> 4;
    int kbL = threadIdx.x & 15;
    int row = tt * 16 + m;
    float v[32];
    float s = 0.0f, ss = 0.0f;
    #pragma unroll
    for (int i = 0; i < 4; ++i) {
        int k0 = (kbL + i * 16) * 8;
        #pragma unroll
        for (int j = 0; j < 8; ++j) {
            float x = dload(X, (size_t)row * D_DIM + k0 + j, xf);
            v[i * 8 + j] = x;
            s += x; ss += x * x;
        }
    }
    float mu = 0.0f, rs = 1.0f;
    if (LN) {
        #pragma unroll
        for (int o = 1; o < 16; o <<= 1) { s += __shfl_xor(s, o); ss += __shfl_xor(ss, o); }
        mu = s * (1.0f / D_DIM);
        float var = ss * (1.0f / D_DIM) - mu * mu;
        rs = rsqrtf(var + 1e-5f);
    }
    #pragma unroll
    for (int i = 0; i < 4; ++i) {
        int kb = kbL + i * 16;
        unsigned pk[4];
        #pragma unroll
        for (int jp = 0; jp < 4; ++jp) {
            int k0 = kb * 8 + jp * 2;
            float v0 = v[i * 8 + jp * 2];
            float v1 = v[i * 8 + jp * 2 + 1];
            if (LN) {
                v0 = (v0 - mu) * rs * dload(lnw, k0, f) + dload(lnb, k0, f);
                v1 = (v1 - mu) * rs * dload(lnw, k0 + 1, f) + dload(lnb, k0 + 1, f);
            }
            pk[jp] = f2bf(v0) | (f2bf(v1) << 16);
        }
        uint4 wv = {pk[0], pk[1], pk[2], pk[3]};
        Af[((size_t)tt * 64 + kb) * 16 + m] = wv;
    }
}

template <bool LN>
__global__ __launch_bounds__(256, 1)
void pack_a_kernel(const void* __restrict__ X, int x_raw,
                   const void* __restrict__ lnw, const void* __restrict__ lnb,
                   uint4* __restrict__ Af, const int* __restrict__ flagp) {
    int f = *flagp;
    pack_a_body<LN>(X, x_raw ? f : 1, f, lnw, lnb, Af, blockIdx.x);
}

// Combined q/k/v A-pack: ranges [0,64) me, [64,576) ck, [576,704) cv.
__global__ __launch_bounds__(256, 1)
void pack_a3_kernel(const void* __restrict__ me, const void* __restrict__ l1w, const void* __restrict__ l1b,
                    const void* __restrict__ ck, const void* __restrict__ l2w, const void* __restrict__ l2b,
                    const void* __restrict__ cv, const void* __restrict__ l3w, const void* __restrict__ l3b,
                    uint4* __restrict__ Aq, uint4* __restrict__ Ak, uint4* __restrict__ Av,
                    const int* __restrict__ flagp) {
    int f = *flagp;
    int b = blockIdx.x;
    if (b < 64)       pack_a_body<true>(me, f, f, l1w, l1b, Aq, b);
    else if (b < 576) pack_a_body<true>(ck, f, f, l2w, l2b, Ak, b - 64);
    else              pack_a_body<true>(cv, f, f, l3w, l3b, Av, b - 576);
}

// ---------------------------------------------------------------------------
// Pack all 5 weights into bf16 B-fragments (one launch, blockIdx.y selects).
// ---------------------------------------------------------------------------
__global__ void pack_w_kernel(const void* W0, const void* W1, const void* W2,
                              const void* W3, const void* W4,
                              uint4* B0, uint4* B1, uint4* B2, uint4* B3, uint4* B4,
                              const int* __restrict__ flagp) {
    __shared__ float t[64][65];
    const void* Ws[5] = {W0, W1, W2, W3, W4};
    uint4* Bs[5] = {B0, B1, B2, B3, B4};
    const void* W = Ws[blockIdx.y];
    uint4* Bf = Bs[blockIdx.y];
    int f = *flagp;
    int b = blockIdx.x;
    int n0 = (b & 7) * 64, k0 = (b >> 3) * 64;
    int tid = threadIdx.x;
    for (int i = 0; i < 16; ++i) {
        int e = i * 256 + tid;
        int r = e >> 6, c = e & 63;
        t[r][c] = dload(W, (size_t)(k0 + r) * D_DIM + n0 + c, f);
    }
    __syncthreads();
    #pragma unroll
    for (int i = 0; i < 2; ++i) {
        int e = i * 256 + tid;
        int nl = e & 63, kbl = e >> 6;
        unsigned pk[4];
        #pragma unroll
        for (int jp = 0; jp < 4; ++jp)
            pk[jp] = f2bf(t[kbl * 8 + jp * 2][nl]) | (f2bf(t[kbl * 8 + jp * 2 + 1][nl]) << 16);
        uint4 wv = {pk[0], pk[1], pk[2], pk[3]};
        int n = n0 + nl;
        Bf[(((size_t)(n >> 4)) * 64 + (k0 / 8 + kbl)) * 16 + (n & 15)] = wv;
    }
}

// ---------------------------------------------------------------------------
// Fragment MFMA GEMM, templated epilogue:
// OUT=0 fp32 Y; OUT=1 score-frag (q); OUT=2 PV B-frag (v);
// OUT=3 u-split score-B frag (k): nt = ctx_tile*4 + u.
// ---------------------------------------------------------------------------
template <int OUT>
__global__ __launch_bounds__(256, 1)
void mfma_gemm_kernel(const uint4* __restrict__ Af, const uint4* __restrict__ Bf,
                      const void* __restrict__ bias, float* __restrict__ Y,
                      uint4* __restrict__ Fout, int Rtt,
                      const int* __restrict__ flagp) {
    __shared__ float t[64][65];
    int f = *flagp;
    int w = threadIdx.x >> 6, lane = threadIdx.x & 63;
    int q = lane >> 4, mn = lane & 15;
    int mt = blockIdx.y * 4 + w;
    int nt0 = blockIdx.x * 4;
    f32x4 acc[4] = {{0.f,0.f,0.f,0.f},{0.f,0.f,0.f,0.f},{0.f,0.f,0.f,0.f},{0.f,0.f,0.f,0.f}};
    for (int kw = 0; kw < 16; ++kw) {
        short8 a = *(const short8*)(Af + ((size_t)mt * 64 + kw * 4 + q) * 16 + mn);
        #pragma unroll
        for (int i = 0; i < 4; ++i) {
            short8 b = *(const short8*)(Bf + (((size_t)(nt0 + i)) * 64 + kw * 4 + q) * 16 + mn);
            acc[i] = __builtin_amdgcn_mfma_f32_16x16x32_bf16(a, b, acc[i], 0, 0, 0);
        }
    }
    if constexpr (OUT == 0) {
        #pragma unroll
        for (int i = 0; i < 4; ++i) {
            int col = (nt0 + i) * 16 + mn;
            float bv = dload(bias, col, f);
            #pragma unroll
            for (int r = 0; r < 4; ++r)
                Y[(size_t)(mt * 16 + q * 4 + r) * D_DIM + col] = acc[i][r] + bv;
        }
    } else {
        #pragma unroll
        for (int i = 0; i < 4; ++i) {
            float bv = dload(bias, (nt0 + i) * 16 + mn, f);
            #pragma unroll
            for (int r = 0; r < 4; ++r)
                t[w * 16 + q * 4 + r][i * 16 + mn] = acc[i][r] + bv;
        }
        __syncthreads();
        int h = blockIdx.x;
        if constexpr (OUT == 1) {
            #pragma unroll
            for (int e0 = 0; e0 < 2; ++e0) {
                int e = e0 * 256 + threadIdx.x;
                int m = e & 15, kb = (e >> 4) & 7, ttl = e >> 7;
                const float* src = &t[ttl * 16 + m][kb * 8];
                uint4 wv;
                wv.x = f2bf(src[0]) | (f2bf(src[1]) << 16);
                wv.y = f2bf(src[2]) | (f2bf(src[3]) << 16);
                wv.z = f2bf(src[4]) | (f2bf(src[5]) << 16);
                wv.w = f2bf(src[6]) | (f2bf(src[7]) << 16);
                Fout[(((size_t)h * Rtt + blockIdx.y * 4 + ttl) * 8 + kb) * 16 + m] = wv;
            }
        } else if constexpr (OUT == 2) {
            #pragma unroll
            for (int e0 = 0; e0 < 2; ++e0) {
                int e = e0 * 256 + threadIdx.x;
                int lane2 = e & 63, nt = (e >> 6) & 3, ctl = e >> 8;
                int nm2 = lane2 & 15, q2 = lane2 >> 4;
                int col = nt * 16 + nm2;
                int rb = ctl * 32 + q2 * 8;
                uint4 wv;
                wv.x = f2bf(t[rb + 0][col]) | (f2bf(t[rb + 1][col]) << 16);
                wv.y = f2bf(t[rb + 2][col]) | (f2bf(t[rb + 3][col]) << 16);
                wv.z = f2bf(t[rb + 4][col]) | (f2bf(t[rb + 5][col]) << 16);
                wv.w = f2bf(t[rb + 6][col]) | (f2bf(t[rb + 7][col]) << 16);
                Fout[(((size_t)h * 64 + blockIdx.y * 2 + ctl) * 4 + nt) * 64 + lane2] = wv;
            }
        } else {
            #pragma unroll
            for (int e0 = 0; e0 < 2; ++e0) {
                int e = e0 * 256 + threadIdx.x;
                int m2 = e & 15, kb = (e >> 4) & 7, u = e >> 7;
                const float* src = &t[m2 * 4 + u][kb * 8];
                uint4 wv;
                wv.x = f2bf(src[0]) | (f2bf(src[1]) << 16);
                wv.y = f2bf(src[2]) | (f2bf(src[3]) << 16);
                wv.z = f2bf(src[4]) | (f2bf(src[5]) << 16);
                wv.w = f2bf(src[6]) | (f2bf(src[7]) << 16);
                int nt = blockIdx.y * 4 + u;
                Fout[(((size_t)h * 512 + nt) * 8 + kb) * 16 + m2] = wv;
            }
        }
    }
}

// ---------------------------------------------------------------------------
// FUSED MFMA flash attention — TWO-PASS register-resident softmax (round-14
// postmortem: online-softmax serial chain was latency-bound at both-pipes-
// idle). Phase 1: all 32 score MFMAs for the 256-ctx split, sc[] in regs.
// Phase 2: one split-max per row (16 reg values + 4 shuffles). No alpha.
// Phase 3: exp -> LDS -> P-frag -> PV MFMAs; row sums in regs, reduced once.
// ---------------------------------------------------------------------------
__global__ __launch_bounds__(256, 1)
void attn_fused_kernel(const uint4* __restrict__ qf, const uint4* __restrict__ kf,
                       const uint4* __restrict__ vf,
                       float* __restrict__ pacc, float* __restrict__ pm,
                       float* __restrict__ pl) {
    __shared__ float sp[4][16][36];
    int tid = threadIdx.x;
    int w = tid >> 6, lane = tid & 63;
    int q = lane >> 4, nm = lane & 15;
    int b = blockIdx.x;
    int s = b & 7;
    int h = (b >> 3) & 7;
    int qb = b >> 6;
    int mt = qb * 4 + w;

    short8 a0 = *(const short8*)(qf + (((size_t)h * 64 + mt) * 8 + q) * 16 + nm);
    short8 a1 = *(const short8*)(qf + (((size_t)h * 64 + mt) * 8 + 4 + q) * 16 + nm);

    // Phase 1: scores for all 8 super-tiles (16 ctx16-tiles), MaxSim over u.
    f32x4 sc[8][2];
    #pragma unroll
    for (int st = 0; st < 8; ++st) {
        #pragma unroll
        for (int hh = 0; hh < 2; ++hh) {
            int ct16 = (s * 8 + st) * 2 + hh;
            f32x4 scv = {-1e30f, -1e30f, -1e30f, -1e30f};
            #pragma unroll
            for (int u = 0; u < 4; ++u) {
                int nt = ct16 * 4 + u;
                short8 b0 = *(const short8*)(kf + (((size_t)h * 512 + nt) * 8 + q) * 16 + nm);
                short8 b1 = *(const short8*)(kf + (((size_t)h * 512 + nt) * 8 + 4 + q) * 16 + nm);
                f32x4 acc = {0.0f, 0.0f, 0.0f, 0.0f};
                acc = __builtin_amdgcn_mfma_f32_16x16x32_bf16(a0, b0, acc, 0, 0, 0);
                acc = __builtin_amdgcn_mfma_f32_16x16x32_bf16(a1, b1, acc, 0, 0, 0);
                #pragma unroll
                for (int r = 0; r < 4; ++r) scv[r] = fmaxf(scv[r], acc[r]);
            }
            #pragma unroll
            for (int r = 0; r < 4; ++r) sc[st][hh][r] = scv[r] * 0.125f;  // 1/sqrt(dk)
        }
    }

    // Phase 2: split max per query row (one shuffle tree, no online alpha).
    float mrow[4], lrow[4];
    #pragma unroll
    for (int r = 0; r < 4; ++r) {
        float m = sc[0][0][r];
        #pragma unroll
        for (int st = 0; st < 8; ++st) {
            m = fmaxf(m, sc[st][0][r]);
            m = fmaxf(m, sc[st][1][r]);
        }
        m = fmaxf(m, __shfl_xor(m, 1));
        m = fmaxf(m, __shfl_xor(m, 2));
        m = fmaxf(m, __shfl_xor(m, 4));
        m = fmaxf(m, __shfl_xor(m, 8));
        mrow[r] = m;
        lrow[r] = 0.0f;
    }

    // Phase 3: exp -> P-frag via per-wave LDS -> PV MFMAs (K=32 per tile).
    f32x4 acc_o[4] = {{0.f,0.f,0.f,0.f},{0.f,0.f,0.f,0.f},{0.f,0.f,0.f,0.f},{0.f,0.f,0.f,0.f}};
    #pragma unroll
    for (int st = 0; st < 8; ++st) {
        #pragma unroll
        for (int r = 0; r < 4; ++r) {
            float p0 = __expf(sc[st][0][r] - mrow[r]);
            float p1 = __expf(sc[st][1][r] - mrow[r]);
            sp[w][q * 4 + r][nm] = p0;
            sp[w][q * 4 + r][16 + nm] = p1;
            lrow[r] += p0 + p1;
        }
        float4 pa0 = *(const float4*)&sp[w][nm][q * 8];
        float4 pa1 = *(const float4*)&sp[w][nm][q * 8 + 4];
        uint4 av;
        av.x = f2bf(pa0.x) | (f2bf(pa0.y) << 16);
        av.y = f2bf(pa0.z) | (f2bf(pa0.w) << 16);
        av.z = f2bf(pa1.x) | (f2bf(pa1.y) << 16);
        av.w = f2bf(pa1.z) | (f2bf(pa1.w) << 16);
        short8 ap = *(short8*)&av;
        int ct32 = s * 8 + st;
        #pragma unroll
        for (int nt2 = 0; nt2 < 4; ++nt2) {
            short8 bv = *(const short8*)(vf + (((size_t)h * 64 + ct32) * 4 + nt2) * 64 + lane);
            acc_o[nt2] = __builtin_amdgcn_mfma_f32_16x16x32_bf16(ap, bv, acc_o[nt2], 0, 0, 0);
        }
    }

    // Row-sum reduction across the 16 context lanes (once).
    #pragma unroll
    for (int r = 0; r < 4; ++r) {
        float ps = lrow[r];
        ps += __shfl_xor(ps, 1);
        ps += __shfl_xor(ps, 2);
        ps += __shfl_xor(ps, 4);
        ps += __shfl_xor(ps, 8);
        lrow[r] = ps;
    }

    int p_idx = ((qb * 8 + h) << 3) + s;
    float* po = pacc + ((size_t)p_idx * 64 + w * 16) * 64;
    #pragma unroll
    for (int nt2 = 0; nt2 < 4; ++nt2)
        #pragma unroll
        for (int r = 0; r < 4; ++r)
            po[(q * 4 + r) * 64 + nt2 * 16 + nm] = acc_o[nt2][r];
    if (nm == 0) {
        #pragma unroll
        for (int r = 0; r < 4; ++r) {
            pm[p_idx * 64 + w * 16 + q * 4 + r] = mrow[r];
            pl[p_idx * 64 + w * 16 + q * 4 + r] = lrow[r];
        }
    }
}

// Merge 8 c-split partials; emit wo-GEMM A-fragments directly.
__global__ void attn_merge2_kernel(const float* __restrict__ pacc, const float* __restrict__ pm,
                                   const float* __restrict__ pl, uint4* __restrict__ oAf) {
    int b = blockIdx.x;                // qb*8 + h
    int qb = b >> 3, h = b & 7;
    int tid = threadIdx.x;
    int t_loc = tid & 63, dg = tid >> 6;
    int p0 = b * 8;
    float M = -1e30f;
    #pragma unroll
    for (int s = 0; s < 8; ++s) M = fmaxf(M, pm[(p0 + s) * 64 + t_loc]);
    float L = 0.0f;
    float4 o[4] = {};
    #pragma unroll
    for (int s = 0; s < 8; ++s) {
        float e = __expf(pm[(p0 + s) * 64 + t_loc] - M);
        L += pl[(p0 + s) * 64 + t_loc] * e;
        const float4* po = (const float4*)(pacc + ((size_t)(p0 + s) * 64 + t_loc) * 64 + dg * 16);
        #pragma unroll
        for (int d = 0; d < 4; ++d) {
            float4 v = po[d];
            o[d].x += v.x * e; o[d].y += v.y * e; o[d].z += v.z * e; o[d].w += v.w * e;
        }
    }
    float inv = 1.0f / L;
    int t = qb * 64 + t_loc;
    int tt = t >> 4, m = t & 15;
    int kb0 = h * 8 + dg * 2;
    uint4 u0, u1;
    u0.x = f2bf(o[0].x * inv) | (f2bf(o[0].y * inv) << 16);
    u0.y = f2bf(o[0].z * inv) | (f2bf(o[0].w * inv) << 16);
    u0.z = f2bf(o[1].x * inv) | (f2bf(o[1].y * inv) << 16);
    u0.w = f2bf(o[1].z * inv) | (f2bf(o[1].w * inv) << 16);
    u1.x = f2bf(o[2].x * inv) | (f2bf(o[2].y * inv) << 16);
    u1.y = f2bf(o[2].z * inv) | (f2bf(o[2].w * inv) << 16);
    u1.z = f2bf(o[3].x * inv) | (f2bf(o[3].y * inv) << 16);
    u1.w = f2bf(o[3].z * inv) | (f2bf(o[3].w * inv) << 16);
    oAf[((size_t)tt * 64 + kb0) * 16 + m] = u0;
    oAf[((size_t)tt * 64 + kb0 + 1) * 16 + m] = u1;
}

extern "C" void kernel_launch(void* const* d_in, const int* in_sizes, int n_in,
                              void* d_out, int out_size, void* d_ws, size_t ws_size,
                              hipStream_t stream) {
    const void* model_embed = d_in[0];
    const void* ctx_key     = d_in[1];
    const void* ctx_val     = d_in[2];
    const void* ln1w = d_in[3];  const void* ln1b = d_in[4];
    const void* ln2w = d_in[5];  const void* ln2b = d_in[6];
    const void* ln3w = d_in[7];  const void* ln3b = d_in[8];
    const void* ln4w = d_in[9];  const void* ln4b = d_in[10];
    const void* wq = d_in[11];   const void* bq = d_in[12];
    const void* wk = d_in[13];   const void* bk = d_in[14];
    const void* wv = d_in[15];   const void* bv = d_in[16];
    const void* wo = d_in[17];   const void* bo = d_in[18];
    const void* wp = d_in[19];   const void* bp = d_in[20];

    int*   flagp = (int*)d_ws;
    float* ws    = (float*)d_ws + 16;
    float* o1    = ws;                         // 524288 fp32
    float* qTf   = o1 + 524288;                // qf   262144 fl (1 MB)
    float* kTf   = qTf + 262144;               // kf  2097152 fl (8 MB)
    float* Aqf   = kTf + 2097152;              // Aq   262144 fl
    float* Akf   = Aqf + 262144;               // Ak  2097152 fl
    float* Avf   = Akf + 2097152;              // Av   524288 fl
    float* vff   = Avf + 524288;               // vf   524288 fl (also oAf)
    float* pacc2 = vff + 524288;               // 4194304 fl (16 MB)
    float* pm2   = pacc2 + 4194304;            // 65536
    float* pl2   = pm2 + 65536;                // 65536
    float* wfr   = pl2 + 65536;                // 655360 fl (5 W-frags)

    uint4* qf  = (uint4*)qTf;
    uint4* kf  = (uint4*)kTf;
    uint4* Aq  = (uint4*)Aqf;
    uint4* Ak  = (uint4*)Akf;
    uint4* Av  = (uint4*)Avf;
    uint4* vf  = (uint4*)vff;
    uint4* oAf = (uint4*)vff;                  // reuse after attn consumes vf
    uint4* wfq = (uint4*)wfr;
    uint4* wfk = wfq + 32768;
    uint4* wfv = wfk + 32768;
    uint4* wfo = wfv + 32768;
    uint4* wfp = wfo + 32768;

    detect_kernel<<<1, 256, 0, stream>>>(model_embed, flagp);

    pack_w_kernel<<<dim3(64, 5), 256, 0, stream>>>(wq, wk, wv, wo, wp,
                                                   wfq, wfk, wfv, wfo, wfp, flagp);
    pack_a3_kernel<<<704, 256, 0, stream>>>(model_embed, ln1w, ln1b,
                                            ctx_key, ln2w, ln2b,
                                            ctx_val, ln3w, ln3b,
                                            Aq, Ak, Av, flagp);

    mfma_gemm_kernel<1><<<dim3(8, 16), 256, 0, stream>>>(Aq, wfq, bq, nullptr, qf, 64, flagp);
    mfma_gemm_kernel<3><<<dim3(8, 128), 256, 0, stream>>>(Ak, wfk, bk, nullptr, kf, 512, flagp);
    mfma_gemm_kernel<2><<<dim3(8, 32), 256, 0, stream>>>(Av, wfv, bv, nullptr, vf, 0, flagp);

    attn_fused_kernel<<<1024, 256, 0, stream>>>(qf, kf, vf, pacc2, pm2, pl2);
    attn_merge2_kernel<<<128, 256, 0, stream>>>(pacc2, pm2, pl2, oAf);

    mfma_gemm_kernel<0><<<dim3(8, 16), 256, 0, stream>>>(oAf, wfo, bo, o1, nullptr, 0, flagp);
    pack_a_kernel<true><<<64, 256, 0, stream>>>(o1, 0, ln4w, ln4b, Aq, flagp);
    mfma_gemm_kernel<0><<<dim3(8, 16), 256, 0, stream>>>(Aq, wfp, bp, (float*)d_out, nullptr, 0, flagp);

    (void)ws_size;
}